// Round 1
// baseline (371.704 us; speedup 1.0000x reference)
//
#include <hip/hip_runtime.h>
#include <hip/hip_bf16.h>

#define B_ 1024
#define D_ 256
#define R_ 16384
#define W_ 64

typedef float f32x4 __attribute__((ext_vector_type(4)));
typedef __bf16 bf16x8 __attribute__((ext_vector_type(8)));

__device__ __forceinline__ float bf2f(unsigned short u) {
    union { unsigned int i; float f; } v; v.i = ((unsigned int)u) << 16; return v.f;
}
__device__ __forceinline__ unsigned short f2bf(float f) {
    union { float fv; unsigned int i; } v; v.fv = f;
    unsigned int r = v.i + 0x7FFFu + ((v.i >> 16) & 1u);
    return (unsigned short)(r >> 16);
}
__device__ __forceinline__ f32x4 mfma16(bf16x8 a, bf16x8 b, f32x4 c) {
    return __builtin_amdgcn_mfma_f32_16x16x32_bf16(a, b, c, 0, 0, 0);
}
__device__ __forceinline__ bf16x8 ld_bf8(const unsigned short* p) {
    return *(const bf16x8*)p;
}

// ---------------- arena element offsets (each segment start 16-elem aligned) ----
// Wp is no longer staged through the arena: k_transpose_wp reads the fp32 input
// directly and emits bf16 WpT (saves ~17 MB of convert round-trip).
#define AO_X     0
#define AO_WV    262144
#define AO_BV    278528
#define AO_WB    278592
#define AO_BB    278848
#define AO_WG    278864
#define AO_BG    279120
#define AO_BP    279136
#define AO_CK    295520
#define AO_CB    295536
#define AO_MEM   295552
#define AO_TOT   1344128

__global__ __launch_bounds__(256) void k_sentinel(float* __restrict__ out, float val) {
    out[blockIdx.x * 256 + threadIdx.x] = val;
}

__global__ __launch_bounds__(256) void k_zero(float* __restrict__ z) {
    z[blockIdx.x * 256 + threadIdx.x] = 0.f;
}

// ---------------- K-convert: fp32 inputs -> bf16 arena (no Wp) ----------------
__global__ __launch_bounds__(256) void k_convert(
        const float* x, const float* Wv, const float* bv, const float* Wb, const float* bb,
        const float* Wg, const float* bg, const float* bp,
        const float* ck, const float* cb, const float* mem,
        unsigned short* __restrict__ dst) {
    int base = blockIdx.x * 512 + threadIdx.x;
#pragma unroll
    for (int h = 0; h < 2; h++) {
        int idx = base + h * 256;
        if (idx >= AO_TOT) continue;
        const float* p; int st; int n;
        if      (idx >= AO_MEM) { p = mem; st = AO_MEM; n = R_ * W_; }
        else if (idx >= AO_CB)  { p = cb;  st = AO_CB;  n = 1; }
        else if (idx >= AO_CK)  { p = ck;  st = AO_CK;  n = 3; }
        else if (idx >= AO_BP)  { p = bp;  st = AO_BP;  n = R_; }
        else if (idx >= AO_BG)  { p = bg;  st = AO_BG;  n = 1; }
        else if (idx >= AO_WG)  { p = Wg;  st = AO_WG;  n = D_; }
        else if (idx >= AO_BB)  { p = bb;  st = AO_BB;  n = 1; }
        else if (idx >= AO_WB)  { p = Wb;  st = AO_WB;  n = D_; }
        else if (idx >= AO_BV)  { p = bv;  st = AO_BV;  n = W_; }
        else if (idx >= AO_WV)  { p = Wv;  st = AO_WV;  n = D_ * W_; }
        else                    { p = x;   st = AO_X;   n = B_ * D_; }
        int local = idx - st;
        dst[idx] = (local < n) ? f2bf(p[local]) : (unsigned short)0;
    }
}

// ---------------- K0: transpose+convert Wp fp32 [D,R] -> WpT bf16 [R,D] --------
__global__ __launch_bounds__(256) void k_transpose_wp(const float* __restrict__ Wp,
                                                      unsigned short* __restrict__ WpT) {
    __shared__ unsigned short tile[64][66];
    int r0 = blockIdx.x * 64, d0 = blockIdx.y * 64;
    int t = threadIdx.x, lane = t & 63, wv = t >> 6;
#pragma unroll
    for (int i = 0; i < 16; i++) {
        int dl = wv + 4 * i;
        tile[dl][lane] = f2bf(Wp[(size_t)(d0 + dl) * R_ + r0 + lane]);
    }
    __syncthreads();
#pragma unroll
    for (int i = 0; i < 16; i++) {
        int rl = wv + 4 * i;
        WpT[(size_t)(r0 + rl) * D_ + d0 + lane] = tile[lane][rl];
    }
}

// ---------------- K1: controller heads: v, vb, bovn=beta/vn, beta, gamma ----------
__global__ __launch_bounds__(64) void k_heads(const unsigned short* __restrict__ x,
        const unsigned short* __restrict__ Wv, const unsigned short* __restrict__ bv,
        const unsigned short* __restrict__ Wb, const unsigned short* __restrict__ bb,
        const unsigned short* __restrict__ Wg, const unsigned short* __restrict__ bg,
        float* __restrict__ v, unsigned short* __restrict__ vb,
        float* __restrict__ bovn, float* __restrict__ beta, float* __restrict__ gamma) {
    __shared__ float sx[256];
    int b = blockIdx.x, lane = threadIdx.x;
#pragma unroll
    for (int j = 0; j < 4; j++) sx[lane + 64 * j] = bf2f(x[b * 256 + lane + 64 * j]);
    __syncthreads();
    float acc = 0.f;
#pragma unroll 8
    for (int d = 0; d < 256; d++) acc += sx[d] * bf2f(Wv[d * 64 + lane]);
    acc += bf2f(bv[lane]);
    v[b * 64 + lane] = acc;
    vb[b * 64 + lane] = f2bf(acc);
    float sq = acc * acc;
#pragma unroll
    for (int d = 32; d >= 1; d >>= 1) sq += __shfl_xor(sq, d, 64);
    float pb = 0.f, pg = 0.f;
#pragma unroll
    for (int j = 0; j < 4; j++) {
        float xv = sx[lane + 64 * j];
        pb += xv * bf2f(Wb[lane + 64 * j]);
        pg += xv * bf2f(Wg[lane + 64 * j]);
    }
#pragma unroll
    for (int d = 32; d >= 1; d >>= 1) { pb += __shfl_xor(pb, d, 64); pg += __shfl_xor(pg, d, 64); }
    if (lane == 0) {
        float vn = sqrtf(sq);
        float zb = pb + bf2f(bb[0]);
        float zg = pg + bf2f(bg[0]);
        float be = (zb > 20.f) ? zb : log1pf(__expf(zb));
        beta[b]  = be;
        bovn[b]  = be / (vn + 1e-16f);
        gamma[b] = 1.f + ((zg > 20.f) ? zg : log1pf(__expf(zg)));
    }
}

// ---------------- K2: mem row inverse norms ----------------
__global__ __launch_bounds__(256) void k_mn(const unsigned short* __restrict__ mem, float* __restrict__ invmn) {
    int lane = threadIdx.x & 63;
    int gw = blockIdx.x * 4 + (threadIdx.x >> 6);
    for (int row = gw; row < R_; row += 256) {
        float m = bf2f(mem[row * 64 + lane]);
        float s = m * m;
#pragma unroll
        for (int d = 32; d >= 1; d >>= 1) s += __shfl_xor(s, d, 64);
        if (lane == 0) invmn[row] = 1.0f / (sqrtf(s) + 1e-16f);
    }
}

// ---------------- K3: sim MFMA -> E = exp(acc*bovn*invmn - beta), S[b] ----------
__global__ __launch_bounds__(256, 8) void k_sim(const unsigned short* __restrict__ vb,
        const unsigned short* __restrict__ mem,
        const float* __restrict__ bovn, const float* __restrict__ invmn,
        const float* __restrict__ beta,
        unsigned short* __restrict__ E, float* __restrict__ S) {
    __shared__ unsigned short etile[64][132];
    __shared__ float sred[4][64];
    int bx = blockIdx.x;
    int rc = bx & 127, tb = bx >> 7;
    int t = threadIdx.x, wv = t >> 6, l = t & 63;
    int lane15 = l & 15, quad = l >> 4;
    int rr0 = rc * 128 + wv * 32 + lane15;
    bf16x8 bm[2][2];
    float im[2];
#pragma unroll
    for (int nt = 0; nt < 2; nt++) {
        int rr = rr0 + nt * 16;
        bm[nt][0] = ld_bf8(mem + rr * 64 + quad * 8);
        bm[nt][1] = ld_bf8(mem + rr * 64 + 32 + quad * 8);
        im[nt] = invmn[rr];
    }
    bf16x8 afr[4][2];
    float bvl[4][4], bel[4][4];
#pragma unroll
    for (int m = 0; m < 4; m++) {
        int brow = tb * 64 + m * 16 + lane15;
        afr[m][0] = ld_bf8(vb + brow * 64 + quad * 8);
        afr[m][1] = ld_bf8(vb + brow * 64 + 32 + quad * 8);
#pragma unroll
        for (int reg = 0; reg < 4; reg++) {
            int b2 = tb * 64 + m * 16 + quad * 4 + reg;
            bvl[m][reg] = bovn[b2];
            bel[m][reg] = beta[b2];
        }
    }
    float sp[4][4];
#pragma unroll
    for (int m = 0; m < 4; m++)
#pragma unroll
        for (int r = 0; r < 4; r++) sp[m][r] = 0.f;

#pragma unroll
    for (int nt = 0; nt < 2; nt++) {
        int rl = wv * 32 + nt * 16 + lane15;
#pragma unroll
        for (int m = 0; m < 4; m++) {
            f32x4 acc = (f32x4){0.f, 0.f, 0.f, 0.f};
            acc = mfma16(afr[m][0], bm[nt][0], acc);
            acc = mfma16(afr[m][1], bm[nt][1], acc);
#pragma unroll
            for (int reg = 0; reg < 4; reg++) {
                float e = __expf(acc[reg] * (bvl[m][reg] * im[nt]) - bel[m][reg]);
                sp[m][reg] += e;
                etile[m * 16 + quad * 4 + reg][rl] = f2bf(e);
            }
        }
    }
#pragma unroll
    for (int m = 0; m < 4; m++)
#pragma unroll
        for (int reg = 0; reg < 4; reg++) {
            float s = sp[m][reg];
            s += __shfl_xor(s, 1, 64); s += __shfl_xor(s, 2, 64);
            s += __shfl_xor(s, 4, 64); s += __shfl_xor(s, 8, 64);
            if (lane15 == 0) sred[wv][m * 16 + quad * 4 + reg] = s;
        }
    __syncthreads();
#pragma unroll
    for (int j = 0; j < 4; j++) {
        int idx8 = t + j * 256;
        int row = idx8 >> 4;
        int c8 = (idx8 & 15) * 8;
        *(bf16x8*)(E + (size_t)(tb * 64 + row) * R_ + rc * 128 + c8) =
            *(const bf16x8*)&etile[row][c8];
    }
    if (t < 64)
        atomicAdd(&S[tb * 64 + t], sred[0][t] + sred[1][t] + sred[2][t] + sred[3][t]);
}

// ---------------- K4: conv+pow -> AT [R,B] (transposed!), T[b] ----------------
__global__ __launch_bounds__(256) void k_conv(const unsigned short* __restrict__ E,
        unsigned short* __restrict__ AT,
        const float* __restrict__ S, const float* __restrict__ gamma,
        const unsigned short* __restrict__ conv_k, const unsigned short* __restrict__ conv_b,
        float* __restrict__ T) {
    __shared__ unsigned short ein[64][132];
    __shared__ unsigned short hl[64], hr[64];
    __shared__ unsigned short aout[128][68];
    __shared__ float red[64], sS[64], sG[64];
    float k0 = bf2f(conv_k[0]), k1 = bf2f(conv_k[1]), k2 = bf2f(conv_k[2]);
    float cb = bf2f(conv_b[0]);
    int b0 = (blockIdx.x >> 7) * 64;
    int r0 = (blockIdx.x & 127) * 128;
    int t = threadIdx.x;
    if (t < 64) {
        red[t] = 0.f;
        sS[t] = 1.0f / S[b0 + t];
        sG[t] = gamma[b0 + t];
        hl[t] = (r0 > 0) ? E[(b0 + t) * R_ + r0 - 1] : (unsigned short)0;
    } else if (t < 128) {
        int tb = t - 64;
        hr[tb] = (r0 + 128 < R_) ? E[(b0 + tb) * R_ + r0 + 128] : (unsigned short)0;
    }
#pragma unroll
    for (int j = 0; j < 8; j++) {
        int idx4 = t + j * 256;
        int row = idx4 >> 5, c4 = (idx4 & 31) * 4;
        *(ushort4*)&ein[row][c4] = *(const ushort4*)(E + (b0 + row) * R_ + r0 + c4);
    }
    __syncthreads();
#pragma unroll 4
    for (int j = 0; j < 32; j++) {
        int idx = t + j * 256;
        int row = idx >> 7, col = idx & 127;
        float el = (col == 0)   ? bf2f(hl[row]) : bf2f(ein[row][col - 1]);
        float ec = bf2f(ein[row][col]);
        float er = (col == 127) ? bf2f(hr[row]) : bf2f(ein[row][col + 1]);
        float wc = (k0 * el + k1 * ec + k2 * er) * sS[row] + cb;
        wc = fmaxf(wc, 1e-30f);
        float au = __expf(sG[row] * __logf(wc));
        aout[col][row] = f2bf(au);
        float s = au;
#pragma unroll
        for (int d = 32; d >= 1; d >>= 1) s += __shfl_xor(s, d, 64);
        if ((t & 63) == 0) atomicAdd(&red[row], s);
    }
    __syncthreads();
    if (t < 64) atomicAdd(&T[b0 + t], red[t]);
#pragma unroll
    for (int j = 0; j < 8; j++) {
        int idx4 = t + j * 256;
        int rrow = idx4 >> 4, c4 = (idx4 & 15) * 4;
        *(ushort4*)(AT + (size_t)(r0 + rrow) * B_ + b0 + c4) = *(ushort4*)&aout[rrow][c4];
    }
}

// ---------------- K4b: build vp' [80,1024] bf16 ----------------
__global__ __launch_bounds__(256) void k_vp2(const float* __restrict__ v, const float* __restrict__ T,
                                             unsigned short* __restrict__ vpb) {
    int idx = blockIdx.x * 256 + threadIdx.x;
    int m = idx >> 10, b = idx & 1023;
    float s = 1.0f / ((T[b] + (float)R_ * 1e-16f) * (float)B_);
    float val = (m < 64) ? v[b * 64 + m] * s : ((m == 64) ? s : 0.f);
    vpb[idx] = f2bf(val);
}

// ---------------- K5: MFMA GEMM mem2T = mem*(1-er) + vp'^ AT ----------------
__global__ __launch_bounds__(256) void k_add(const unsigned short* __restrict__ AT,
        const unsigned short* __restrict__ vpb,
        const unsigned short* __restrict__ memb, unsigned short* __restrict__ mem2T) {
    __shared__ unsigned short smem[64][68];
    __shared__ unsigned short sm2[64][68];
    int r0 = blockIdx.x * 64;
    int t = threadIdx.x, wv = t >> 6, l = t & 63;
    int lane15 = l & 15, quad = l >> 4;
#pragma unroll
    for (int j = 0; j < 4; j++) {
        int idx4 = t + j * 256;
        int rl = idx4 >> 4, w4 = (idx4 & 15) * 4;
        *(ushort4*)&smem[rl][w4] = *(const ushort4*)(memb + (r0 + rl) * 64 + w4);
    }
    __syncthreads();

    const unsigned short* Brow = AT + (size_t)(r0 + wv * 16 + lane15) * B_ + quad * 8;
    const unsigned short* A0 = vpb + (0 * 16 + lane15) * B_ + quad * 8;
    const unsigned short* A1 = vpb + (1 * 16 + lane15) * B_ + quad * 8;
    const unsigned short* A2 = vpb + (2 * 16 + lane15) * B_ + quad * 8;
    const unsigned short* A3 = vpb + (3 * 16 + lane15) * B_ + quad * 8;
    const unsigned short* A4 = vpb + (4 * 16 + lane15) * B_ + quad * 8;
    f32x4 acc0 = {0,0,0,0}, acc1 = {0,0,0,0}, acc2 = {0,0,0,0}, acc3 = {0,0,0,0}, acc4 = {0,0,0,0};
#pragma unroll 4
    for (int k0 = 0; k0 < B_; k0 += 32) {
        bf16x8 bf = ld_bf8(Brow + k0);
        acc0 = mfma16(ld_bf8(A0 + k0), bf, acc0);
        acc1 = mfma16(ld_bf8(A1 + k0), bf, acc1);
        acc2 = mfma16(ld_bf8(A2 + k0), bf, acc2);
        acc3 = mfma16(ld_bf8(A3 + k0), bf, acc3);
        acc4 = mfma16(ld_bf8(A4 + k0), bf, acc4);
    }
    float er = __shfl(acc4[0], l & 15, 64);
    float ome = 1.f - er;
    f32x4 accs[4] = {acc0, acc1, acc2, acc3};
#pragma unroll
    for (int mt = 0; mt < 4; mt++) {
#pragma unroll
        for (int reg = 0; reg < 4; reg++) {
            int w = mt * 16 + quad * 4 + reg;
            int rl = wv * 16 + lane15;
            float m2 = bf2f(smem[rl][w]) * ome + accs[mt][reg];
            sm2[w][rl] = f2bf(m2);
        }
    }
    __syncthreads();
#pragma unroll
    for (int j = 0; j < 4; j++) {
        int idx4 = t + j * 256;
        int w = idx4 >> 4, r4 = (idx4 & 15) * 4;
        *(ushort4*)(mem2T + (size_t)w * R_ + r0 + r4) = *(ushort4*)&sm2[w][r4];
    }
}

// ---------------- K6: read head, barrier-free streaming form ----------------
// Swapped-operand QK^T: C[r][b] = sum_d WpT[r][d] x[b][d] -> both operands are
// contiguous 16B loads from L1/L2, no LDS staging, no per-phase barriers.
// E stays in registers (packed bf16); PV B-fragments are assembled by 8 shfl +
// 4 selects per fragment. Per block: 64 b cols x 256 r rows (64 r per wave).
// XCD-bijective swizzle: the 16 tb-blocks sharing one WpT slice map to one XCD.
// Waves combine their 64x64 output tiles in LDS (2 barriers total) so global
// atomic count stays at 4096/block.
__global__ __launch_bounds__(256) void k_read(const unsigned short* __restrict__ x,
        const unsigned short* __restrict__ WpT, const unsigned short* __restrict__ bp,
        const unsigned short* __restrict__ mem2T,
        float* __restrict__ outacc, float* __restrict__ Sp) {
    __shared__ float osum[64][66];
    int bx = blockIdx.x;
    int xcd = bx & 7, s = bx >> 3;
    int rc = xcd * 8 + (s >> 4);   // [0,64) : 256-row r chunk
    int tb = s & 15;               // [0,16) : 64-col b chunk
    int t = threadIdx.x, wv = t >> 6, l = t & 63;
    int l15 = l & 15, q = l >> 4;
    int rbase = rc * 256 + wv * 64;
    int bbase = tb * 64;

    // zero output-staging LDS (barrier before use is the one below)
#pragma unroll
    for (int j = 0; j < 16; j++) {
        int idx = t + j * 256;
        osum[idx & 63][idx >> 6] = 0.f;
    }

    // ---- QK^T: acc[mf][nf] = C[r = rbase+mf*16+row][b = bbase+nf*16+col]
    f32x4 acc[4][4];
#pragma unroll
    for (int mf = 0; mf < 4; mf++)
#pragma unroll
        for (int nf = 0; nf < 4; nf++) acc[mf][nf] = (f32x4){0.f, 0.f, 0.f, 0.f};
    const unsigned short* Ab = WpT + (size_t)(rbase + l15) * 256 + q * 8;
    const unsigned short* Bb = x + (size_t)(bbase + l15) * 256 + q * 8;
#pragma unroll
    for (int kk = 0; kk < 8; kk++) {
        bf16x8 af[4], bf[4];
#pragma unroll
        for (int mf = 0; mf < 4; mf++) af[mf] = ld_bf8(Ab + (size_t)mf * 16 * 256 + kk * 32);
#pragma unroll
        for (int nf = 0; nf < 4; nf++) bf[nf] = ld_bf8(Bb + (size_t)nf * 16 * 256 + kk * 32);
#pragma unroll
        for (int mf = 0; mf < 4; mf++)
#pragma unroll
            for (int nf = 0; nf < 4; nf++)
                acc[mf][nf] = mfma16(af[mf], bf[nf], acc[mf][nf]);
    }

    // ---- exp(+bp), pack to bf16 pairs, per-b partial sums (bf16-quantized to
    //      match the PV numerator, as before)
    unsigned int pk[4][4][2];
    float se[4] = {0.f, 0.f, 0.f, 0.f};
#pragma unroll
    for (int mf = 0; mf < 4; mf++) {
        ushort4 b4 = *(const ushort4*)(bp + rbase + mf * 16 + q * 4);
        float bp0 = bf2f(b4.x), bp1 = bf2f(b4.y), bp2 = bf2f(b4.z), bp3 = bf2f(b4.w);
#pragma unroll
        for (int nf = 0; nf < 4; nf++) {
            unsigned short u0 = f2bf(__expf(acc[mf][nf][0] + bp0));
            unsigned short u1 = f2bf(__expf(acc[mf][nf][1] + bp1));
            unsigned short u2 = f2bf(__expf(acc[mf][nf][2] + bp2));
            unsigned short u3 = f2bf(__expf(acc[mf][nf][3] + bp3));
            pk[mf][nf][0] = (unsigned int)u0 | ((unsigned int)u1 << 16);
            pk[mf][nf][1] = (unsigned int)u2 | ((unsigned int)u3 << 16);
            se[nf] += bf2f(u0) + bf2f(u1) + bf2f(u2) + bf2f(u3);
        }
    }
#pragma unroll
    for (int nf = 0; nf < 4; nf++) {
        float sv = se[nf];
        sv += __shfl_xor(sv, 16, 64);
        sv += __shfl_xor(sv, 32, 64);
        if (q == 0) atomicAdd(&Sp[bbase + nf * 16 + l15], sv);
    }

    // ---- PV: accO[wf][nf] = C[w][b] over K = wave's 64 r (2 tiles of 32).
    // B-frag lane (q,c) needs r = 32*tt + 8q + j, b = bbase+nf*16+c:
    //   dw0,dw1 from src lane 32*(q&1)+c ; dw2,dw3 from +16 ; m-frag 2*tt+(q>>1).
    f32x4 accO[4][4];
#pragma unroll
    for (int wf = 0; wf < 4; wf++)
#pragma unroll
        for (int nf = 0; nf < 4; nf++) accO[wf][nf] = (f32x4){0.f, 0.f, 0.f, 0.f};
    int srcA = ((q & 1) << 5) | l15;
    int srcB = srcA + 16;
    int hiq = q >> 1;
#pragma unroll
    for (int tt = 0; tt < 2; tt++) {
        bf16x8 bfr[4];
#pragma unroll
        for (int nf = 0; nf < 4; nf++) {
            unsigned int w0a = (unsigned int)__shfl((int)pk[2 * tt][nf][0], srcA, 64);
            unsigned int w0b = (unsigned int)__shfl((int)pk[2 * tt + 1][nf][0], srcA, 64);
            unsigned int w1a = (unsigned int)__shfl((int)pk[2 * tt][nf][1], srcA, 64);
            unsigned int w1b = (unsigned int)__shfl((int)pk[2 * tt + 1][nf][1], srcA, 64);
            unsigned int w2a = (unsigned int)__shfl((int)pk[2 * tt][nf][0], srcB, 64);
            unsigned int w2b = (unsigned int)__shfl((int)pk[2 * tt + 1][nf][0], srcB, 64);
            unsigned int w3a = (unsigned int)__shfl((int)pk[2 * tt][nf][1], srcB, 64);
            unsigned int w3b = (unsigned int)__shfl((int)pk[2 * tt + 1][nf][1], srcB, 64);
            union { unsigned int u[4]; bf16x8 v; } cv;
            cv.u[0] = hiq ? w0b : w0a;
            cv.u[1] = hiq ? w1b : w1a;
            cv.u[2] = hiq ? w2b : w2a;
            cv.u[3] = hiq ? w3b : w3a;
            bfr[nf] = cv.v;
        }
#pragma unroll
        for (int wf = 0; wf < 4; wf++) {
            bf16x8 va = ld_bf8(mem2T + (size_t)(wf * 16 + l15) * R_ + rbase + tt * 32 + q * 8);
#pragma unroll
            for (int nf = 0; nf < 4; nf++)
                accO[wf][nf] = mfma16(va, bfr[nf], accO[wf][nf]);
        }
    }

    // ---- combine 4 waves' tiles in LDS, then one global atomic set per block
    __syncthreads();
#pragma unroll
    for (int wf = 0; wf < 4; wf++)
#pragma unroll
        for (int nf = 0; nf < 4; nf++)
#pragma unroll
            for (int reg = 0; reg < 4; reg++)
                atomicAdd(&osum[wf * 16 + q * 4 + reg][nf * 16 + l15], accO[wf][nf][reg]);
    __syncthreads();
#pragma unroll
    for (int j = 0; j < 16; j++) {
        int idx = t + j * 256;
        int w = idx & 63, b2 = idx >> 6;
        atomicAdd(&outacc[(bbase + b2) * 64 + w], osum[w][b2]);
    }
}

// ---------------- K7: out = outacc / Sp -> FP32 ----------------
__global__ __launch_bounds__(256) void k_out(const float* __restrict__ outacc,
                                             const float* __restrict__ Sp,
                                             float* __restrict__ out) {
    int idx = blockIdx.x * 256 + threadIdx.x;
    int b = idx >> 6;
    out[idx] = outacc[idx] / Sp[b];
}

extern "C" void kernel_launch(void* const* d_in, const int* in_sizes, int n_in,
                              void* d_out, int out_size, void* d_ws, size_t ws_size,
                              hipStream_t stream) {
    (void)n_in; (void)out_size;
    float* outp = (float*)d_out;

    char* ws = (char*)d_ws;
    size_t o = 0;
    unsigned short* arena = (unsigned short*)(ws + o); o += (size_t)AO_TOT * 2;
    unsigned short* WpT = (unsigned short*)(ws + o); o += (size_t)R_ * D_ * 2;
    unsigned short* E   = (unsigned short*)(ws + o); o += (size_t)B_ * R_ * 2;
    unsigned short* AT  = (unsigned short*)(ws + o); o += (size_t)B_ * R_ * 2;
    float* v            = (float*)(ws + o);          o += (size_t)B_ * 64 * 4;
    unsigned short* vb  = (unsigned short*)(ws + o); o += (size_t)B_ * 64 * 2;
    unsigned short* vpb = (unsigned short*)(ws + o); o += (size_t)80 * B_ * 2;
    float* invmn        = (float*)(ws + o);          o += (size_t)R_ * 4;
    float* bovn         = (float*)(ws + o);          o += 4096;
    float* beta         = (float*)(ws + o);          o += 4096;
    float* gamma        = (float*)(ws + o);          o += 4096;
    unsigned short* m2T = (unsigned short*)(ws + o); o += (size_t)R_ * 64 * 2;
    float* zbase  = (float*)(ws + o);
    float* S      = (float*)(ws + o);                o += 4096;
    float* T      = (float*)(ws + o);                o += 4096;
    float* Sp     = (float*)(ws + o);                o += 4096;
    float* outacc = (float*)(ws + o);                o += (size_t)B_ * 64 * 4;

    if (ws_size < o) {
        k_sentinel<<<256, 256, 0, stream>>>(outp, 1000.0f);
        return;
    }
    if (in_sizes[0] != B_ * D_ || in_sizes[7] != D_ * R_ || in_sizes[11] != R_ * W_) {
        k_sentinel<<<256, 256, 0, stream>>>(outp, 2000.0f);
        return;
    }

    k_zero<<<268, 256, 0, stream>>>(zbase);
    k_convert<<<(AO_TOT + 511) / 512, 256, 0, stream>>>(
        (const float*)d_in[0], (const float*)d_in[1], (const float*)d_in[2],
        (const float*)d_in[3], (const float*)d_in[4], (const float*)d_in[5],
        (const float*)d_in[6], (const float*)d_in[8],
        (const float*)d_in[9], (const float*)d_in[10], (const float*)d_in[11], arena);

    k_transpose_wp<<<dim3(256, 4), 256, 0, stream>>>((const float*)d_in[7], WpT);
    k_heads<<<1024, 64, 0, stream>>>(arena + AO_X, arena + AO_WV, arena + AO_BV,
                                     arena + AO_WB, arena + AO_BB, arena + AO_WG,
                                     arena + AO_BG, v, vb, bovn, beta, gamma);
    k_mn<<<64, 256, 0, stream>>>(arena + AO_MEM, invmn);
    k_sim<<<2048, 256, 0, stream>>>(vb, arena + AO_MEM, bovn, invmn, beta, E, S);
    k_conv<<<2048, 256, 0, stream>>>(E, AT, S, gamma, arena + AO_CK, arena + AO_CB, T);
    k_vp2<<<320, 256, 0, stream>>>(v, T, vpb);
    k_add<<<256, 256, 0, stream>>>(AT, vpb, arena + AO_MEM, m2T);
    k_read<<<1024, 256, 0, stream>>>(arena + AO_X, WpT, arena + AO_BP, m2T, outacc, Sp);
    k_out<<<256, 256, 0, stream>>>(outacc, Sp, outp);
}

// Round 2
// 286.413 us; speedup vs baseline: 1.2978x; 1.2978x over previous
//
#include <hip/hip_runtime.h>
#include <hip/hip_bf16.h>

#define B_ 1024
#define D_ 256
#define R_ 16384
#define W_ 64

typedef float f32x4 __attribute__((ext_vector_type(4)));
typedef __bf16 bf16x8 __attribute__((ext_vector_type(8)));

__device__ __forceinline__ float bf2f(unsigned short u) {
    union { unsigned int i; float f; } v; v.i = ((unsigned int)u) << 16; return v.f;
}
__device__ __forceinline__ unsigned short f2bf(float f) {
    union { float fv; unsigned int i; } v; v.fv = f;
    unsigned int r = v.i + 0x7FFFu + ((v.i >> 16) & 1u);
    return (unsigned short)(r >> 16);
}
__device__ __forceinline__ f32x4 mfma16(bf16x8 a, bf16x8 b, f32x4 c) {
    return __builtin_amdgcn_mfma_f32_16x16x32_bf16(a, b, c, 0, 0, 0);
}
__device__ __forceinline__ bf16x8 ld_bf8(const unsigned short* p) {
    return *(const bf16x8*)p;
}

// ---------------- arena element offsets (each segment start 16-elem aligned) ----
// Wp is not staged through the arena: k_transpose_wp reads the fp32 input
// directly and emits bf16 WpT (saves ~17 MB of convert round-trip).
#define AO_X     0
#define AO_WV    262144
#define AO_BV    278528
#define AO_WB    278592
#define AO_BB    278848
#define AO_WG    278864
#define AO_BG    279120
#define AO_BP    279136
#define AO_CK    295520
#define AO_CB    295536
#define AO_MEM   295552
#define AO_TOT   1344128

__global__ __launch_bounds__(256) void k_sentinel(float* __restrict__ out, float val) {
    out[blockIdx.x * 256 + threadIdx.x] = val;
}

__global__ __launch_bounds__(256) void k_zero(float* __restrict__ z) {
    z[blockIdx.x * 256 + threadIdx.x] = 0.f;
}

// ---------------- K-convert: fp32 inputs -> bf16 arena (no Wp) ----------------
__global__ __launch_bounds__(256) void k_convert(
        const float* x, const float* Wv, const float* bv, const float* Wb, const float* bb,
        const float* Wg, const float* bg, const float* bp,
        const float* ck, const float* cb, const float* mem,
        unsigned short* __restrict__ dst) {
    int base = blockIdx.x * 512 + threadIdx.x;
#pragma unroll
    for (int h = 0; h < 2; h++) {
        int idx = base + h * 256;
        if (idx >= AO_TOT) continue;
        const float* p; int st; int n;
        if      (idx >= AO_MEM) { p = mem; st = AO_MEM; n = R_ * W_; }
        else if (idx >= AO_CB)  { p = cb;  st = AO_CB;  n = 1; }
        else if (idx >= AO_CK)  { p = ck;  st = AO_CK;  n = 3; }
        else if (idx >= AO_BP)  { p = bp;  st = AO_BP;  n = R_; }
        else if (idx >= AO_BG)  { p = bg;  st = AO_BG;  n = 1; }
        else if (idx >= AO_WG)  { p = Wg;  st = AO_WG;  n = D_; }
        else if (idx >= AO_BB)  { p = bb;  st = AO_BB;  n = 1; }
        else if (idx >= AO_WB)  { p = Wb;  st = AO_WB;  n = D_; }
        else if (idx >= AO_BV)  { p = bv;  st = AO_BV;  n = W_; }
        else if (idx >= AO_WV)  { p = Wv;  st = AO_WV;  n = D_ * W_; }
        else                    { p = x;   st = AO_X;   n = B_ * D_; }
        int local = idx - st;
        dst[idx] = (local < n) ? f2bf(p[local]) : (unsigned short)0;
    }
}

// ---------------- K0: transpose+convert Wp fp32 [D,R] -> WpT bf16 [R,D] --------
__global__ __launch_bounds__(256) void k_transpose_wp(const float* __restrict__ Wp,
                                                      unsigned short* __restrict__ WpT) {
    __shared__ unsigned short tile[64][66];
    int r0 = blockIdx.x * 64, d0 = blockIdx.y * 64;
    int t = threadIdx.x, lane = t & 63, wv = t >> 6;
#pragma unroll
    for (int i = 0; i < 16; i++) {
        int dl = wv + 4 * i;
        tile[dl][lane] = f2bf(Wp[(size_t)(d0 + dl) * R_ + r0 + lane]);
    }
    __syncthreads();
#pragma unroll
    for (int i = 0; i < 16; i++) {
        int rl = wv + 4 * i;
        WpT[(size_t)(r0 + rl) * D_ + d0 + lane] = tile[lane][rl];
    }
}

// ---------------- K1: controller heads: v, vb, bovn=beta/vn, beta, gamma ----------
__global__ __launch_bounds__(64) void k_heads(const unsigned short* __restrict__ x,
        const unsigned short* __restrict__ Wv, const unsigned short* __restrict__ bv,
        const unsigned short* __restrict__ Wb, const unsigned short* __restrict__ bb,
        const unsigned short* __restrict__ Wg, const unsigned short* __restrict__ bg,
        float* __restrict__ v, unsigned short* __restrict__ vb,
        float* __restrict__ bovn, float* __restrict__ beta, float* __restrict__ gamma) {
    __shared__ float sx[256];
    int b = blockIdx.x, lane = threadIdx.x;
#pragma unroll
    for (int j = 0; j < 4; j++) sx[lane + 64 * j] = bf2f(x[b * 256 + lane + 64 * j]);
    __syncthreads();
    float acc = 0.f;
#pragma unroll 8
    for (int d = 0; d < 256; d++) acc += sx[d] * bf2f(Wv[d * 64 + lane]);
    acc += bf2f(bv[lane]);
    v[b * 64 + lane] = acc;
    vb[b * 64 + lane] = f2bf(acc);
    float sq = acc * acc;
#pragma unroll
    for (int d = 32; d >= 1; d >>= 1) sq += __shfl_xor(sq, d, 64);
    float pb = 0.f, pg = 0.f;
#pragma unroll
    for (int j = 0; j < 4; j++) {
        float xv = sx[lane + 64 * j];
        pb += xv * bf2f(Wb[lane + 64 * j]);
        pg += xv * bf2f(Wg[lane + 64 * j]);
    }
#pragma unroll
    for (int d = 32; d >= 1; d >>= 1) { pb += __shfl_xor(pb, d, 64); pg += __shfl_xor(pg, d, 64); }
    if (lane == 0) {
        float vn = sqrtf(sq);
        float zb = pb + bf2f(bb[0]);
        float zg = pg + bf2f(bg[0]);
        float be = (zb > 20.f) ? zb : log1pf(__expf(zb));
        beta[b]  = be;
        bovn[b]  = be / (vn + 1e-16f);
        gamma[b] = 1.f + ((zg > 20.f) ? zg : log1pf(__expf(zg)));
    }
}

// ---------------- K2: mem row inverse norms ----------------
__global__ __launch_bounds__(256) void k_mn(const unsigned short* __restrict__ mem, float* __restrict__ invmn) {
    int lane = threadIdx.x & 63;
    int gw = blockIdx.x * 4 + (threadIdx.x >> 6);
    for (int row = gw; row < R_; row += 256) {
        float m = bf2f(mem[row * 64 + lane]);
        float s = m * m;
#pragma unroll
        for (int d = 32; d >= 1; d >>= 1) s += __shfl_xor(s, d, 64);
        if (lane == 0) invmn[row] = 1.0f / (sqrtf(s) + 1e-16f);
    }
}

// ---------------- K3: sim MFMA -> E = exp(acc*bovn*invmn - beta), S[b] ----------
__global__ __launch_bounds__(256, 8) void k_sim(const unsigned short* __restrict__ vb,
        const unsigned short* __restrict__ mem,
        const float* __restrict__ bovn, const float* __restrict__ invmn,
        const float* __restrict__ beta,
        unsigned short* __restrict__ E, float* __restrict__ S) {
    __shared__ unsigned short etile[64][132];
    __shared__ float sred[4][64];
    int bx = blockIdx.x;
    int rc = bx & 127, tb = bx >> 7;
    int t = threadIdx.x, wv = t >> 6, l = t & 63;
    int lane15 = l & 15, quad = l >> 4;
    int rr0 = rc * 128 + wv * 32 + lane15;
    bf16x8 bm[2][2];
    float im[2];
#pragma unroll
    for (int nt = 0; nt < 2; nt++) {
        int rr = rr0 + nt * 16;
        bm[nt][0] = ld_bf8(mem + rr * 64 + quad * 8);
        bm[nt][1] = ld_bf8(mem + rr * 64 + 32 + quad * 8);
        im[nt] = invmn[rr];
    }
    bf16x8 afr[4][2];
    float bvl[4][4], bel[4][4];
#pragma unroll
    for (int m = 0; m < 4; m++) {
        int brow = tb * 64 + m * 16 + lane15;
        afr[m][0] = ld_bf8(vb + brow * 64 + quad * 8);
        afr[m][1] = ld_bf8(vb + brow * 64 + 32 + quad * 8);
#pragma unroll
        for (int reg = 0; reg < 4; reg++) {
            int b2 = tb * 64 + m * 16 + quad * 4 + reg;
            bvl[m][reg] = bovn[b2];
            bel[m][reg] = beta[b2];
        }
    }
    float sp[4][4];
#pragma unroll
    for (int m = 0; m < 4; m++)
#pragma unroll
        for (int r = 0; r < 4; r++) sp[m][r] = 0.f;

#pragma unroll
    for (int nt = 0; nt < 2; nt++) {
        int rl = wv * 32 + nt * 16 + lane15;
#pragma unroll
        for (int m = 0; m < 4; m++) {
            f32x4 acc = (f32x4){0.f, 0.f, 0.f, 0.f};
            acc = mfma16(afr[m][0], bm[nt][0], acc);
            acc = mfma16(afr[m][1], bm[nt][1], acc);
#pragma unroll
            for (int reg = 0; reg < 4; reg++) {
                float e = __expf(acc[reg] * (bvl[m][reg] * im[nt]) - bel[m][reg]);
                sp[m][reg] += e;
                etile[m * 16 + quad * 4 + reg][rl] = f2bf(e);
            }
        }
    }
#pragma unroll
    for (int m = 0; m < 4; m++)
#pragma unroll
        for (int reg = 0; reg < 4; reg++) {
            float s = sp[m][reg];
            s += __shfl_xor(s, 1, 64); s += __shfl_xor(s, 2, 64);
            s += __shfl_xor(s, 4, 64); s += __shfl_xor(s, 8, 64);
            if (lane15 == 0) sred[wv][m * 16 + quad * 4 + reg] = s;
        }
    __syncthreads();
#pragma unroll
    for (int j = 0; j < 4; j++) {
        int idx8 = t + j * 256;
        int row = idx8 >> 4;
        int c8 = (idx8 & 15) * 8;
        *(bf16x8*)(E + (size_t)(tb * 64 + row) * R_ + rc * 128 + c8) =
            *(const bf16x8*)&etile[row][c8];
    }
    if (t < 64)
        atomicAdd(&S[tb * 64 + t], sred[0][t] + sred[1][t] + sred[2][t] + sred[3][t]);
}

// ---------------- K4: conv+pow -> AT [R,B] (transposed!), T[b] ----------------
__global__ __launch_bounds__(256) void k_conv(const unsigned short* __restrict__ E,
        unsigned short* __restrict__ AT,
        const float* __restrict__ S, const float* __restrict__ gamma,
        const unsigned short* __restrict__ conv_k, const unsigned short* __restrict__ conv_b,
        float* __restrict__ T) {
    __shared__ unsigned short ein[64][132];
    __shared__ unsigned short hl[64], hr[64];
    __shared__ unsigned short aout[128][68];
    __shared__ float red[64], sS[64], sG[64];
    float k0 = bf2f(conv_k[0]), k1 = bf2f(conv_k[1]), k2 = bf2f(conv_k[2]);
    float cb = bf2f(conv_b[0]);
    int b0 = (blockIdx.x >> 7) * 64;
    int r0 = (blockIdx.x & 127) * 128;
    int t = threadIdx.x;
    if (t < 64) {
        red[t] = 0.f;
        sS[t] = 1.0f / S[b0 + t];
        sG[t] = gamma[b0 + t];
        hl[t] = (r0 > 0) ? E[(b0 + t) * R_ + r0 - 1] : (unsigned short)0;
    } else if (t < 128) {
        int tb = t - 64;
        hr[tb] = (r0 + 128 < R_) ? E[(b0 + tb) * R_ + r0 + 128] : (unsigned short)0;
    }
#pragma unroll
    for (int j = 0; j < 8; j++) {
        int idx4 = t + j * 256;
        int row = idx4 >> 5, c4 = (idx4 & 31) * 4;
        *(ushort4*)&ein[row][c4] = *(const ushort4*)(E + (b0 + row) * R_ + r0 + c4);
    }
    __syncthreads();
#pragma unroll 4
    for (int j = 0; j < 32; j++) {
        int idx = t + j * 256;
        int row = idx >> 7, col = idx & 127;
        float el = (col == 0)   ? bf2f(hl[row]) : bf2f(ein[row][col - 1]);
        float ec = bf2f(ein[row][col]);
        float er = (col == 127) ? bf2f(hr[row]) : bf2f(ein[row][col + 1]);
        float wc = (k0 * el + k1 * ec + k2 * er) * sS[row] + cb;
        wc = fmaxf(wc, 1e-30f);
        float au = __expf(sG[row] * __logf(wc));
        aout[col][row] = f2bf(au);
        float s = au;
#pragma unroll
        for (int d = 32; d >= 1; d >>= 1) s += __shfl_xor(s, d, 64);
        if ((t & 63) == 0) atomicAdd(&red[row], s);
    }
    __syncthreads();
    if (t < 64) atomicAdd(&T[b0 + t], red[t]);
#pragma unroll
    for (int j = 0; j < 8; j++) {
        int idx4 = t + j * 256;
        int rrow = idx4 >> 4, c4 = (idx4 & 15) * 4;
        *(ushort4*)(AT + (size_t)(r0 + rrow) * B_ + b0 + c4) = *(ushort4*)&aout[rrow][c4];
    }
}

// ---------------- K4b: build vp' [80,1024] bf16 ----------------
__global__ __launch_bounds__(256) void k_vp2(const float* __restrict__ v, const float* __restrict__ T,
                                             unsigned short* __restrict__ vpb) {
    int idx = blockIdx.x * 256 + threadIdx.x;
    int m = idx >> 10, b = idx & 1023;
    float s = 1.0f / ((T[b] + (float)R_ * 1e-16f) * (float)B_);
    float val = (m < 64) ? v[b * 64 + m] * s : ((m == 64) ? s : 0.f);
    vpb[idx] = f2bf(val);
}

// ---------------- K5: MFMA GEMM mem2T = mem*(1-er) + vp'^ AT ----------------
__global__ __launch_bounds__(256) void k_add(const unsigned short* __restrict__ AT,
        const unsigned short* __restrict__ vpb,
        const unsigned short* __restrict__ memb, unsigned short* __restrict__ mem2T) {
    __shared__ unsigned short smem[64][68];
    __shared__ unsigned short sm2[64][68];
    int r0 = blockIdx.x * 64;
    int t = threadIdx.x, wv = t >> 6, l = t & 63;
    int lane15 = l & 15, quad = l >> 4;
#pragma unroll
    for (int j = 0; j < 4; j++) {
        int idx4 = t + j * 256;
        int rl = idx4 >> 4, w4 = (idx4 & 15) * 4;
        *(ushort4*)&smem[rl][w4] = *(const ushort4*)(memb + (r0 + rl) * 64 + w4);
    }
    __syncthreads();

    const unsigned short* Brow = AT + (size_t)(r0 + wv * 16 + lane15) * B_ + quad * 8;
    const unsigned short* A0 = vpb + (0 * 16 + lane15) * B_ + quad * 8;
    const unsigned short* A1 = vpb + (1 * 16 + lane15) * B_ + quad * 8;
    const unsigned short* A2 = vpb + (2 * 16 + lane15) * B_ + quad * 8;
    const unsigned short* A3 = vpb + (3 * 16 + lane15) * B_ + quad * 8;
    const unsigned short* A4 = vpb + (4 * 16 + lane15) * B_ + quad * 8;
    f32x4 acc0 = {0,0,0,0}, acc1 = {0,0,0,0}, acc2 = {0,0,0,0}, acc3 = {0,0,0,0}, acc4 = {0,0,0,0};
#pragma unroll 4
    for (int k0 = 0; k0 < B_; k0 += 32) {
        bf16x8 bf = ld_bf8(Brow + k0);
        acc0 = mfma16(ld_bf8(A0 + k0), bf, acc0);
        acc1 = mfma16(ld_bf8(A1 + k0), bf, acc1);
        acc2 = mfma16(ld_bf8(A2 + k0), bf, acc2);
        acc3 = mfma16(ld_bf8(A3 + k0), bf, acc3);
        acc4 = mfma16(ld_bf8(A4 + k0), bf, acc4);
    }
    float er = __shfl(acc4[0], l & 15, 64);
    float ome = 1.f - er;
    f32x4 accs[4] = {acc0, acc1, acc2, acc3};
#pragma unroll
    for (int mt = 0; mt < 4; mt++) {
#pragma unroll
        for (int reg = 0; reg < 4; reg++) {
            int w = mt * 16 + quad * 4 + reg;
            int rl = wv * 16 + lane15;
            float m2 = bf2f(smem[rl][w]) * ome + accs[mt][reg];
            sm2[w][rl] = f2bf(m2);
        }
    }
    __syncthreads();
#pragma unroll
    for (int j = 0; j < 4; j++) {
        int idx4 = t + j * 256;
        int w = idx4 >> 4, r4 = (idx4 & 15) * 4;
        *(ushort4*)(mem2T + (size_t)w * R_ + r0 + r4) = *(ushort4*)&sm2[w][r4];
    }
}

// ---------------- K6: flash read head (R0 structure + XCD-bijective swizzle)
// 1024 blocks. HW dispatches block bx to XCD bx%8, so map: xcd = bx&7,
// grp = bx>>3; rc = xcd*8 + (grp>>4) in [0,64), tb = grp&15. All 16 blocks
// sharing one 128KB WpT slice (same rc) land on ONE XCD -> slice is fetched
// from HBM once and staging loads hit that XCD's L2 (~200cyc vs ~900cyc HBM),
// shortening each phase's vmcnt-drain critical path.
// LDS: bstage 32x264 + etile 64x264 = 50,688 B (3 blocks/CU).
// Staging loads register-double-buffered: phase ss+1's loads issued during ss.
__global__ __launch_bounds__(256) void k_read(const unsigned short* __restrict__ x,
        const unsigned short* __restrict__ WpT, const unsigned short* __restrict__ bp,
        const unsigned short* __restrict__ mem2T,
        float* __restrict__ outacc, float* __restrict__ Sp) {
    __shared__ unsigned short bstage[32 * 264];
    __shared__ unsigned short etile[64 * 264];
    int bx = blockIdx.x;
    int xcd = bx & 7, grp = bx >> 3;
    int rc = xcd * 8 + (grp >> 4), tb = grp & 15;
    int t = threadIdx.x, wv = t >> 6, l = t & 63;
    int lane15 = l & 15, quad = l >> 4;
    int brow = tb * 64 + wv * 16 + lane15;
    bf16x8 afr[8];
#pragma unroll
    for (int kk = 0; kk < 8; kk++)
        afr[kk] = ld_bf8(x + brow * 256 + kk * 32 + quad * 8);
    f32x4 accO[4];
#pragma unroll
    for (int nt = 0; nt < 4; nt++) accO[nt] = (f32x4){0.f, 0.f, 0.f, 0.f};
    float sp[4] = {0.f, 0.f, 0.f, 0.f};

    int srow = t >> 3, scg = (t & 7) * 8;
    bf16x8 pf[4];
    {   // prefetch phase 0
        const unsigned short* src = WpT + (size_t)(rc * 256 + srow) * 256 + scg;
#pragma unroll
        for (int j = 0; j < 4; j++) pf[j] = *(const bf16x8*)(src + 64 * j);
    }
    for (int ss = 0; ss < 8; ss++) {
        {   // commit prefetched rows to LDS, then issue next phase's loads
            unsigned short* dst = bstage + srow * 264 + scg;
#pragma unroll
            for (int j = 0; j < 4; j++) *(bf16x8*)(dst + 64 * j) = pf[j];
        }
        if (ss < 7) {
            const unsigned short* src = WpT
                + (size_t)(rc * 256 + (ss + 1) * 32 + srow) * 256 + scg;
#pragma unroll
            for (int j = 0; j < 4; j++) pf[j] = *(const bf16x8*)(src + 64 * j);
        }
        __syncthreads();
        int rbase = rc * 256 + ss * 32;
#pragma unroll
        for (int nt = 0; nt < 2; nt++) {
            f32x4 acc = (f32x4){0.f, 0.f, 0.f, 0.f};
            const unsigned short* bb = bstage + (nt * 16 + lane15) * 264 + quad * 8;
#pragma unroll
            for (int kk = 0; kk < 8; kk++) {
                bf16x8 bfr = *(const bf16x8*)(bb + kk * 32);
                acc = mfma16(afr[kk], bfr, acc);
            }
            int rr = rbase + nt * 16 + lane15;
            float bpv = bf2f(bp[rr]);
            int rloc = ss * 32 + nt * 16 + lane15;
#pragma unroll
            for (int reg = 0; reg < 4; reg++) {
                float e = __expf(acc[reg] + bpv);
                unsigned short ue = f2bf(e);
                sp[reg] += bf2f(ue);   // match PV numerator quantization
                etile[(wv * 16 + quad * 4 + reg) * 264 + rloc] = ue;
            }
        }
        __syncthreads();
    }
#pragma unroll
    for (int nt = 0; nt < 4; nt++) {
        const unsigned short* vbase = mem2T + (size_t)(nt * 16 + lane15) * R_
                                      + rc * 256 + quad * 8;
        const unsigned short* abase = etile + (wv * 16 + lane15) * 264 + quad * 8;
#pragma unroll
        for (int kk = 0; kk < 8; kk++) {
            bf16x8 ea = *(const bf16x8*)(abase + kk * 32);
            bf16x8 vv = *(const bf16x8*)(vbase + kk * 32);
            accO[nt] = mfma16(ea, vv, accO[nt]);
        }
    }
#pragma unroll
    for (int nt = 0; nt < 4; nt++) {
        int wcol = nt * 16 + lane15;
#pragma unroll
        for (int reg = 0; reg < 4; reg++) {
            int b2 = tb * 64 + wv * 16 + quad * 4 + reg;
            atomicAdd(&outacc[b2 * 64 + wcol], accO[nt][reg]);
        }
    }
#pragma unroll
    for (int reg = 0; reg < 4; reg++) {
        float s = sp[reg];
        s += __shfl_xor(s, 1, 64); s += __shfl_xor(s, 2, 64);
        s += __shfl_xor(s, 4, 64); s += __shfl_xor(s, 8, 64);
        if (lane15 == 0) {
            int b2 = tb * 64 + wv * 16 + quad * 4 + reg;
            atomicAdd(&Sp[b2], s);
        }
    }
}

// ---------------- K7: out = outacc / Sp -> FP32 ----------------
__global__ __launch_bounds__(256) void k_out(const float* __restrict__ outacc,
                                             const float* __restrict__ Sp,
                                             float* __restrict__ out) {
    int idx = blockIdx.x * 256 + threadIdx.x;
    int b = idx >> 6;
    out[idx] = outacc[idx] / Sp[b];
}

extern "C" void kernel_launch(void* const* d_in, const int* in_sizes, int n_in,
                              void* d_out, int out_size, void* d_ws, size_t ws_size,
                              hipStream_t stream) {
    (void)n_in; (void)out_size;
    float* outp = (float*)d_out;

    char* ws = (char*)d_ws;
    size_t o = 0;
    unsigned short* arena = (unsigned short*)(ws + o); o += (size_t)AO_TOT * 2;
    unsigned short* WpT = (unsigned short*)(ws + o); o += (size_t)R_ * D_ * 2;
    unsigned short* E   = (unsigned short*)(ws + o); o += (size_t)B_ * R_ * 2;
    unsigned short* AT  = (unsigned short*)(ws + o); o += (size_t)B_ * R_ * 2;
    float* v            = (float*)(ws + o);          o += (size_t)B_ * 64 * 4;
    unsigned short* vb  = (unsigned short*)(ws + o); o += (size_t)B_ * 64 * 2;
    unsigned short* vpb = (unsigned short*)(ws + o); o += (size_t)80 * B_ * 2;
    float* invmn        = (float*)(ws + o);          o += (size_t)R_ * 4;
    float* bovn         = (float*)(ws + o);          o += 4096;
    float* beta         = (float*)(ws + o);          o += 4096;
    float* gamma        = (float*)(ws + o);          o += 4096;
    unsigned short* m2T = (unsigned short*)(ws + o); o += (size_t)R_ * 64 * 2;
    float* zbase  = (float*)(ws + o);
    float* S      = (float*)(ws + o);                o += 4096;
    float* T      = (float*)(ws + o);                o += 4096;
    float* Sp     = (float*)(ws + o);                o += 4096;
    float* outacc = (float*)(ws + o);                o += (size_t)B_ * 64 * 4;

    if (ws_size < o) {
        k_sentinel<<<256, 256, 0, stream>>>(outp, 1000.0f);
        return;
    }
    if (in_sizes[0] != B_ * D_ || in_sizes[7] != D_ * R_ || in_sizes[11] != R_ * W_) {
        k_sentinel<<<256, 256, 0, stream>>>(outp, 2000.0f);
        return;
    }

    k_zero<<<268, 256, 0, stream>>>(zbase);
    k_convert<<<(AO_TOT + 511) / 512, 256, 0, stream>>>(
        (const float*)d_in[0], (const float*)d_in[1], (const float*)d_in[2],
        (const float*)d_in[3], (const float*)d_in[4], (const float*)d_in[5],
        (const float*)d_in[6], (const float*)d_in[8],
        (const float*)d_in[9], (const float*)d_in[10], (const float*)d_in[11], arena);

    k_transpose_wp<<<dim3(256, 4), 256, 0, stream>>>((const float*)d_in[7], WpT);
    k_heads<<<1024, 64, 0, stream>>>(arena + AO_X, arena + AO_WV, arena + AO_BV,
                                     arena + AO_WB, arena + AO_BB, arena + AO_WG,
                                     arena + AO_BG, v, vb, bovn, beta, gamma);
    k_mn<<<64, 256, 0, stream>>>(arena + AO_MEM, invmn);
    k_sim<<<2048, 256, 0, stream>>>(vb, arena + AO_MEM, bovn, invmn, beta, E, S);
    k_conv<<<2048, 256, 0, stream>>>(E, AT, S, gamma, arena + AO_CK, arena + AO_CB, T);
    k_vp2<<<320, 256, 0, stream>>>(v, T, vpb);
    k_add<<<256, 256, 0, stream>>>(AT, vpb, arena + AO_MEM, m2T);
    k_read<<<1024, 256, 0, stream>>>(arena + AO_X, WpT, arena + AO_BP, m2T, outacc, Sp);
    k_out<<<256, 256, 0, stream>>>(outacc, Sp, outp);
}

// Round 4
// 269.398 us; speedup vs baseline: 1.3798x; 1.0632x over previous
//
#include <hip/hip_runtime.h>
#include <hip/hip_bf16.h>

#define B_ 1024
#define D_ 256
#define R_ 16384
#define W_ 64

typedef float f32x4 __attribute__((ext_vector_type(4)));
typedef __bf16 bf16x8 __attribute__((ext_vector_type(8)));

__device__ __forceinline__ float bf2f(unsigned short u) {
    union { unsigned int i; float f; } v; v.i = ((unsigned int)u) << 16; return v.f;
}
__device__ __forceinline__ unsigned short f2bf(float f) {
    union { float fv; unsigned int i; } v; v.fv = f;
    unsigned int r = v.i + 0x7FFFu + ((v.i >> 16) & 1u);
    return (unsigned short)(r >> 16);
}
__device__ __forceinline__ f32x4 mfma16(bf16x8 a, bf16x8 b, f32x4 c) {
    return __builtin_amdgcn_mfma_f32_16x16x32_bf16(a, b, c, 0, 0, 0);
}
__device__ __forceinline__ bf16x8 ld_bf8(const unsigned short* p) {
    return *(const bf16x8*)p;
}

// ---------------- arena element offsets (each segment start 16-elem aligned) ----
// Wp is not staged through the arena: k_transpose_wp reads the fp32 input
// directly and emits bf16 WpT (saves ~17 MB of convert round-trip).
#define AO_X     0
#define AO_WV    262144
#define AO_BV    278528
#define AO_WB    278592
#define AO_BB    278848
#define AO_WG    278864
#define AO_BG    279120
#define AO_BP    279136
#define AO_CK    295520
#define AO_CB    295536
#define AO_MEM   295552
#define AO_TOT   1344128

__global__ __launch_bounds__(256) void k_sentinel(float* __restrict__ out, float val) {
    out[blockIdx.x * 256 + threadIdx.x] = val;
}

__global__ __launch_bounds__(256) void k_zero(float* __restrict__ z) {
    z[blockIdx.x * 256 + threadIdx.x] = 0.f;
}

// ---------------- K-convert: fp32 inputs -> bf16 arena (no Wp) ----------------
__global__ __launch_bounds__(256) void k_convert(
        const float* x, const float* Wv, const float* bv, const float* Wb, const float* bb,
        const float* Wg, const float* bg, const float* bp,
        const float* ck, const float* cb, const float* mem,
        unsigned short* __restrict__ dst) {
    int base = blockIdx.x * 512 + threadIdx.x;
#pragma unroll
    for (int h = 0; h < 2; h++) {
        int idx = base + h * 256;
        if (idx >= AO_TOT) continue;
        const float* p; int st; int n;
        if      (idx >= AO_MEM) { p = mem; st = AO_MEM; n = R_ * W_; }
        else if (idx >= AO_CB)  { p = cb;  st = AO_CB;  n = 1; }
        else if (idx >= AO_CK)  { p = ck;  st = AO_CK;  n = 3; }
        else if (idx >= AO_BP)  { p = bp;  st = AO_BP;  n = R_; }
        else if (idx >= AO_BG)  { p = bg;  st = AO_BG;  n = 1; }
        else if (idx >= AO_WG)  { p = Wg;  st = AO_WG;  n = D_; }
        else if (idx >= AO_BB)  { p = bb;  st = AO_BB;  n = 1; }
        else if (idx >= AO_WB)  { p = Wb;  st = AO_WB;  n = D_; }
        else if (idx >= AO_BV)  { p = bv;  st = AO_BV;  n = W_; }
        else if (idx >= AO_WV)  { p = Wv;  st = AO_WV;  n = D_ * W_; }
        else                    { p = x;   st = AO_X;   n = B_ * D_; }
        int local = idx - st;
        dst[idx] = (local < n) ? f2bf(p[local]) : (unsigned short)0;
    }
}

// ---------------- K0: transpose+convert Wp fp32 [D,R] -> WpT bf16 [R,D] --------
__global__ __launch_bounds__(256) void k_transpose_wp(const float* __restrict__ Wp,
                                                      unsigned short* __restrict__ WpT) {
    __shared__ unsigned short tile[64][66];
    int r0 = blockIdx.x * 64, d0 = blockIdx.y * 64;
    int t = threadIdx.x, lane = t & 63, wv = t >> 6;
#pragma unroll
    for (int i = 0; i < 16; i++) {
        int dl = wv + 4 * i;
        tile[dl][lane] = f2bf(Wp[(size_t)(d0 + dl) * R_ + r0 + lane]);
    }
    __syncthreads();
#pragma unroll
    for (int i = 0; i < 16; i++) {
        int rl = wv + 4 * i;
        WpT[(size_t)(r0 + rl) * D_ + d0 + lane] = tile[lane][rl];
    }
}

// ---------------- K1: controller heads: v, vb, bovn=beta/vn, beta, gamma ----------
__global__ __launch_bounds__(64) void k_heads(const unsigned short* __restrict__ x,
        const unsigned short* __restrict__ Wv, const unsigned short* __restrict__ bv,
        const unsigned short* __restrict__ Wb, const unsigned short* __restrict__ bb,
        const unsigned short* __restrict__ Wg, const unsigned short* __restrict__ bg,
        float* __restrict__ v, unsigned short* __restrict__ vb,
        float* __restrict__ bovn, float* __restrict__ beta, float* __restrict__ gamma) {
    __shared__ float sx[256];
    int b = blockIdx.x, lane = threadIdx.x;
#pragma unroll
    for (int j = 0; j < 4; j++) sx[lane + 64 * j] = bf2f(x[b * 256 + lane + 64 * j]);
    __syncthreads();
    float acc = 0.f;
#pragma unroll 8
    for (int d = 0; d < 256; d++) acc += sx[d] * bf2f(Wv[d * 64 + lane]);
    acc += bf2f(bv[lane]);
    v[b * 64 + lane] = acc;
    vb[b * 64 + lane] = f2bf(acc);
    float sq = acc * acc;
#pragma unroll
    for (int d = 32; d >= 1; d >>= 1) sq += __shfl_xor(sq, d, 64);
    float pb = 0.f, pg = 0.f;
#pragma unroll
    for (int j = 0; j < 4; j++) {
        float xv = sx[lane + 64 * j];
        pb += xv * bf2f(Wb[lane + 64 * j]);
        pg += xv * bf2f(Wg[lane + 64 * j]);
    }
#pragma unroll
    for (int d = 32; d >= 1; d >>= 1) { pb += __shfl_xor(pb, d, 64); pg += __shfl_xor(pg, d, 64); }
    if (lane == 0) {
        float vn = sqrtf(sq);
        float zb = pb + bf2f(bb[0]);
        float zg = pg + bf2f(bg[0]);
        float be = (zb > 20.f) ? zb : log1pf(__expf(zb));
        beta[b]  = be;
        bovn[b]  = be / (vn + 1e-16f);
        gamma[b] = 1.f + ((zg > 20.f) ? zg : log1pf(__expf(zg)));
    }
}

// ---------------- K2: mem row inverse norms ----------------
__global__ __launch_bounds__(256) void k_mn(const unsigned short* __restrict__ mem, float* __restrict__ invmn) {
    int lane = threadIdx.x & 63;
    int gw = blockIdx.x * 4 + (threadIdx.x >> 6);
    for (int row = gw; row < R_; row += 256) {
        float m = bf2f(mem[row * 64 + lane]);
        float s = m * m;
#pragma unroll
        for (int d = 32; d >= 1; d >>= 1) s += __shfl_xor(s, d, 64);
        if (lane == 0) invmn[row] = 1.0f / (sqrtf(s) + 1e-16f);
    }
}

// ---------------- K3: sim MFMA -> E = exp(acc*bovn*invmn - beta), S[b] ----------
__global__ __launch_bounds__(256, 8) void k_sim(const unsigned short* __restrict__ vb,
        const unsigned short* __restrict__ mem,
        const float* __restrict__ bovn, const float* __restrict__ invmn,
        const float* __restrict__ beta,
        unsigned short* __restrict__ E, float* __restrict__ S) {
    __shared__ unsigned short etile[64][132];
    __shared__ float sred[4][64];
    int bx = blockIdx.x;
    int rc = bx & 127, tb = bx >> 7;
    int t = threadIdx.x, wv = t >> 6, l = t & 63;
    int lane15 = l & 15, quad = l >> 4;
    int rr0 = rc * 128 + wv * 32 + lane15;
    bf16x8 bm[2][2];
    float im[2];
#pragma unroll
    for (int nt = 0; nt < 2; nt++) {
        int rr = rr0 + nt * 16;
        bm[nt][0] = ld_bf8(mem + rr * 64 + quad * 8);
        bm[nt][1] = ld_bf8(mem + rr * 64 + 32 + quad * 8);
        im[nt] = invmn[rr];
    }
    bf16x8 afr[4][2];
    float bvl[4][4], bel[4][4];
#pragma unroll
    for (int m = 0; m < 4; m++) {
        int brow = tb * 64 + m * 16 + lane15;
        afr[m][0] = ld_bf8(vb + brow * 64 + quad * 8);
        afr[m][1] = ld_bf8(vb + brow * 64 + 32 + quad * 8);
#pragma unroll
        for (int reg = 0; reg < 4; reg++) {
            int b2 = tb * 64 + m * 16 + quad * 4 + reg;
            bvl[m][reg] = bovn[b2];
            bel[m][reg] = beta[b2];
        }
    }
    float sp[4][4];
#pragma unroll
    for (int m = 0; m < 4; m++)
#pragma unroll
        for (int r = 0; r < 4; r++) sp[m][r] = 0.f;

#pragma unroll
    for (int nt = 0; nt < 2; nt++) {
        int rl = wv * 32 + nt * 16 + lane15;
#pragma unroll
        for (int m = 0; m < 4; m++) {
            f32x4 acc = (f32x4){0.f, 0.f, 0.f, 0.f};
            acc = mfma16(afr[m][0], bm[nt][0], acc);
            acc = mfma16(afr[m][1], bm[nt][1], acc);
#pragma unroll
            for (int reg = 0; reg < 4; reg++) {
                float e = __expf(acc[reg] * (bvl[m][reg] * im[nt]) - bel[m][reg]);
                sp[m][reg] += e;
                etile[m * 16 + quad * 4 + reg][rl] = f2bf(e);
            }
        }
    }
#pragma unroll
    for (int m = 0; m < 4; m++)
#pragma unroll
        for (int reg = 0; reg < 4; reg++) {
            float s = sp[m][reg];
            s += __shfl_xor(s, 1, 64); s += __shfl_xor(s, 2, 64);
            s += __shfl_xor(s, 4, 64); s += __shfl_xor(s, 8, 64);
            if (lane15 == 0) sred[wv][m * 16 + quad * 4 + reg] = s;
        }
    __syncthreads();
#pragma unroll
    for (int j = 0; j < 4; j++) {
        int idx8 = t + j * 256;
        int row = idx8 >> 4;
        int c8 = (idx8 & 15) * 8;
        *(bf16x8*)(E + (size_t)(tb * 64 + row) * R_ + rc * 128 + c8) =
            *(const bf16x8*)&etile[row][c8];
    }
    if (t < 64)
        atomicAdd(&S[tb * 64 + t], sred[0][t] + sred[1][t] + sred[2][t] + sred[3][t]);
}

// ---------------- K4: conv+pow -> AT [R,B] (transposed!), T[b] ----------------
// Thread t owns row b = t>>2 and a contiguous run of 32 r's (base = (t&3)*32).
// Rolling el/ec/er window -> 1 new LDS read per element, no boundary ternaries
// (halo staged in-tile: col 128 = right halo, col 130 = left halo).
// T-reduction: per-thread scalar accumulator + 2 shfl_xor across the 4 threads
// sharing a b (was: 6 shuffles PER ELEMENT + LDS atomics).
// pow via __builtin_amdgcn_exp2f(g*log2(wc)) -- v_exp_f32 IS 2^x on gfx950.
__global__ __launch_bounds__(256) void k_conv(const unsigned short* __restrict__ E,
        unsigned short* __restrict__ AT,
        const float* __restrict__ S, const float* __restrict__ gamma,
        const unsigned short* __restrict__ conv_k, const unsigned short* __restrict__ conv_b,
        float* __restrict__ T) {
    __shared__ unsigned short ein[64][132];   // cols 0..127: r0..r0+127; 128: right halo; 130: left halo
    __shared__ unsigned short aout[128][68];
    float k0 = bf2f(conv_k[0]), k1 = bf2f(conv_k[1]), k2 = bf2f(conv_k[2]);
    float cb = bf2f(conv_b[0]);
    int b0 = (blockIdx.x >> 7) * 64;
    int r0 = (blockIdx.x & 127) * 128;
    int t = threadIdx.x;
    // stage main tile (coalesced ushort4)
#pragma unroll
    for (int j = 0; j < 8; j++) {
        int idx4 = t + j * 256;
        int row = idx4 >> 5, c4 = (idx4 & 31) * 4;
        *(ushort4*)&ein[row][c4] = *(const ushort4*)(E + (b0 + row) * R_ + r0 + c4);
    }
    // halos
    if (t < 64) {
        ein[t][130] = (r0 > 0) ? E[(b0 + t) * R_ + r0 - 1] : (unsigned short)0;
    } else if (t < 128) {
        int tb = t - 64;
        ein[tb][128] = (r0 + 128 < R_) ? E[(b0 + tb) * R_ + r0 + 128] : (unsigned short)0;
    }
    int b = t >> 2;
    int base = (t & 3) * 32;
    float sS_ = 1.0f / S[b0 + b];
    float g = gamma[b0 + b];
    __syncthreads();

    float el = bf2f((base == 0) ? ein[b][130] : ein[b][base - 1]);
    float ec = bf2f(ein[b][base]);
    float tacc = 0.f;
#pragma unroll
    for (int i = 0; i < 32; i++) {
        float er = bf2f(ein[b][base + 1 + i]);
        float wc = (k0 * el + k1 * ec + k2 * er) * sS_ + cb;
        wc = fmaxf(wc, 1e-30f);
        float au = __builtin_amdgcn_exp2f(g * __log2f(wc));
        aout[base + i][b] = f2bf(au);
        tacc += au;
        el = ec; ec = er;
    }
    tacc += __shfl_xor(tacc, 1, 64);
    tacc += __shfl_xor(tacc, 2, 64);
    if ((t & 3) == 0) atomicAdd(&T[b0 + b], tacc);
    __syncthreads();
#pragma unroll
    for (int j = 0; j < 8; j++) {
        int idx4 = t + j * 256;
        int rrow = idx4 >> 4, c4 = (idx4 & 15) * 4;
        *(ushort4*)(AT + (size_t)(r0 + rrow) * B_ + b0 + c4) = *(ushort4*)&aout[rrow][c4];
    }
}

// ---------------- K4b: build vp' [80,1024] bf16 ----------------
__global__ __launch_bounds__(256) void k_vp2(const float* __restrict__ v, const float* __restrict__ T,
                                             unsigned short* __restrict__ vpb) {
    int idx = blockIdx.x * 256 + threadIdx.x;
    int m = idx >> 10, b = idx & 1023;
    float s = 1.0f / ((T[b] + (float)R_ * 1e-16f) * (float)B_);
    float val = (m < 64) ? v[b * 64 + m] * s : ((m == 64) ? s : 0.f);
    vpb[idx] = f2bf(val);
}

// ---------------- K5: MFMA GEMM mem2T = mem*(1-er) + vp'^ AT ----------------
__global__ __launch_bounds__(256) void k_add(const unsigned short* __restrict__ AT,
        const unsigned short* __restrict__ vpb,
        const unsigned short* __restrict__ memb, unsigned short* __restrict__ mem2T) {
    __shared__ unsigned short smem[64][68];
    __shared__ unsigned short sm2[64][68];
    int r0 = blockIdx.x * 64;
    int t = threadIdx.x, wv = t >> 6, l = t & 63;
    int lane15 = l & 15, quad = l >> 4;
#pragma unroll
    for (int j = 0; j < 4; j++) {
        int idx4 = t + j * 256;
        int rl = idx4 >> 4, w4 = (idx4 & 15) * 4;
        *(ushort4*)&smem[rl][w4] = *(const ushort4*)(memb + (r0 + rl) * 64 + w4);
    }
    __syncthreads();

    const unsigned short* Brow = AT + (size_t)(r0 + wv * 16 + lane15) * B_ + quad * 8;
    const unsigned short* A0 = vpb + (0 * 16 + lane15) * B_ + quad * 8;
    const unsigned short* A1 = vpb + (1 * 16 + lane15) * B_ + quad * 8;
    const unsigned short* A2 = vpb + (2 * 16 + lane15) * B_ + quad * 8;
    const unsigned short* A3 = vpb + (3 * 16 + lane15) * B_ + quad * 8;
    const unsigned short* A4 = vpb + (4 * 16 + lane15) * B_ + quad * 8;
    f32x4 acc0 = {0,0,0,0}, acc1 = {0,0,0,0}, acc2 = {0,0,0,0}, acc3 = {0,0,0,0}, acc4 = {0,0,0,0};
#pragma unroll 4
    for (int k0 = 0; k0 < B_; k0 += 32) {
        bf16x8 bf = ld_bf8(Brow + k0);
        acc0 = mfma16(ld_bf8(A0 + k0), bf, acc0);
        acc1 = mfma16(ld_bf8(A1 + k0), bf, acc1);
        acc2 = mfma16(ld_bf8(A2 + k0), bf, acc2);
        acc3 = mfma16(ld_bf8(A3 + k0), bf, acc3);
        acc4 = mfma16(ld_bf8(A4 + k0), bf, acc4);
    }
    float er = __shfl(acc4[0], l & 15, 64);
    float ome = 1.f - er;
    f32x4 accs[4] = {acc0, acc1, acc2, acc3};
#pragma unroll
    for (int mt = 0; mt < 4; mt++) {
#pragma unroll
        for (int reg = 0; reg < 4; reg++) {
            int w = mt * 16 + quad * 4 + reg;
            int rl = wv * 16 + lane15;
            float m2 = bf2f(smem[rl][w]) * ome + accs[mt][reg];
            sm2[w][rl] = f2bf(m2);
        }
    }
    __syncthreads();
#pragma unroll
    for (int j = 0; j < 4; j++) {
        int idx4 = t + j * 256;
        int w = idx4 >> 4, r4 = (idx4 & 15) * 4;
        *(ushort4*)(mem2T + (size_t)w * R_ + r0 + r4) = *(ushort4*)&sm2[w][r4];
    }
}

// ---------------- K6: flash read head (R0 structure + XCD-bijective swizzle)
// 1024 blocks. HW dispatches block bx to XCD bx%8, so map: xcd = bx&7,
// grp = bx>>3; rc = xcd*8 + (grp>>4) in [0,64), tb = grp&15. All 16 blocks
// sharing one 128KB WpT slice (same rc) land on ONE XCD -> slice is fetched
// from HBM once and staging loads hit that XCD's L2 (~200cyc vs ~900cyc HBM),
// shortening each phase's vmcnt-drain critical path.
// LDS: bstage 32x264 + etile 64x264 = 50,688 B (3 blocks/CU).
// Staging loads register-double-buffered: phase ss+1's loads issued during ss.
__global__ __launch_bounds__(256) void k_read(const unsigned short* __restrict__ x,
        const unsigned short* __restrict__ WpT, const unsigned short* __restrict__ bp,
        const unsigned short* __restrict__ mem2T,
        float* __restrict__ outacc, float* __restrict__ Sp) {
    __shared__ unsigned short bstage[32 * 264];
    __shared__ unsigned short etile[64 * 264];
    int bx = blockIdx.x;
    int xcd = bx & 7, grp = bx >> 3;
    int rc = xcd * 8 + (grp >> 4), tb = grp & 15;
    int t = threadIdx.x, wv = t >> 6, l = t & 63;
    int lane15 = l & 15, quad = l >> 4;
    int brow = tb * 64 + wv * 16 + lane15;
    bf16x8 afr[8];
#pragma unroll
    for (int kk = 0; kk < 8; kk++)
        afr[kk] = ld_bf8(x + brow * 256 + kk * 32 + quad * 8);
    f32x4 accO[4];
#pragma unroll
    for (int nt = 0; nt < 4; nt++) accO[nt] = (f32x4){0.f, 0.f, 0.f, 0.f};
    float sp[4] = {0.f, 0.f, 0.f, 0.f};

    int srow = t >> 3, scg = (t & 7) * 8;
    bf16x8 pf[4];
    {   // prefetch phase 0
        const unsigned short* src = WpT + (size_t)(rc * 256 + srow) * 256 + scg;
#pragma unroll
        for (int j = 0; j < 4; j++) pf[j] = *(const bf16x8*)(src + 64 * j);
    }
    for (int ss = 0; ss < 8; ss++) {
        {   // commit prefetched rows to LDS, then issue next phase's loads
            unsigned short* dst = bstage + srow * 264 + scg;
#pragma unroll
            for (int j = 0; j < 4; j++) *(bf16x8*)(dst + 64 * j) = pf[j];
        }
        if (ss < 7) {
            const unsigned short* src = WpT
                + (size_t)(rc * 256 + (ss + 1) * 32 + srow) * 256 + scg;
#pragma unroll
            for (int j = 0; j < 4; j++) pf[j] = *(const bf16x8*)(src + 64 * j);
        }
        __syncthreads();
        int rbase = rc * 256 + ss * 32;
#pragma unroll
        for (int nt = 0; nt < 2; nt++) {
            f32x4 acc = (f32x4){0.f, 0.f, 0.f, 0.f};
            const unsigned short* bb = bstage + (nt * 16 + lane15) * 264 + quad * 8;
#pragma unroll
            for (int kk = 0; kk < 8; kk++) {
                bf16x8 bfr = *(const bf16x8*)(bb + kk * 32);
                acc = mfma16(afr[kk], bfr, acc);
            }
            int rr = rbase + nt * 16 + lane15;
            float bpv = bf2f(bp[rr]);
            int rloc = ss * 32 + nt * 16 + lane15;
#pragma unroll
            for (int reg = 0; reg < 4; reg++) {
                float e = __expf(acc[reg] + bpv);
                unsigned short ue = f2bf(e);
                sp[reg] += bf2f(ue);   // match PV numerator quantization
                etile[(wv * 16 + quad * 4 + reg) * 264 + rloc] = ue;
            }
        }
        __syncthreads();
    }
#pragma unroll
    for (int nt = 0; nt < 4; nt++) {
        const unsigned short* vbase = mem2T + (size_t)(nt * 16 + lane15) * R_
                                      + rc * 256 + quad * 8;
        const unsigned short* abase = etile + (wv * 16 + lane15) * 264 + quad * 8;
#pragma unroll
        for (int kk = 0; kk < 8; kk++) {
            bf16x8 ea = *(const bf16x8*)(abase + kk * 32);
            bf16x8 vv = *(const bf16x8*)(vbase + kk * 32);
            accO[nt] = mfma16(ea, vv, accO[nt]);
        }
    }
#pragma unroll
    for (int nt = 0; nt < 4; nt++) {
        int wcol = nt * 16 + lane15;
#pragma unroll
        for (int reg = 0; reg < 4; reg++) {
            int b2 = tb * 64 + wv * 16 + quad * 4 + reg;
            atomicAdd(&outacc[b2 * 64 + wcol], accO[nt][reg]);
        }
    }
#pragma unroll
    for (int reg = 0; reg < 4; reg++) {
        float s = sp[reg];
        s += __shfl_xor(s, 1, 64); s += __shfl_xor(s, 2, 64);
        s += __shfl_xor(s, 4, 64); s += __shfl_xor(s, 8, 64);
        if (lane15 == 0) {
            int b2 = tb * 64 + wv * 16 + quad * 4 + reg;
            atomicAdd(&Sp[b2], s);
        }
    }
}

// ---------------- K7: out = outacc / Sp -> FP32 ----------------
__global__ __launch_bounds__(256) void k_out(const float* __restrict__ outacc,
                                             const float* __restrict__ Sp,
                                             float* __restrict__ out) {
    int idx = blockIdx.x * 256 + threadIdx.x;
    int b = idx >> 6;
    out[idx] = outacc[idx] / Sp[b];
}

extern "C" void kernel_launch(void* const* d_in, const int* in_sizes, int n_in,
                              void* d_out, int out_size, void* d_ws, size_t ws_size,
                              hipStream_t stream) {
    (void)n_in; (void)out_size;
    float* outp = (float*)d_out;

    char* ws = (char*)d_ws;
    size_t o = 0;
    unsigned short* arena = (unsigned short*)(ws + o); o += (size_t)AO_TOT * 2;
    unsigned short* WpT = (unsigned short*)(ws + o); o += (size_t)R_ * D_ * 2;
    unsigned short* E   = (unsigned short*)(ws + o); o += (size_t)B_ * R_ * 2;
    unsigned short* AT  = (unsigned short*)(ws + o); o += (size_t)B_ * R_ * 2;
    float* v            = (float*)(ws + o);          o += (size_t)B_ * 64 * 4;
    unsigned short* vb  = (unsigned short*)(ws + o); o += (size_t)B_ * 64 * 2;
    unsigned short* vpb = (unsigned short*)(ws + o); o += (size_t)80 * B_ * 2;
    float* invmn        = (float*)(ws + o);          o += (size_t)R_ * 4;
    float* bovn         = (float*)(ws + o);          o += 4096;
    float* beta         = (float*)(ws + o);          o += 4096;
    float* gamma        = (float*)(ws + o);          o += 4096;
    unsigned short* m2T = (unsigned short*)(ws + o); o += (size_t)R_ * 64 * 2;
    float* zbase  = (float*)(ws + o);
    float* S      = (float*)(ws + o);                o += 4096;
    float* T      = (float*)(ws + o);                o += 4096;
    float* Sp     = (float*)(ws + o);                o += 4096;
    float* outacc = (float*)(ws + o);                o += (size_t)B_ * 64 * 4;

    if (ws_size < o) {
        k_sentinel<<<256, 256, 0, stream>>>(outp, 1000.0f);
        return;
    }
    if (in_sizes[0] != B_ * D_ || in_sizes[7] != D_ * R_ || in_sizes[11] != R_ * W_) {
        k_sentinel<<<256, 256, 0, stream>>>(outp, 2000.0f);
        return;
    }

    k_zero<<<268, 256, 0, stream>>>(zbase);
    k_convert<<<(AO_TOT + 511) / 512, 256, 0, stream>>>(
        (const float*)d_in[0], (const float*)d_in[1], (const float*)d_in[2],
        (const float*)d_in[3], (const float*)d_in[4], (const float*)d_in[5],
        (const float*)d_in[6], (const float*)d_in[8],
        (const float*)d_in[9], (const float*)d_in[10], (const float*)d_in[11], arena);

    k_transpose_wp<<<dim3(256, 4), 256, 0, stream>>>((const float*)d_in[7], WpT);
    k_heads<<<1024, 64, 0, stream>>>(arena + AO_X, arena + AO_WV, arena + AO_BV,
                                     arena + AO_WB, arena + AO_BB, arena + AO_WG,
                                     arena + AO_BG, v, vb, bovn, beta, gamma);
    k_mn<<<64, 256, 0, stream>>>(arena + AO_MEM, invmn);
    k_sim<<<2048, 256, 0, stream>>>(vb, arena + AO_MEM, bovn, invmn, beta, E, S);
    k_conv<<<2048, 256, 0, stream>>>(E, AT, S, gamma, arena + AO_CK, arena + AO_CB, T);
    k_vp2<<<320, 256, 0, stream>>>(v, T, vpb);
    k_add<<<256, 256, 0, stream>>>(AT, vpb, arena + AO_MEM, m2T);
    k_read<<<1024, 256, 0, stream>>>(arena + AO_X, WpT, arena + AO_BP, m2T, outacc, Sp);
    k_out<<<256, 256, 0, stream>>>(outacc, Sp, outp);
}

// Round 6
// 269.048 us; speedup vs baseline: 1.3815x; 1.0013x over previous
//
#include <hip/hip_runtime.h>
#include <hip/hip_bf16.h>

#define B_ 1024
#define D_ 256
#define R_ 16384
#define W_ 64

typedef float f32x4 __attribute__((ext_vector_type(4)));
typedef __bf16 bf16x8 __attribute__((ext_vector_type(8)));

__device__ __forceinline__ float bf2f(unsigned short u) {
    union { unsigned int i; float f; } v; v.i = ((unsigned int)u) << 16; return v.f;
}
__device__ __forceinline__ unsigned short f2bf(float f) {
    union { float fv; unsigned int i; } v; v.fv = f;
    unsigned int r = v.i + 0x7FFFu + ((v.i >> 16) & 1u);
    return (unsigned short)(r >> 16);
}
__device__ __forceinline__ f32x4 mfma16(bf16x8 a, bf16x8 b, f32x4 c) {
    return __builtin_amdgcn_mfma_f32_16x16x32_bf16(a, b, c, 0, 0, 0);
}
__device__ __forceinline__ bf16x8 ld_bf8(const unsigned short* p) {
    return *(const bf16x8*)p;
}

// ---------------- arena element offsets (each segment start 16-elem aligned) ----
// Wp is not staged through the arena: k_transpose_wp reads the fp32 input
// directly and emits bf16 WpT (saves ~17 MB of convert round-trip).
#define AO_X     0
#define AO_WV    262144
#define AO_BV    278528
#define AO_WB    278592
#define AO_BB    278848
#define AO_WG    278864
#define AO_BG    279120
#define AO_BP    279136
#define AO_CK    295520
#define AO_CB    295536
#define AO_MEM   295552
#define AO_TOT   1344128

__global__ __launch_bounds__(256) void k_sentinel(float* __restrict__ out, float val) {
    out[blockIdx.x * 256 + threadIdx.x] = val;
}

__global__ __launch_bounds__(256) void k_zero(float* __restrict__ z) {
    z[blockIdx.x * 256 + threadIdx.x] = 0.f;
}

// ---------------- K-convert: fp32 inputs -> bf16 arena (no Wp) ----------------
__global__ __launch_bounds__(256) void k_convert(
        const float* x, const float* Wv, const float* bv, const float* Wb, const float* bb,
        const float* Wg, const float* bg, const float* bp,
        const float* ck, const float* cb, const float* mem,
        unsigned short* __restrict__ dst) {
    int base = blockIdx.x * 512 + threadIdx.x;
#pragma unroll
    for (int h = 0; h < 2; h++) {
        int idx = base + h * 256;
        if (idx >= AO_TOT) continue;
        const float* p; int st; int n;
        if      (idx >= AO_MEM) { p = mem; st = AO_MEM; n = R_ * W_; }
        else if (idx >= AO_CB)  { p = cb;  st = AO_CB;  n = 1; }
        else if (idx >= AO_CK)  { p = ck;  st = AO_CK;  n = 3; }
        else if (idx >= AO_BP)  { p = bp;  st = AO_BP;  n = R_; }
        else if (idx >= AO_BG)  { p = bg;  st = AO_BG;  n = 1; }
        else if (idx >= AO_WG)  { p = Wg;  st = AO_WG;  n = D_; }
        else if (idx >= AO_BB)  { p = bb;  st = AO_BB;  n = 1; }
        else if (idx >= AO_WB)  { p = Wb;  st = AO_WB;  n = D_; }
        else if (idx >= AO_BV)  { p = bv;  st = AO_BV;  n = W_; }
        else if (idx >= AO_WV)  { p = Wv;  st = AO_WV;  n = D_ * W_; }
        else                    { p = x;   st = AO_X;   n = B_ * D_; }
        int local = idx - st;
        dst[idx] = (local < n) ? f2bf(p[local]) : (unsigned short)0;
    }
}

// ---------------- K0: transpose+convert Wp fp32 [D,R] -> WpT bf16 [R,D] --------
__global__ __launch_bounds__(256) void k_transpose_wp(const float* __restrict__ Wp,
                                                      unsigned short* __restrict__ WpT) {
    __shared__ unsigned short tile[64][66];
    int r0 = blockIdx.x * 64, d0 = blockIdx.y * 64;
    int t = threadIdx.x, lane = t & 63, wv = t >> 6;
#pragma unroll
    for (int i = 0; i < 16; i++) {
        int dl = wv + 4 * i;
        tile[dl][lane] = f2bf(Wp[(size_t)(d0 + dl) * R_ + r0 + lane]);
    }
    __syncthreads();
#pragma unroll
    for (int i = 0; i < 16; i++) {
        int rl = wv + 4 * i;
        WpT[(size_t)(r0 + rl) * D_ + d0 + lane] = tile[lane][rl];
    }
}

// ---------------- K1: controller heads: v, vb, bovn=beta/vn, beta, gamma ----------
__global__ __launch_bounds__(64) void k_heads(const unsigned short* __restrict__ x,
        const unsigned short* __restrict__ Wv, const unsigned short* __restrict__ bv,
        const unsigned short* __restrict__ Wb, const unsigned short* __restrict__ bb,
        const unsigned short* __restrict__ Wg, const unsigned short* __restrict__ bg,
        float* __restrict__ v, unsigned short* __restrict__ vb,
        float* __restrict__ bovn, float* __restrict__ beta, float* __restrict__ gamma) {
    __shared__ float sx[256];
    int b = blockIdx.x, lane = threadIdx.x;
#pragma unroll
    for (int j = 0; j < 4; j++) sx[lane + 64 * j] = bf2f(x[b * 256 + lane + 64 * j]);
    __syncthreads();
    float acc = 0.f;
#pragma unroll 8
    for (int d = 0; d < 256; d++) acc += sx[d] * bf2f(Wv[d * 64 + lane]);
    acc += bf2f(bv[lane]);
    v[b * 64 + lane] = acc;
    vb[b * 64 + lane] = f2bf(acc);
    float sq = acc * acc;
#pragma unroll
    for (int d = 32; d >= 1; d >>= 1) sq += __shfl_xor(sq, d, 64);
    float pb = 0.f, pg = 0.f;
#pragma unroll
    for (int j = 0; j < 4; j++) {
        float xv = sx[lane + 64 * j];
        pb += xv * bf2f(Wb[lane + 64 * j]);
        pg += xv * bf2f(Wg[lane + 64 * j]);
    }
#pragma unroll
    for (int d = 32; d >= 1; d >>= 1) { pb += __shfl_xor(pb, d, 64); pg += __shfl_xor(pg, d, 64); }
    if (lane == 0) {
        float vn = sqrtf(sq);
        float zb = pb + bf2f(bb[0]);
        float zg = pg + bf2f(bg[0]);
        float be = (zb > 20.f) ? zb : log1pf(__expf(zb));
        beta[b]  = be;
        bovn[b]  = be / (vn + 1e-16f);
        gamma[b] = 1.f + ((zg > 20.f) ? zg : log1pf(__expf(zg)));
    }
}

// ---------------- K2: mem row inverse norms ----------------
__global__ __launch_bounds__(256) void k_mn(const unsigned short* __restrict__ mem, float* __restrict__ invmn) {
    int lane = threadIdx.x & 63;
    int gw = blockIdx.x * 4 + (threadIdx.x >> 6);
    for (int row = gw; row < R_; row += 256) {
        float m = bf2f(mem[row * 64 + lane]);
        float s = m * m;
#pragma unroll
        for (int d = 32; d >= 1; d >>= 1) s += __shfl_xor(s, d, 64);
        if (lane == 0) invmn[row] = 1.0f / (sqrtf(s) + 1e-16f);
    }
}

// ---------------- K3: sim MFMA -> E = exp(acc*bovn*invmn - beta), S[b] ----------
__global__ __launch_bounds__(256, 8) void k_sim(const unsigned short* __restrict__ vb,
        const unsigned short* __restrict__ mem,
        const float* __restrict__ bovn, const float* __restrict__ invmn,
        const float* __restrict__ beta,
        unsigned short* __restrict__ E, float* __restrict__ S) {
    __shared__ unsigned short etile[64][132];
    __shared__ float sred[4][64];
    int bx = blockIdx.x;
    int rc = bx & 127, tb = bx >> 7;
    int t = threadIdx.x, wv = t >> 6, l = t & 63;
    int lane15 = l & 15, quad = l >> 4;
    int rr0 = rc * 128 + wv * 32 + lane15;
    bf16x8 bm[2][2];
    float im[2];
#pragma unroll
    for (int nt = 0; nt < 2; nt++) {
        int rr = rr0 + nt * 16;
        bm[nt][0] = ld_bf8(mem + rr * 64 + quad * 8);
        bm[nt][1] = ld_bf8(mem + rr * 64 + 32 + quad * 8);
        im[nt] = invmn[rr];
    }
    bf16x8 afr[4][2];
    float bvl[4][4], bel[4][4];
#pragma unroll
    for (int m = 0; m < 4; m++) {
        int brow = tb * 64 + m * 16 + lane15;
        afr[m][0] = ld_bf8(vb + brow * 64 + quad * 8);
        afr[m][1] = ld_bf8(vb + brow * 64 + 32 + quad * 8);
#pragma unroll
        for (int reg = 0; reg < 4; reg++) {
            int b2 = tb * 64 + m * 16 + quad * 4 + reg;
            bvl[m][reg] = bovn[b2];
            bel[m][reg] = beta[b2];
        }
    }
    float sp[4][4];
#pragma unroll
    for (int m = 0; m < 4; m++)
#pragma unroll
        for (int r = 0; r < 4; r++) sp[m][r] = 0.f;

#pragma unroll
    for (int nt = 0; nt < 2; nt++) {
        int rl = wv * 32 + nt * 16 + lane15;
#pragma unroll
        for (int m = 0; m < 4; m++) {
            f32x4 acc = (f32x4){0.f, 0.f, 0.f, 0.f};
            acc = mfma16(afr[m][0], bm[nt][0], acc);
            acc = mfma16(afr[m][1], bm[nt][1], acc);
#pragma unroll
            for (int reg = 0; reg < 4; reg++) {
                float e = __expf(acc[reg] * (bvl[m][reg] * im[nt]) - bel[m][reg]);
                sp[m][reg] += e;
                etile[m * 16 + quad * 4 + reg][rl] = f2bf(e);
            }
        }
    }
#pragma unroll
    for (int m = 0; m < 4; m++)
#pragma unroll
        for (int reg = 0; reg < 4; reg++) {
            float s = sp[m][reg];
            s += __shfl_xor(s, 1, 64); s += __shfl_xor(s, 2, 64);
            s += __shfl_xor(s, 4, 64); s += __shfl_xor(s, 8, 64);
            if (lane15 == 0) sred[wv][m * 16 + quad * 4 + reg] = s;
        }
    __syncthreads();
#pragma unroll
    for (int j = 0; j < 4; j++) {
        int idx8 = t + j * 256;
        int row = idx8 >> 4;
        int c8 = (idx8 & 15) * 8;
        *(bf16x8*)(E + (size_t)(tb * 64 + row) * R_ + rc * 128 + c8) =
            *(const bf16x8*)&etile[row][c8];
    }
    if (t < 64)
        atomicAdd(&S[tb * 64 + t], sred[0][t] + sred[1][t] + sred[2][t] + sred[3][t]);
}

// ---------------- K4: conv+pow -> AT [R,B] (transposed!), T[b] ----------------
// Thread t owns row b = t>>2 and a contiguous run of 32 r's (base = (t&3)*32).
// Rolling el/ec/er window -> 1 new LDS read per element, no boundary ternaries
// (halo staged in-tile: col 128 = right halo, col 130 = left halo).
// T-reduction: per-thread scalar accumulator + 2 shfl_xor across the 4 threads
// sharing a b (was: 6 shuffles PER ELEMENT + LDS atomics).
// pow via __builtin_amdgcn_exp2f(g*log2(wc)) -- v_exp_f32 IS 2^x on gfx950.
__global__ __launch_bounds__(256) void k_conv(const unsigned short* __restrict__ E,
        unsigned short* __restrict__ AT,
        const float* __restrict__ S, const float* __restrict__ gamma,
        const unsigned short* __restrict__ conv_k, const unsigned short* __restrict__ conv_b,
        float* __restrict__ T) {
    __shared__ unsigned short ein[64][132];   // cols 0..127: r0..r0+127; 128: right halo; 130: left halo
    __shared__ unsigned short aout[128][68];
    float k0 = bf2f(conv_k[0]), k1 = bf2f(conv_k[1]), k2 = bf2f(conv_k[2]);
    float cb = bf2f(conv_b[0]);
    int b0 = (blockIdx.x >> 7) * 64;
    int r0 = (blockIdx.x & 127) * 128;
    int t = threadIdx.x;
    // stage main tile (coalesced ushort4)
#pragma unroll
    for (int j = 0; j < 8; j++) {
        int idx4 = t + j * 256;
        int row = idx4 >> 5, c4 = (idx4 & 31) * 4;
        *(ushort4*)&ein[row][c4] = *(const ushort4*)(E + (b0 + row) * R_ + r0 + c4);
    }
    // halos
    if (t < 64) {
        ein[t][130] = (r0 > 0) ? E[(b0 + t) * R_ + r0 - 1] : (unsigned short)0;
    } else if (t < 128) {
        int tb = t - 64;
        ein[tb][128] = (r0 + 128 < R_) ? E[(b0 + tb) * R_ + r0 + 128] : (unsigned short)0;
    }
    int b = t >> 2;
    int base = (t & 3) * 32;
    float sS_ = 1.0f / S[b0 + b];
    float g = gamma[b0 + b];
    __syncthreads();

    float el = bf2f((base == 0) ? ein[b][130] : ein[b][base - 1]);
    float ec = bf2f(ein[b][base]);
    float tacc = 0.f;
#pragma unroll
    for (int i = 0; i < 32; i++) {
        float er = bf2f(ein[b][base + 1 + i]);
        float wc = (k0 * el + k1 * ec + k2 * er) * sS_ + cb;
        wc = fmaxf(wc, 1e-30f);
        float au = __builtin_amdgcn_exp2f(g * __log2f(wc));
        aout[base + i][b] = f2bf(au);
        tacc += au;
        el = ec; ec = er;
    }
    tacc += __shfl_xor(tacc, 1, 64);
    tacc += __shfl_xor(tacc, 2, 64);
    if ((t & 3) == 0) atomicAdd(&T[b0 + b], tacc);
    __syncthreads();
#pragma unroll
    for (int j = 0; j < 8; j++) {
        int idx4 = t + j * 256;
        int rrow = idx4 >> 4, c4 = (idx4 & 15) * 4;
        *(ushort4*)(AT + (size_t)(r0 + rrow) * B_ + b0 + c4) = *(ushort4*)&aout[rrow][c4];
    }
}

// ---------------- K4b: build vp' [80,1024] bf16 ----------------
__global__ __launch_bounds__(256) void k_vp2(const float* __restrict__ v, const float* __restrict__ T,
                                             unsigned short* __restrict__ vpb) {
    int idx = blockIdx.x * 256 + threadIdx.x;
    int m = idx >> 10, b = idx & 1023;
    float s = 1.0f / ((T[b] + (float)R_ * 1e-16f) * (float)B_);
    float val = (m < 64) ? v[b * 64 + m] * s : ((m == 64) ? s : 0.f);
    vpb[idx] = f2bf(val);
}

// ---------------- K5: MFMA GEMM mem2T = mem*(1-er) + vp'^ AT ----------------
__global__ __launch_bounds__(256) void k_add(const unsigned short* __restrict__ AT,
        const unsigned short* __restrict__ vpb,
        const unsigned short* __restrict__ memb, unsigned short* __restrict__ mem2T) {
    __shared__ unsigned short smem[64][68];
    __shared__ unsigned short sm2[64][68];
    int r0 = blockIdx.x * 64;
    int t = threadIdx.x, wv = t >> 6, l = t & 63;
    int lane15 = l & 15, quad = l >> 4;
#pragma unroll
    for (int j = 0; j < 4; j++) {
        int idx4 = t + j * 256;
        int rl = idx4 >> 4, w4 = (idx4 & 15) * 4;
        *(ushort4*)&smem[rl][w4] = *(const ushort4*)(memb + (r0 + rl) * 64 + w4);
    }
    __syncthreads();

    const unsigned short* Brow = AT + (size_t)(r0 + wv * 16 + lane15) * B_ + quad * 8;
    const unsigned short* A0 = vpb + (0 * 16 + lane15) * B_ + quad * 8;
    const unsigned short* A1 = vpb + (1 * 16 + lane15) * B_ + quad * 8;
    const unsigned short* A2 = vpb + (2 * 16 + lane15) * B_ + quad * 8;
    const unsigned short* A3 = vpb + (3 * 16 + lane15) * B_ + quad * 8;
    const unsigned short* A4 = vpb + (4 * 16 + lane15) * B_ + quad * 8;
    f32x4 acc0 = {0,0,0,0}, acc1 = {0,0,0,0}, acc2 = {0,0,0,0}, acc3 = {0,0,0,0}, acc4 = {0,0,0,0};
#pragma unroll 4
    for (int k0 = 0; k0 < B_; k0 += 32) {
        bf16x8 bf = ld_bf8(Brow + k0);
        acc0 = mfma16(ld_bf8(A0 + k0), bf, acc0);
        acc1 = mfma16(ld_bf8(A1 + k0), bf, acc1);
        acc2 = mfma16(ld_bf8(A2 + k0), bf, acc2);
        acc3 = mfma16(ld_bf8(A3 + k0), bf, acc3);
        acc4 = mfma16(ld_bf8(A4 + k0), bf, acc4);
    }
    float er = __shfl(acc4[0], l & 15, 64);
    float ome = 1.f - er;
    f32x4 accs[4] = {acc0, acc1, acc2, acc3};
#pragma unroll
    for (int mt = 0; mt < 4; mt++) {
#pragma unroll
        for (int reg = 0; reg < 4; reg++) {
            int w = mt * 16 + quad * 4 + reg;
            int rl = wv * 16 + lane15;
            float m2 = bf2f(smem[rl][w]) * ome + accs[mt][reg];
            sm2[w][rl] = f2bf(m2);
        }
    }
    __syncthreads();
#pragma unroll
    for (int j = 0; j < 4; j++) {
        int idx4 = t + j * 256;
        int w = idx4 >> 4, r4 = (idx4 & 15) * 4;
        *(ushort4*)(mem2T + (size_t)w * R_ + r0 + r4) = *(ushort4*)&sm2[w][r4];
    }
}

// ---------------- K6: flash read head, fused-PV single-barrier pipeline ------
// Keeps R4's XCD swizzle (16 blocks sharing a WpT slice -> one XCD's L2).
// Changes vs R4 (which was 43.8us at 22% occupancy, 7.3MB fetch, latency-bound):
//  * bstage double-buffered -> ONE barrier per phase (8 vs 16). Buffer
//    (ss+1)&1 was last read in phase ss-1, completed before phase ss's barrier.
//  * etile (33.8KB) removed. P->PV transpose is wave-private: per-phase
//    ptile[wave][16][40] (5KB). PV fused into each phase: after exp, write 8
//    P values, read back one b128 A-fragment, 4 PV MFMAs with vv fragments
//    loaded from L2 right after the barrier (hidden under QK MFMAs).
//  * LDS 50688 -> 38912 B -> 4 blocks/CU (16 waves, was 12);
//    __launch_bounds__(256,4) caps VGPR at 128 for 4 waves/SIMD.
__global__ __launch_bounds__(256, 4) void k_read(const unsigned short* __restrict__ x,
        const unsigned short* __restrict__ WpT, const unsigned short* __restrict__ bp,
        const unsigned short* __restrict__ mem2T,
        float* __restrict__ outacc, float* __restrict__ Sp) {
    __shared__ unsigned short bstage[2][32 * 264];
    __shared__ unsigned short ptile[4][16 * 40];
    int bx = blockIdx.x;
    int xcd = bx & 7, grp = bx >> 3;
    int rc = xcd * 8 + (grp >> 4), tb = grp & 15;
    int t = threadIdx.x, wv = t >> 6, l = t & 63;
    int lane15 = l & 15, quad = l >> 4;
    int brow = tb * 64 + wv * 16 + lane15;
    bf16x8 afr[8];
#pragma unroll
    for (int kk = 0; kk < 8; kk++)
        afr[kk] = ld_bf8(x + brow * 256 + kk * 32 + quad * 8);
    f32x4 accO[4];
#pragma unroll
    for (int nt = 0; nt < 4; nt++) accO[nt] = (f32x4){0.f, 0.f, 0.f, 0.f};
    float sp[4] = {0.f, 0.f, 0.f, 0.f};
    unsigned short* ptw = &ptile[wv][0];

    int srow = t >> 3, scg = (t & 7) * 8;
    bf16x8 pf[4];
    {   // prefetch phase 0 staging
        const unsigned short* src = WpT + (size_t)(rc * 256 + srow) * 256 + scg;
#pragma unroll
        for (int j = 0; j < 4; j++) pf[j] = *(const bf16x8*)(src + 64 * j);
    }
    const unsigned short* vrow = mem2T + (size_t)lane15 * R_ + rc * 256 + quad * 8;

    for (int ss = 0; ss < 8; ss++) {
        unsigned short* bcur = bstage[ss & 1];
        {   // commit prefetched rows, then issue next phase's loads
            unsigned short* dst = bcur + srow * 264 + scg;
#pragma unroll
            for (int j = 0; j < 4; j++) *(bf16x8*)(dst + 64 * j) = pf[j];
        }
        if (ss < 7) {
            const unsigned short* src = WpT
                + (size_t)(rc * 256 + (ss + 1) * 32 + srow) * 256 + scg;
#pragma unroll
            for (int j = 0; j < 4; j++) pf[j] = *(const bf16x8*)(src + 64 * j);
        }
        __syncthreads();
        // V fragments for this k-slice; L2-resident, lands under the QK MFMAs
        bf16x8 vv0 = ld_bf8(vrow + (size_t)0 * 16 * R_ + ss * 32);
        bf16x8 vv1 = ld_bf8(vrow + (size_t)1 * 16 * R_ + ss * 32);
        bf16x8 vv2 = ld_bf8(vrow + (size_t)2 * 16 * R_ + ss * 32);
        bf16x8 vv3 = ld_bf8(vrow + (size_t)3 * 16 * R_ + ss * 32);
        int rbase = rc * 256 + ss * 32;
#pragma unroll
        for (int nt = 0; nt < 2; nt++) {
            f32x4 acc = (f32x4){0.f, 0.f, 0.f, 0.f};
            const unsigned short* bb = bcur + (nt * 16 + lane15) * 264 + quad * 8;
#pragma unroll
            for (int kk = 0; kk < 8; kk++) {
                bf16x8 bfr = *(const bf16x8*)(bb + kk * 32);
                acc = mfma16(afr[kk], bfr, acc);
            }
            int rr = rbase + nt * 16 + lane15;
            float bpv = bf2f(bp[rr]);
#pragma unroll
            for (int reg = 0; reg < 4; reg++) {
                float e = __expf(acc[reg] + bpv);
                unsigned short ue = f2bf(e);
                sp[reg] += bf2f(ue);   // match PV numerator quantization
                ptw[(quad * 4 + reg) * 40 + nt * 16 + lane15] = ue;
            }
        }
        // wave-private transpose readback -> PV A-fragment for this k-slice
        bf16x8 pa = *(const bf16x8*)(ptw + lane15 * 40 + quad * 8);
        accO[0] = mfma16(pa, vv0, accO[0]);
        accO[1] = mfma16(pa, vv1, accO[1]);
        accO[2] = mfma16(pa, vv2, accO[2]);
        accO[3] = mfma16(pa, vv3, accO[3]);
    }
#pragma unroll
    for (int nt = 0; nt < 4; nt++) {
        int wcol = nt * 16 + lane15;
#pragma unroll
        for (int reg = 0; reg < 4; reg++) {
            int b2 = tb * 64 + wv * 16 + quad * 4 + reg;
            atomicAdd(&outacc[b2 * 64 + wcol], accO[nt][reg]);
        }
    }
#pragma unroll
    for (int reg = 0; reg < 4; reg++) {
        float s = sp[reg];
        s += __shfl_xor(s, 1, 64); s += __shfl_xor(s, 2, 64);
        s += __shfl_xor(s, 4, 64); s += __shfl_xor(s, 8, 64);
        if (lane15 == 0) {
            int b2 = tb * 64 + wv * 16 + quad * 4 + reg;
            atomicAdd(&Sp[b2], s);
        }
    }
}

// ---------------- K7: out = outacc / Sp -> FP32 ----------------
__global__ __launch_bounds__(256) void k_out(const float* __restrict__ outacc,
                                             const float* __restrict__ Sp,
                                             float* __restrict__ out) {
    int idx = blockIdx.x * 256 + threadIdx.x;
    int b = idx >> 6;
    out[idx] = outacc[idx] / Sp[b];
}

extern "C" void kernel_launch(void* const* d_in, const int* in_sizes, int n_in,
                              void* d_out, int out_size, void* d_ws, size_t ws_size,
                              hipStream_t stream) {
    (void)n_in; (void)out_size;
    float* outp = (float*)d_out;

    char* ws = (char*)d_ws;
    size_t o = 0;
    unsigned short* arena = (unsigned short*)(ws + o); o += (size_t)AO_TOT * 2;
    unsigned short* WpT = (unsigned short*)(ws + o); o += (size_t)R_ * D_ * 2;
    unsigned short* E   = (unsigned short*)(ws + o); o += (size_t)B_ * R_ * 2;
    unsigned short* AT  = (unsigned short*)(ws + o); o += (size_t)B_ * R_ * 2;
    float* v            = (float*)(ws + o);          o += (size_t)B_ * 64 * 4;
    unsigned short* vb  = (unsigned short*)(ws + o); o += (size_t)B_ * 64 * 2;
    unsigned short* vpb = (unsigned short*)(ws + o); o += (size_t)80 * B_ * 2;
    float* invmn        = (float*)(ws + o);          o += (size_t)R_ * 4;
    float* bovn         = (float*)(ws + o);          o += 4096;
    float* beta         = (float*)(ws + o);          o += 4096;
    float* gamma        = (float*)(ws + o);          o += 4096;
    unsigned short* m2T = (unsigned short*)(ws + o); o += (size_t)R_ * 64 * 2;
    float* zbase  = (float*)(ws + o);
    float* S      = (float*)(ws + o);                o += 4096;
    float* T      = (float*)(ws + o);                o += 4096;
    float* Sp     = (float*)(ws + o);                o += 4096;
    float* outacc = (float*)(ws + o);                o += (size_t)B_ * 64 * 4;

    if (ws_size < o) {
        k_sentinel<<<256, 256, 0, stream>>>(outp, 1000.0f);
        return;
    }
    if (in_sizes[0] != B_ * D_ || in_sizes[7] != D_ * R_ || in_sizes[11] != R_ * W_) {
        k_sentinel<<<256, 256, 0, stream>>>(outp, 2000.0f);
        return;
    }

    k_zero<<<268, 256, 0, stream>>>(zbase);
    k_convert<<<(AO_TOT + 511) / 512, 256, 0, stream>>>(
        (const float*)d_in[0], (const float*)d_in[1], (const float*)d_in[2],
        (const float*)d_in[3], (const float*)d_in[4], (const float*)d_in[5],
        (const float*)d_in[6], (const float*)d_in[8],
        (const float*)d_in[9], (const float*)d_in[10], (const float*)d_in[11], arena);

    k_transpose_wp<<<dim3(256, 4), 256, 0, stream>>>((const float*)d_in[7], WpT);
    k_heads<<<1024, 64, 0, stream>>>(arena + AO_X, arena + AO_WV, arena + AO_BV,
                                     arena + AO_WB, arena + AO_BB, arena + AO_WG,
                                     arena + AO_BG, v, vb, bovn, beta, gamma);
    k_mn<<<64, 256, 0, stream>>>(arena + AO_MEM, invmn);
    k_sim<<<2048, 256, 0, stream>>>(vb, arena + AO_MEM, bovn, invmn, beta, E, S);
    k_conv<<<2048, 256, 0, stream>>>(E, AT, S, gamma, arena + AO_CK, arena + AO_CB, T);
    k_vp2<<<320, 256, 0, stream>>>(v, T, vpb);
    k_add<<<256, 256, 0, stream>>>(AT, vpb, arena + AO_MEM, m2T);
    k_read<<<1024, 256, 0, stream>>>(arena + AO_X, WpT, arena + AO_BP, m2T, outacc, Sp);
    k_out<<<256, 256, 0, stream>>>(outacc, Sp, outp);
}

// Round 7
// 267.640 us; speedup vs baseline: 1.3888x; 1.0053x over previous
//
#include <hip/hip_runtime.h>
#include <hip/hip_bf16.h>

#define B_ 1024
#define D_ 256
#define R_ 16384
#define W_ 64

typedef float f32x4 __attribute__((ext_vector_type(4)));
typedef __bf16 bf16x8 __attribute__((ext_vector_type(8)));

__device__ __forceinline__ float bf2f(unsigned short u) {
    union { unsigned int i; float f; } v; v.i = ((unsigned int)u) << 16; return v.f;
}
__device__ __forceinline__ unsigned short f2bf(float f) {
    union { float fv; unsigned int i; } v; v.fv = f;
    unsigned int r = v.i + 0x7FFFu + ((v.i >> 16) & 1u);
    return (unsigned short)(r >> 16);
}
__device__ __forceinline__ f32x4 mfma16(bf16x8 a, bf16x8 b, f32x4 c) {
    return __builtin_amdgcn_mfma_f32_16x16x32_bf16(a, b, c, 0, 0, 0);
}
__device__ __forceinline__ bf16x8 ld_bf8(const unsigned short* p) {
    return *(const bf16x8*)p;
}

// ---------------- arena element offsets (each segment start 16-elem aligned) ----
// Wp is not staged through the arena: k_transpose_wp reads the fp32 input
// directly and emits bf16 WpT (saves ~17 MB of convert round-trip).
#define AO_X     0
#define AO_WV    262144
#define AO_BV    278528
#define AO_WB    278592
#define AO_BB    278848
#define AO_WG    278864
#define AO_BG    279120
#define AO_BP    279136
#define AO_CK    295520
#define AO_CB    295536
#define AO_MEM   295552
#define AO_TOT   1344128

__global__ __launch_bounds__(256) void k_sentinel(float* __restrict__ out, float val) {
    out[blockIdx.x * 256 + threadIdx.x] = val;
}

__global__ __launch_bounds__(256) void k_zero(float* __restrict__ z) {
    z[blockIdx.x * 256 + threadIdx.x] = 0.f;
}

// ---------------- K-convert: fp32 inputs -> bf16 arena (no Wp) ----------------
__global__ __launch_bounds__(256) void k_convert(
        const float* x, const float* Wv, const float* bv, const float* Wb, const float* bb,
        const float* Wg, const float* bg, const float* bp,
        const float* ck, const float* cb, const float* mem,
        unsigned short* __restrict__ dst) {
    int base = blockIdx.x * 512 + threadIdx.x;
#pragma unroll
    for (int h = 0; h < 2; h++) {
        int idx = base + h * 256;
        if (idx >= AO_TOT) continue;
        const float* p; int st; int n;
        if      (idx >= AO_MEM) { p = mem; st = AO_MEM; n = R_ * W_; }
        else if (idx >= AO_CB)  { p = cb;  st = AO_CB;  n = 1; }
        else if (idx >= AO_CK)  { p = ck;  st = AO_CK;  n = 3; }
        else if (idx >= AO_BP)  { p = bp;  st = AO_BP;  n = R_; }
        else if (idx >= AO_BG)  { p = bg;  st = AO_BG;  n = 1; }
        else if (idx >= AO_WG)  { p = Wg;  st = AO_WG;  n = D_; }
        else if (idx >= AO_BB)  { p = bb;  st = AO_BB;  n = 1; }
        else if (idx >= AO_WB)  { p = Wb;  st = AO_WB;  n = D_; }
        else if (idx >= AO_BV)  { p = bv;  st = AO_BV;  n = W_; }
        else if (idx >= AO_WV)  { p = Wv;  st = AO_WV;  n = D_ * W_; }
        else                    { p = x;   st = AO_X;   n = B_ * D_; }
        int local = idx - st;
        dst[idx] = (local < n) ? f2bf(p[local]) : (unsigned short)0;
    }
}

// ---------------- K0: transpose+convert Wp fp32 [D,R] -> WpT bf16 [R,D] --------
__global__ __launch_bounds__(256) void k_transpose_wp(const float* __restrict__ Wp,
                                                      unsigned short* __restrict__ WpT) {
    __shared__ unsigned short tile[64][66];
    int r0 = blockIdx.x * 64, d0 = blockIdx.y * 64;
    int t = threadIdx.x, lane = t & 63, wv = t >> 6;
#pragma unroll
    for (int i = 0; i < 16; i++) {
        int dl = wv + 4 * i;
        tile[dl][lane] = f2bf(Wp[(size_t)(d0 + dl) * R_ + r0 + lane]);
    }
    __syncthreads();
#pragma unroll
    for (int i = 0; i < 16; i++) {
        int rl = wv + 4 * i;
        WpT[(size_t)(r0 + rl) * D_ + d0 + lane] = tile[lane][rl];
    }
}

// ---------------- K1: controller heads: v, vb, bovn=beta/vn, beta, gamma ----------
__global__ __launch_bounds__(64) void k_heads(const unsigned short* __restrict__ x,
        const unsigned short* __restrict__ Wv, const unsigned short* __restrict__ bv,
        const unsigned short* __restrict__ Wb, const unsigned short* __restrict__ bb,
        const unsigned short* __restrict__ Wg, const unsigned short* __restrict__ bg,
        float* __restrict__ v, unsigned short* __restrict__ vb,
        float* __restrict__ bovn, float* __restrict__ beta, float* __restrict__ gamma) {
    __shared__ float sx[256];
    int b = blockIdx.x, lane = threadIdx.x;
#pragma unroll
    for (int j = 0; j < 4; j++) sx[lane + 64 * j] = bf2f(x[b * 256 + lane + 64 * j]);
    __syncthreads();
    float acc = 0.f;
#pragma unroll 8
    for (int d = 0; d < 256; d++) acc += sx[d] * bf2f(Wv[d * 64 + lane]);
    acc += bf2f(bv[lane]);
    v[b * 64 + lane] = acc;
    vb[b * 64 + lane] = f2bf(acc);
    float sq = acc * acc;
#pragma unroll
    for (int d = 32; d >= 1; d >>= 1) sq += __shfl_xor(sq, d, 64);
    float pb = 0.f, pg = 0.f;
#pragma unroll
    for (int j = 0; j < 4; j++) {
        float xv = sx[lane + 64 * j];
        pb += xv * bf2f(Wb[lane + 64 * j]);
        pg += xv * bf2f(Wg[lane + 64 * j]);
    }
#pragma unroll
    for (int d = 32; d >= 1; d >>= 1) { pb += __shfl_xor(pb, d, 64); pg += __shfl_xor(pg, d, 64); }
    if (lane == 0) {
        float vn = sqrtf(sq);
        float zb = pb + bf2f(bb[0]);
        float zg = pg + bf2f(bg[0]);
        float be = (zb > 20.f) ? zb : log1pf(__expf(zb));
        beta[b]  = be;
        bovn[b]  = be / (vn + 1e-16f);
        gamma[b] = 1.f + ((zg > 20.f) ? zg : log1pf(__expf(zg)));
    }
}

// ---------------- K2: mem row inverse norms ----------------
__global__ __launch_bounds__(256) void k_mn(const unsigned short* __restrict__ mem, float* __restrict__ invmn) {
    int lane = threadIdx.x & 63;
    int gw = blockIdx.x * 4 + (threadIdx.x >> 6);
    for (int row = gw; row < R_; row += 256) {
        float m = bf2f(mem[row * 64 + lane]);
        float s = m * m;
#pragma unroll
        for (int d = 32; d >= 1; d >>= 1) s += __shfl_xor(s, d, 64);
        if (lane == 0) invmn[row] = 1.0f / (sqrtf(s) + 1e-16f);
    }
}

// ---------------- K3: sim MFMA -> E = exp(acc*bovn*invmn - beta), S[b] ----------
__global__ __launch_bounds__(256, 8) void k_sim(const unsigned short* __restrict__ vb,
        const unsigned short* __restrict__ mem,
        const float* __restrict__ bovn, const float* __restrict__ invmn,
        const float* __restrict__ beta,
        unsigned short* __restrict__ E, float* __restrict__ S) {
    __shared__ unsigned short etile[64][132];
    __shared__ float sred[4][64];
    int bx = blockIdx.x;
    int rc = bx & 127, tb = bx >> 7;
    int t = threadIdx.x, wv = t >> 6, l = t & 63;
    int lane15 = l & 15, quad = l >> 4;
    int rr0 = rc * 128 + wv * 32 + lane15;
    bf16x8 bm[2][2];
    float im[2];
#pragma unroll
    for (int nt = 0; nt < 2; nt++) {
        int rr = rr0 + nt * 16;
        bm[nt][0] = ld_bf8(mem + rr * 64 + quad * 8);
        bm[nt][1] = ld_bf8(mem + rr * 64 + 32 + quad * 8);
        im[nt] = invmn[rr];
    }
    bf16x8 afr[4][2];
    float bvl[4][4], bel[4][4];
#pragma unroll
    for (int m = 0; m < 4; m++) {
        int brow = tb * 64 + m * 16 + lane15;
        afr[m][0] = ld_bf8(vb + brow * 64 + quad * 8);
        afr[m][1] = ld_bf8(vb + brow * 64 + 32 + quad * 8);
#pragma unroll
        for (int reg = 0; reg < 4; reg++) {
            int b2 = tb * 64 + m * 16 + quad * 4 + reg;
            bvl[m][reg] = bovn[b2];
            bel[m][reg] = beta[b2];
        }
    }
    float sp[4][4];
#pragma unroll
    for (int m = 0; m < 4; m++)
#pragma unroll
        for (int r = 0; r < 4; r++) sp[m][r] = 0.f;

#pragma unroll
    for (int nt = 0; nt < 2; nt++) {
        int rl = wv * 32 + nt * 16 + lane15;
#pragma unroll
        for (int m = 0; m < 4; m++) {
            f32x4 acc = (f32x4){0.f, 0.f, 0.f, 0.f};
            acc = mfma16(afr[m][0], bm[nt][0], acc);
            acc = mfma16(afr[m][1], bm[nt][1], acc);
#pragma unroll
            for (int reg = 0; reg < 4; reg++) {
                float e = __expf(acc[reg] * (bvl[m][reg] * im[nt]) - bel[m][reg]);
                sp[m][reg] += e;
                etile[m * 16 + quad * 4 + reg][rl] = f2bf(e);
            }
        }
    }
#pragma unroll
    for (int m = 0; m < 4; m++)
#pragma unroll
        for (int reg = 0; reg < 4; reg++) {
            float s = sp[m][reg];
            s += __shfl_xor(s, 1, 64); s += __shfl_xor(s, 2, 64);
            s += __shfl_xor(s, 4, 64); s += __shfl_xor(s, 8, 64);
            if (lane15 == 0) sred[wv][m * 16 + quad * 4 + reg] = s;
        }
    __syncthreads();
#pragma unroll
    for (int j = 0; j < 4; j++) {
        int idx8 = t + j * 256;
        int row = idx8 >> 4;
        int c8 = (idx8 & 15) * 8;
        *(bf16x8*)(E + (size_t)(tb * 64 + row) * R_ + rc * 128 + c8) =
            *(const bf16x8*)&etile[row][c8];
    }
    if (t < 64)
        atomicAdd(&S[tb * 64 + t], sred[0][t] + sred[1][t] + sred[2][t] + sred[3][t]);
}

// ---------------- K4: conv+pow -> AT [R,B] (transposed!), T[b] ----------------
// Thread t owns row b = t>>2 and a contiguous run of 32 r's (base = (t&3)*32).
// Rolling el/ec/er window -> 1 new LDS read per element, no boundary ternaries
// (halo staged in-tile: col 128 = right halo, col 130 = left halo).
// T-reduction: per-thread scalar accumulator + 2 shfl_xor across the 4 threads
// sharing a b (was: 6 shuffles PER ELEMENT + LDS atomics).
// pow via __builtin_amdgcn_exp2f(g*log2(wc)) -- v_exp_f32 IS 2^x on gfx950.
__global__ __launch_bounds__(256) void k_conv(const unsigned short* __restrict__ E,
        unsigned short* __restrict__ AT,
        const float* __restrict__ S, const float* __restrict__ gamma,
        const unsigned short* __restrict__ conv_k, const unsigned short* __restrict__ conv_b,
        float* __restrict__ T) {
    __shared__ unsigned short ein[64][132];   // cols 0..127: r0..r0+127; 128: right halo; 130: left halo
    __shared__ unsigned short aout[128][68];
    float k0 = bf2f(conv_k[0]), k1 = bf2f(conv_k[1]), k2 = bf2f(conv_k[2]);
    float cb = bf2f(conv_b[0]);
    int b0 = (blockIdx.x >> 7) * 64;
    int r0 = (blockIdx.x & 127) * 128;
    int t = threadIdx.x;
    // stage main tile (coalesced ushort4)
#pragma unroll
    for (int j = 0; j < 8; j++) {
        int idx4 = t + j * 256;
        int row = idx4 >> 5, c4 = (idx4 & 31) * 4;
        *(ushort4*)&ein[row][c4] = *(const ushort4*)(E + (b0 + row) * R_ + r0 + c4);
    }
    // halos
    if (t < 64) {
        ein[t][130] = (r0 > 0) ? E[(b0 + t) * R_ + r0 - 1] : (unsigned short)0;
    } else if (t < 128) {
        int tb = t - 64;
        ein[tb][128] = (r0 + 128 < R_) ? E[(b0 + tb) * R_ + r0 + 128] : (unsigned short)0;
    }
    int b = t >> 2;
    int base = (t & 3) * 32;
    float sS_ = 1.0f / S[b0 + b];
    float g = gamma[b0 + b];
    __syncthreads();

    float el = bf2f((base == 0) ? ein[b][130] : ein[b][base - 1]);
    float ec = bf2f(ein[b][base]);
    float tacc = 0.f;
#pragma unroll
    for (int i = 0; i < 32; i++) {
        float er = bf2f(ein[b][base + 1 + i]);
        float wc = (k0 * el + k1 * ec + k2 * er) * sS_ + cb;
        wc = fmaxf(wc, 1e-30f);
        float au = __builtin_amdgcn_exp2f(g * __log2f(wc));
        aout[base + i][b] = f2bf(au);
        tacc += au;
        el = ec; ec = er;
    }
    tacc += __shfl_xor(tacc, 1, 64);
    tacc += __shfl_xor(tacc, 2, 64);
    if ((t & 3) == 0) atomicAdd(&T[b0 + b], tacc);
    __syncthreads();
#pragma unroll
    for (int j = 0; j < 8; j++) {
        int idx4 = t + j * 256;
        int rrow = idx4 >> 4, c4 = (idx4 & 15) * 4;
        *(ushort4*)(AT + (size_t)(r0 + rrow) * B_ + b0 + c4) = *(ushort4*)&aout[rrow][c4];
    }
}

// ---------------- K4b: build vp' [80,1024] bf16 ----------------
__global__ __launch_bounds__(256) void k_vp2(const float* __restrict__ v, const float* __restrict__ T,
                                             unsigned short* __restrict__ vpb) {
    int idx = blockIdx.x * 256 + threadIdx.x;
    int m = idx >> 10, b = idx & 1023;
    float s = 1.0f / ((T[b] + (float)R_ * 1e-16f) * (float)B_);
    float val = (m < 64) ? v[b * 64 + m] * s : ((m == 64) ? s : 0.f);
    vpb[idx] = f2bf(val);
}

// ---------------- K5: MFMA GEMM mem2T = mem*(1-er) + vp'^ AT ----------------
__global__ __launch_bounds__(256) void k_add(const unsigned short* __restrict__ AT,
        const unsigned short* __restrict__ vpb,
        const unsigned short* __restrict__ memb, unsigned short* __restrict__ mem2T) {
    __shared__ unsigned short smem[64][68];
    __shared__ unsigned short sm2[64][68];
    int r0 = blockIdx.x * 64;
    int t = threadIdx.x, wv = t >> 6, l = t & 63;
    int lane15 = l & 15, quad = l >> 4;
#pragma unroll
    for (int j = 0; j < 4; j++) {
        int idx4 = t + j * 256;
        int rl = idx4 >> 4, w4 = (idx4 & 15) * 4;
        *(ushort4*)&smem[rl][w4] = *(const ushort4*)(memb + (r0 + rl) * 64 + w4);
    }
    __syncthreads();

    const unsigned short* Brow = AT + (size_t)(r0 + wv * 16 + lane15) * B_ + quad * 8;
    const unsigned short* A0 = vpb + (0 * 16 + lane15) * B_ + quad * 8;
    const unsigned short* A1 = vpb + (1 * 16 + lane15) * B_ + quad * 8;
    const unsigned short* A2 = vpb + (2 * 16 + lane15) * B_ + quad * 8;
    const unsigned short* A3 = vpb + (3 * 16 + lane15) * B_ + quad * 8;
    const unsigned short* A4 = vpb + (4 * 16 + lane15) * B_ + quad * 8;
    f32x4 acc0 = {0,0,0,0}, acc1 = {0,0,0,0}, acc2 = {0,0,0,0}, acc3 = {0,0,0,0}, acc4 = {0,0,0,0};
#pragma unroll 4
    for (int k0 = 0; k0 < B_; k0 += 32) {
        bf16x8 bf = ld_bf8(Brow + k0);
        acc0 = mfma16(ld_bf8(A0 + k0), bf, acc0);
        acc1 = mfma16(ld_bf8(A1 + k0), bf, acc1);
        acc2 = mfma16(ld_bf8(A2 + k0), bf, acc2);
        acc3 = mfma16(ld_bf8(A3 + k0), bf, acc3);
        acc4 = mfma16(ld_bf8(A4 + k0), bf, acc4);
    }
    float er = __shfl(acc4[0], l & 15, 64);
    float ome = 1.f - er;
    f32x4 accs[4] = {acc0, acc1, acc2, acc3};
#pragma unroll
    for (int mt = 0; mt < 4; mt++) {
#pragma unroll
        for (int reg = 0; reg < 4; reg++) {
            int w = mt * 16 + quad * 4 + reg;
            int rl = wv * 16 + lane15;
            float m2 = bf2f(smem[rl][w]) * ome + accs[mt][reg];
            sm2[w][rl] = f2bf(m2);
        }
    }
    __syncthreads();
#pragma unroll
    for (int j = 0; j < 4; j++) {
        int idx4 = t + j * 256;
        int w = idx4 >> 4, r4 = (idx4 & 15) * 4;
        *(ushort4*)(mem2T + (size_t)w * R_ + r0 + r4) = *(ushort4*)&sm2[w][r4];
    }
}

// ---------------- K6: flash read head, fused-PV, NO GLOBAL ATOMICS -----------
// R6 structure (XCD swizzle, double-buffered bstage, 1 barrier/phase, fused PV)
// with the output atomics replaced by non-atomic partials:
//   pacc[rc][b][w]  (64 x 1024 x 64 fp32 = 16.8 MB, reuses AT's arena slot --
//                    AT is dead after k_add)
//   Spp[rc][b]      (64 x 1024 fp32, reuses outacc's slot)
// Rationale (R6 post-mortem): 4.2M device-scope fp32 atomicAdds were the
// ~45us floor common to R0/R2/R4/R6 -- cross-XCD coherence pushes each RMW to
// the memory side (WRITE_SIZE ~= atomic_count x 4B). Each (rc,tb) block owns
// its 64x64 tile exclusively -> plain coalesced stores; k_out does the 64-way
// rc reduction (17 MB streaming read, ~3us).
__global__ __launch_bounds__(256, 4) void k_read(const unsigned short* __restrict__ x,
        const unsigned short* __restrict__ WpT, const unsigned short* __restrict__ bp,
        const unsigned short* __restrict__ mem2T,
        float* __restrict__ pacc, float* __restrict__ Spp) {
    __shared__ unsigned short bstage[2][32 * 264];
    __shared__ unsigned short ptile[4][16 * 40];
    int bx = blockIdx.x;
    int xcd = bx & 7, grp = bx >> 3;
    int rc = xcd * 8 + (grp >> 4), tb = grp & 15;
    int t = threadIdx.x, wv = t >> 6, l = t & 63;
    int lane15 = l & 15, quad = l >> 4;
    int brow = tb * 64 + wv * 16 + lane15;
    bf16x8 afr[8];
#pragma unroll
    for (int kk = 0; kk < 8; kk++)
        afr[kk] = ld_bf8(x + brow * 256 + kk * 32 + quad * 8);
    f32x4 accO[4];
#pragma unroll
    for (int nt = 0; nt < 4; nt++) accO[nt] = (f32x4){0.f, 0.f, 0.f, 0.f};
    float sp[4] = {0.f, 0.f, 0.f, 0.f};
    unsigned short* ptw = &ptile[wv][0];

    int srow = t >> 3, scg = (t & 7) * 8;
    bf16x8 pf[4];
    {   // prefetch phase 0 staging
        const unsigned short* src = WpT + (size_t)(rc * 256 + srow) * 256 + scg;
#pragma unroll
        for (int j = 0; j < 4; j++) pf[j] = *(const bf16x8*)(src + 64 * j);
    }
    const unsigned short* vrow = mem2T + (size_t)lane15 * R_ + rc * 256 + quad * 8;

    for (int ss = 0; ss < 8; ss++) {
        unsigned short* bcur = bstage[ss & 1];
        {   // commit prefetched rows, then issue next phase's loads
            unsigned short* dst = bcur + srow * 264 + scg;
#pragma unroll
            for (int j = 0; j < 4; j++) *(bf16x8*)(dst + 64 * j) = pf[j];
        }
        if (ss < 7) {
            const unsigned short* src = WpT
                + (size_t)(rc * 256 + (ss + 1) * 32 + srow) * 256 + scg;
#pragma unroll
            for (int j = 0; j < 4; j++) pf[j] = *(const bf16x8*)(src + 64 * j);
        }
        __syncthreads();
        // V fragments for this k-slice; L2-resident, lands under the QK MFMAs
        bf16x8 vv0 = ld_bf8(vrow + (size_t)0 * 16 * R_ + ss * 32);
        bf16x8 vv1 = ld_bf8(vrow + (size_t)1 * 16 * R_ + ss * 32);
        bf16x8 vv2 = ld_bf8(vrow + (size_t)2 * 16 * R_ + ss * 32);
        bf16x8 vv3 = ld_bf8(vrow + (size_t)3 * 16 * R_ + ss * 32);
        int rbase = rc * 256 + ss * 32;
#pragma unroll
        for (int nt = 0; nt < 2; nt++) {
            f32x4 acc = (f32x4){0.f, 0.f, 0.f, 0.f};
            const unsigned short* bb = bcur + (nt * 16 + lane15) * 264 + quad * 8;
#pragma unroll
            for (int kk = 0; kk < 8; kk++) {
                bf16x8 bfr = *(const bf16x8*)(bb + kk * 32);
                acc = mfma16(afr[kk], bfr, acc);
            }
            int rr = rbase + nt * 16 + lane15;
            float bpv = bf2f(bp[rr]);
#pragma unroll
            for (int reg = 0; reg < 4; reg++) {
                float e = __expf(acc[reg] + bpv);
                unsigned short ue = f2bf(e);
                sp[reg] += bf2f(ue);   // match PV numerator quantization
                ptw[(quad * 4 + reg) * 40 + nt * 16 + lane15] = ue;
            }
        }
        // wave-private transpose readback -> PV A-fragment for this k-slice
        bf16x8 pa = *(const bf16x8*)(ptw + lane15 * 40 + quad * 8);
        accO[0] = mfma16(pa, vv0, accO[0]);
        accO[1] = mfma16(pa, vv1, accO[1]);
        accO[2] = mfma16(pa, vv2, accO[2]);
        accO[3] = mfma16(pa, vv3, accO[3]);
    }
    // non-atomic partial writes: this block is the sole writer of (rc, b-tile)
#pragma unroll
    for (int nt = 0; nt < 4; nt++) {
        int wcol = nt * 16 + lane15;
#pragma unroll
        for (int reg = 0; reg < 4; reg++) {
            int b2 = tb * 64 + wv * 16 + quad * 4 + reg;
            pacc[((size_t)rc * B_ + b2) * 64 + wcol] = accO[nt][reg];
        }
    }
#pragma unroll
    for (int reg = 0; reg < 4; reg++) {
        float s = sp[reg];
        s += __shfl_xor(s, 1, 64); s += __shfl_xor(s, 2, 64);
        s += __shfl_xor(s, 4, 64); s += __shfl_xor(s, 8, 64);
        if (lane15 == 0) {
            int b2 = tb * 64 + wv * 16 + quad * 4 + reg;
            Spp[(size_t)rc * B_ + b2] = s;
        }
    }
}

// ---------------- K7: out = (sum_rc pacc) / (sum_rc Spp) -> FP32 --------------
__global__ __launch_bounds__(256) void k_out(const float* __restrict__ pacc,
                                             const float* __restrict__ Spp,
                                             float* __restrict__ out) {
    int idx = blockIdx.x * 256 + threadIdx.x;   // 65536 elements
    int b = idx >> 6;
    float acc = 0.f, sps = 0.f;
#pragma unroll 8
    for (int rc = 0; rc < 64; rc++) {
        acc += pacc[(size_t)rc * (B_ * 64) + idx];
        sps += Spp[rc * B_ + b];
    }
    out[idx] = acc / sps;
}

extern "C" void kernel_launch(void* const* d_in, const int* in_sizes, int n_in,
                              void* d_out, int out_size, void* d_ws, size_t ws_size,
                              hipStream_t stream) {
    (void)n_in; (void)out_size;
    float* outp = (float*)d_out;

    char* ws = (char*)d_ws;
    size_t o = 0;
    unsigned short* arena = (unsigned short*)(ws + o); o += (size_t)AO_TOT * 2;
    unsigned short* WpT = (unsigned short*)(ws + o); o += (size_t)R_ * D_ * 2;
    unsigned short* E   = (unsigned short*)(ws + o); o += (size_t)B_ * R_ * 2;
    unsigned short* AT  = (unsigned short*)(ws + o); o += (size_t)B_ * R_ * 2;
    float* v            = (float*)(ws + o);          o += (size_t)B_ * 64 * 4;
    unsigned short* vb  = (unsigned short*)(ws + o); o += (size_t)B_ * 64 * 2;
    unsigned short* vpb = (unsigned short*)(ws + o); o += (size_t)80 * B_ * 2;
    float* invmn        = (float*)(ws + o);          o += (size_t)R_ * 4;
    float* bovn         = (float*)(ws + o);          o += 4096;
    float* beta         = (float*)(ws + o);          o += 4096;
    float* gamma        = (float*)(ws + o);          o += 4096;
    unsigned short* m2T = (unsigned short*)(ws + o); o += (size_t)R_ * 64 * 2;
    float* zbase  = (float*)(ws + o);
    float* S      = (float*)(ws + o);                o += 4096;
    float* T      = (float*)(ws + o);                o += 4096;
    float* Sp     = (float*)(ws + o);                o += 4096;  (void)Sp;
    float* Spp    = (float*)(ws + o);                o += (size_t)B_ * 64 * 4;
    // pacc (64 x 1024 x 64 fp32 = 16.8 MB) reuses AT's slot (AT dead after k_add)
    float* pacc = (float*)AT;

    if (ws_size < o) {
        k_sentinel<<<256, 256, 0, stream>>>(outp, 1000.0f);
        return;
    }
    if (in_sizes[0] != B_ * D_ || in_sizes[7] != D_ * R_ || in_sizes[11] != R_ * W_) {
        k_sentinel<<<256, 256, 0, stream>>>(outp, 2000.0f);
        return;
    }

    k_zero<<<268, 256, 0, stream>>>(zbase);
    k_convert<<<(AO_TOT + 511) / 512, 256, 0, stream>>>(
        (const float*)d_in[0], (const float*)d_in[1], (const float*)d_in[2],
        (const float*)d_in[3], (const float*)d_in[4], (const float*)d_in[5],
        (const float*)d_in[6], (const float*)d_in[8],
        (const float*)d_in[9], (const float*)d_in[10], (const float*)d_in[11], arena);

    k_transpose_wp<<<dim3(256, 4), 256, 0, stream>>>((const float*)d_in[7], WpT);
    k_heads<<<1024, 64, 0, stream>>>(arena + AO_X, arena + AO_WV, arena + AO_BV,
                                     arena + AO_WB, arena + AO_BB, arena + AO_WG,
                                     arena + AO_BG, v, vb, bovn, beta, gamma);
    k_mn<<<64, 256, 0, stream>>>(arena + AO_MEM, invmn);
    k_sim<<<2048, 256, 0, stream>>>(vb, arena + AO_MEM, bovn, invmn, beta, E, S);
    k_conv<<<2048, 256, 0, stream>>>(E, AT, S, gamma, arena + AO_CK, arena + AO_CB, T);
    k_vp2<<<320, 256, 0, stream>>>(v, T, vpb);
    k_add<<<256, 256, 0, stream>>>(AT, vpb, arena + AO_MEM, m2T);
    k_read<<<1024, 256, 0, stream>>>(arena + AO_X, WpT, arena + AO_BP, m2T, pacc, Spp);
    k_out<<<256, 256, 0, stream>>>(pacc, Spp, outp);
}

// Round 8
// 220.634 us; speedup vs baseline: 1.6847x; 1.2131x over previous
//
#include <hip/hip_runtime.h>
#include <hip/hip_bf16.h>

#define B_ 1024
#define D_ 256
#define R_ 16384
#define W_ 64

typedef float f32x4 __attribute__((ext_vector_type(4)));
typedef __bf16 bf16x8 __attribute__((ext_vector_type(8)));

__device__ __forceinline__ float bf2f(unsigned short u) {
    union { unsigned int i; float f; } v; v.i = ((unsigned int)u) << 16; return v.f;
}
__device__ __forceinline__ unsigned short f2bf(float f) {
    union { float fv; unsigned int i; } v; v.fv = f;
    unsigned int r = v.i + 0x7FFFu + ((v.i >> 16) & 1u);
    return (unsigned short)(r >> 16);
}
__device__ __forceinline__ f32x4 mfma16(bf16x8 a, bf16x8 b, f32x4 c) {
    return __builtin_amdgcn_mfma_f32_16x16x32_bf16(a, b, c, 0, 0, 0);
}
__device__ __forceinline__ bf16x8 ld_bf8(const unsigned short* p) {
    return *(const bf16x8*)p;
}
__device__ __forceinline__ float sumsq8(bf16x8 v) {
    union { bf16x8 v; unsigned short u[8]; } c; c.v = v;
    float s = 0.f;
#pragma unroll
    for (int j = 0; j < 8; j++) { float f = bf2f(c.u[j]); s += f * f; }
    return s;
}

// ---------------- arena element offsets (each segment start 16-elem aligned) ----
// Wp is not staged through the arena: k_transpose_wp reads the fp32 input
// directly and emits bf16 WpT (saves ~17 MB of convert round-trip).
#define AO_X     0
#define AO_WV    262144
#define AO_BV    278528
#define AO_WB    278592
#define AO_BB    278848
#define AO_WG    278864
#define AO_BG    279120
#define AO_BP    279136
#define AO_CK    295520
#define AO_CB    295536
#define AO_MEM   295552
#define AO_TOT   1344128

__global__ __launch_bounds__(256) void k_sentinel(float* __restrict__ out, float val) {
    out[blockIdx.x * 256 + threadIdx.x] = val;
}

// ---------------- K-convert: fp32 inputs -> bf16 arena (no Wp) ----------------
// Also zeroes the S,T atomic accumulators (zst = S; T is contiguous after S),
// killing the separate k_zero dispatch.
__global__ __launch_bounds__(256) void k_convert(
        const float* x, const float* Wv, const float* bv, const float* Wb, const float* bb,
        const float* Wg, const float* bg, const float* bp,
        const float* ck, const float* cb, const float* mem,
        unsigned short* __restrict__ dst, float* __restrict__ zst) {
    int base = blockIdx.x * 512 + threadIdx.x;
#pragma unroll
    for (int h = 0; h < 2; h++) {
        int idx = base + h * 256;
        if (idx >= AO_TOT) continue;
        if (idx < 2048) zst[idx] = 0.f;   // S[1024] + T[1024]
        const float* p; int st; int n;
        if      (idx >= AO_MEM) { p = mem; st = AO_MEM; n = R_ * W_; }
        else if (idx >= AO_CB)  { p = cb;  st = AO_CB;  n = 1; }
        else if (idx >= AO_CK)  { p = ck;  st = AO_CK;  n = 3; }
        else if (idx >= AO_BP)  { p = bp;  st = AO_BP;  n = R_; }
        else if (idx >= AO_BG)  { p = bg;  st = AO_BG;  n = 1; }
        else if (idx >= AO_WG)  { p = Wg;  st = AO_WG;  n = D_; }
        else if (idx >= AO_BB)  { p = bb;  st = AO_BB;  n = 1; }
        else if (idx >= AO_WB)  { p = Wb;  st = AO_WB;  n = D_; }
        else if (idx >= AO_BV)  { p = bv;  st = AO_BV;  n = W_; }
        else if (idx >= AO_WV)  { p = Wv;  st = AO_WV;  n = D_ * W_; }
        else                    { p = x;   st = AO_X;   n = B_ * D_; }
        int local = idx - st;
        dst[idx] = (local < n) ? f2bf(p[local]) : (unsigned short)0;
    }
}

// ---------------- K0: transpose+convert Wp fp32 [D,R] -> WpT bf16 [R,D] --------
__global__ __launch_bounds__(256) void k_transpose_wp(const float* __restrict__ Wp,
                                                      unsigned short* __restrict__ WpT) {
    __shared__ unsigned short tile[64][66];
    int r0 = blockIdx.x * 64, d0 = blockIdx.y * 64;
    int t = threadIdx.x, lane = t & 63, wv = t >> 6;
#pragma unroll
    for (int i = 0; i < 16; i++) {
        int dl = wv + 4 * i;
        tile[dl][lane] = f2bf(Wp[(size_t)(d0 + dl) * R_ + r0 + lane]);
    }
    __syncthreads();
#pragma unroll
    for (int i = 0; i < 16; i++) {
        int rl = wv + 4 * i;
        WpT[(size_t)(r0 + rl) * D_ + d0 + lane] = tile[lane][rl];
    }
}

// ---------------- K1: controller heads: v, vb, bovn=beta/vn, beta, gamma ----------
__global__ __launch_bounds__(64) void k_heads(const unsigned short* __restrict__ x,
        const unsigned short* __restrict__ Wv, const unsigned short* __restrict__ bv,
        const unsigned short* __restrict__ Wb, const unsigned short* __restrict__ bb,
        const unsigned short* __restrict__ Wg, const unsigned short* __restrict__ bg,
        float* __restrict__ v, unsigned short* __restrict__ vb,
        float* __restrict__ bovn, float* __restrict__ beta, float* __restrict__ gamma) {
    __shared__ float sx[256];
    int b = blockIdx.x, lane = threadIdx.x;
#pragma unroll
    for (int j = 0; j < 4; j++) sx[lane + 64 * j] = bf2f(x[b * 256 + lane + 64 * j]);
    __syncthreads();
    float acc = 0.f;
#pragma unroll 8
    for (int d = 0; d < 256; d++) acc += sx[d] * bf2f(Wv[d * 64 + lane]);
    acc += bf2f(bv[lane]);
    v[b * 64 + lane] = acc;
    vb[b * 64 + lane] = f2bf(acc);
    float sq = acc * acc;
#pragma unroll
    for (int d = 32; d >= 1; d >>= 1) sq += __shfl_xor(sq, d, 64);
    float pb = 0.f, pg = 0.f;
#pragma unroll
    for (int j = 0; j < 4; j++) {
        float xv = sx[lane + 64 * j];
        pb += xv * bf2f(Wb[lane + 64 * j]);
        pg += xv * bf2f(Wg[lane + 64 * j]);
    }
#pragma unroll
    for (int d = 32; d >= 1; d >>= 1) { pb += __shfl_xor(pb, d, 64); pg += __shfl_xor(pg, d, 64); }
    if (lane == 0) {
        float vn = sqrtf(sq);
        float zb = pb + bf2f(bb[0]);
        float zg = pg + bf2f(bg[0]);
        float be = (zb > 20.f) ? zb : log1pf(__expf(zb));
        beta[b]  = be;
        bovn[b]  = be / (vn + 1e-16f);
        gamma[b] = 1.f + ((zg > 20.f) ? zg : log1pf(__expf(zg)));
    }
}

// ---------------- K3: sim MFMA -> E = exp(acc*bovn*invmn - beta), S[b] ----------
// invmn computed INLINE from the already-loaded bm fragments (row sum-of-squares
// + 2 shfl_xor across the quad axis) -- kills the separate k_mn dispatch+pass.
__global__ __launch_bounds__(256, 8) void k_sim(const unsigned short* __restrict__ vb,
        const unsigned short* __restrict__ mem,
        const float* __restrict__ bovn,
        const float* __restrict__ beta,
        unsigned short* __restrict__ E, float* __restrict__ S) {
    __shared__ unsigned short etile[64][132];
    __shared__ float sred[4][64];
    int bx = blockIdx.x;
    int rc = bx & 127, tb = bx >> 7;
    int t = threadIdx.x, wv = t >> 6, l = t & 63;
    int lane15 = l & 15, quad = l >> 4;
    int rr0 = rc * 128 + wv * 32 + lane15;
    bf16x8 bm[2][2];
    float im[2];
#pragma unroll
    for (int nt = 0; nt < 2; nt++) {
        int rr = rr0 + nt * 16;
        bm[nt][0] = ld_bf8(mem + rr * 64 + quad * 8);
        bm[nt][1] = ld_bf8(mem + rr * 64 + 32 + quad * 8);
        float sq = sumsq8(bm[nt][0]) + sumsq8(bm[nt][1]);
        sq += __shfl_xor(sq, 16, 64);
        sq += __shfl_xor(sq, 32, 64);
        im[nt] = 1.0f / (sqrtf(sq) + 1e-16f);
    }
    bf16x8 afr[4][2];
    float bvl[4][4], bel[4][4];
#pragma unroll
    for (int m = 0; m < 4; m++) {
        int brow = tb * 64 + m * 16 + lane15;
        afr[m][0] = ld_bf8(vb + brow * 64 + quad * 8);
        afr[m][1] = ld_bf8(vb + brow * 64 + 32 + quad * 8);
#pragma unroll
        for (int reg = 0; reg < 4; reg++) {
            int b2 = tb * 64 + m * 16 + quad * 4 + reg;
            bvl[m][reg] = bovn[b2];
            bel[m][reg] = beta[b2];
        }
    }
    float sp[4][4];
#pragma unroll
    for (int m = 0; m < 4; m++)
#pragma unroll
        for (int r = 0; r < 4; r++) sp[m][r] = 0.f;

#pragma unroll
    for (int nt = 0; nt < 2; nt++) {
        int rl = wv * 32 + nt * 16 + lane15;
#pragma unroll
        for (int m = 0; m < 4; m++) {
            f32x4 acc = (f32x4){0.f, 0.f, 0.f, 0.f};
            acc = mfma16(afr[m][0], bm[nt][0], acc);
            acc = mfma16(afr[m][1], bm[nt][1], acc);
#pragma unroll
            for (int reg = 0; reg < 4; reg++) {
                float e = __expf(acc[reg] * (bvl[m][reg] * im[nt]) - bel[m][reg]);
                sp[m][reg] += e;
                etile[m * 16 + quad * 4 + reg][rl] = f2bf(e);
            }
        }
    }
#pragma unroll
    for (int m = 0; m < 4; m++)
#pragma unroll
        for (int reg = 0; reg < 4; reg++) {
            float s = sp[m][reg];
            s += __shfl_xor(s, 1, 64); s += __shfl_xor(s, 2, 64);
            s += __shfl_xor(s, 4, 64); s += __shfl_xor(s, 8, 64);
            if (lane15 == 0) sred[wv][m * 16 + quad * 4 + reg] = s;
        }
    __syncthreads();
#pragma unroll
    for (int j = 0; j < 4; j++) {
        int idx8 = t + j * 256;
        int row = idx8 >> 4;
        int c8 = (idx8 & 15) * 8;
        *(bf16x8*)(E + (size_t)(tb * 64 + row) * R_ + rc * 128 + c8) =
            *(const bf16x8*)&etile[row][c8];
    }
    if (t < 64)
        atomicAdd(&S[tb * 64 + t], sred[0][t] + sred[1][t] + sred[2][t] + sred[3][t]);
}

// ---------------- K4: conv+pow -> AT [R,B] (transposed!), T[b] ----------------
__global__ __launch_bounds__(256) void k_conv(const unsigned short* __restrict__ E,
        unsigned short* __restrict__ AT,
        const float* __restrict__ S, const float* __restrict__ gamma,
        const unsigned short* __restrict__ conv_k, const unsigned short* __restrict__ conv_b,
        float* __restrict__ T) {
    __shared__ unsigned short ein[64][132];   // cols 0..127: r0..r0+127; 128: right halo; 130: left halo
    __shared__ unsigned short aout[128][68];
    float k0 = bf2f(conv_k[0]), k1 = bf2f(conv_k[1]), k2 = bf2f(conv_k[2]);
    float cb = bf2f(conv_b[0]);
    int b0 = (blockIdx.x >> 7) * 64;
    int r0 = (blockIdx.x & 127) * 128;
    int t = threadIdx.x;
#pragma unroll
    for (int j = 0; j < 8; j++) {
        int idx4 = t + j * 256;
        int row = idx4 >> 5, c4 = (idx4 & 31) * 4;
        *(ushort4*)&ein[row][c4] = *(const ushort4*)(E + (b0 + row) * R_ + r0 + c4);
    }
    if (t < 64) {
        ein[t][130] = (r0 > 0) ? E[(b0 + t) * R_ + r0 - 1] : (unsigned short)0;
    } else if (t < 128) {
        int tb = t - 64;
        ein[tb][128] = (r0 + 128 < R_) ? E[(b0 + tb) * R_ + r0 + 128] : (unsigned short)0;
    }
    int b = t >> 2;
    int base = (t & 3) * 32;
    float sS_ = 1.0f / S[b0 + b];
    float g = gamma[b0 + b];
    __syncthreads();

    float el = bf2f((base == 0) ? ein[b][130] : ein[b][base - 1]);
    float ec = bf2f(ein[b][base]);
    float tacc = 0.f;
#pragma unroll
    for (int i = 0; i < 32; i++) {
        float er = bf2f(ein[b][base + 1 + i]);
        float wc = (k0 * el + k1 * ec + k2 * er) * sS_ + cb;
        wc = fmaxf(wc, 1e-30f);
        float au = __builtin_amdgcn_exp2f(g * __log2f(wc));
        aout[base + i][b] = f2bf(au);
        tacc += au;
        el = ec; ec = er;
    }
    tacc += __shfl_xor(tacc, 1, 64);
    tacc += __shfl_xor(tacc, 2, 64);
    if ((t & 3) == 0) atomicAdd(&T[b0 + b], tacc);
    __syncthreads();
#pragma unroll
    for (int j = 0; j < 8; j++) {
        int idx4 = t + j * 256;
        int rrow = idx4 >> 4, c4 = (idx4 & 15) * 4;
        *(ushort4*)(AT + (size_t)(r0 + rrow) * B_ + b0 + c4) = *(ushort4*)&aout[rrow][c4];
    }
}

// ---------------- K4b: build vp' [80,1024] bf16 ----------------
__global__ __launch_bounds__(256) void k_vp2(const float* __restrict__ v, const float* __restrict__ T,
                                             unsigned short* __restrict__ vpb) {
    int idx = blockIdx.x * 256 + threadIdx.x;
    int m = idx >> 10, b = idx & 1023;
    float s = 1.0f / ((T[b] + (float)R_ * 1e-16f) * (float)B_);
    float val = (m < 64) ? v[b * 64 + m] * s : ((m == 64) ? s : 0.f);
    vpb[idx] = f2bf(val);
}

// ---------------- K5: MFMA GEMM mem2T = mem*(1-er) + vp'^ AT ----------------
__global__ __launch_bounds__(256) void k_add(const unsigned short* __restrict__ AT,
        const unsigned short* __restrict__ vpb,
        const unsigned short* __restrict__ memb, unsigned short* __restrict__ mem2T) {
    __shared__ unsigned short smem[64][68];
    __shared__ unsigned short sm2[64][68];
    int r0 = blockIdx.x * 64;
    int t = threadIdx.x, wv = t >> 6, l = t & 63;
    int lane15 = l & 15, quad = l >> 4;
#pragma unroll
    for (int j = 0; j < 4; j++) {
        int idx4 = t + j * 256;
        int rl = idx4 >> 4, w4 = (idx4 & 15) * 4;
        *(ushort4*)&smem[rl][w4] = *(const ushort4*)(memb + (r0 + rl) * 64 + w4);
    }
    __syncthreads();

    const unsigned short* Brow = AT + (size_t)(r0 + wv * 16 + lane15) * B_ + quad * 8;
    const unsigned short* A0 = vpb + (0 * 16 + lane15) * B_ + quad * 8;
    const unsigned short* A1 = vpb + (1 * 16 + lane15) * B_ + quad * 8;
    const unsigned short* A2 = vpb + (2 * 16 + lane15) * B_ + quad * 8;
    const unsigned short* A3 = vpb + (3 * 16 + lane15) * B_ + quad * 8;
    const unsigned short* A4 = vpb + (4 * 16 + lane15) * B_ + quad * 8;
    f32x4 acc0 = {0,0,0,0}, acc1 = {0,0,0,0}, acc2 = {0,0,0,0}, acc3 = {0,0,0,0}, acc4 = {0,0,0,0};
#pragma unroll 4
    for (int k0 = 0; k0 < B_; k0 += 32) {
        bf16x8 bf = ld_bf8(Brow + k0);
        acc0 = mfma16(ld_bf8(A0 + k0), bf, acc0);
        acc1 = mfma16(ld_bf8(A1 + k0), bf, acc1);
        acc2 = mfma16(ld_bf8(A2 + k0), bf, acc2);
        acc3 = mfma16(ld_bf8(A3 + k0), bf, acc3);
        acc4 = mfma16(ld_bf8(A4 + k0), bf, acc4);
    }
    float er = __shfl(acc4[0], l & 15, 64);
    float ome = 1.f - er;
    f32x4 accs[4] = {acc0, acc1, acc2, acc3};
#pragma unroll
    for (int mt = 0; mt < 4; mt++) {
#pragma unroll
        for (int reg = 0; reg < 4; reg++) {
            int w = mt * 16 + quad * 4 + reg;
            int rl = wv * 16 + lane15;
            float m2 = bf2f(smem[rl][w]) * ome + accs[mt][reg];
            sm2[w][rl] = f2bf(m2);
        }
    }
    __syncthreads();
#pragma unroll
    for (int j = 0; j < 4; j++) {
        int idx4 = t + j * 256;
        int w = idx4 >> 4, r4 = (idx4 & 15) * 4;
        *(ushort4*)(mem2T + (size_t)w * R_ + r0 + r4) = *(ushort4*)&sm2[w][r4];
    }
}

// ---------------- K6: flash read head, relaxed-barrier pipeline --------------
// R7 structure (XCD swizzle, dbuf bstage, fused PV, non-atomic partials) with
// the KEY fix: __syncthreads() emits s_waitcnt vmcnt(0) before s_barrier,
// draining the next-phase register prefetch at EVERY barrier -- the exposed
// L2 latency was the ~40us floor common to R0..R7. Replaced with
// {lgkmcnt(0); s_barrier} (sched_barrier fenced): LDS writes are still drained
// for cross-wave visibility, but the in-flight global loads (register-only
// destinations) legally span the barrier; the compiler emits a counted vmcnt
// before the dependent ds_write of pf[] at the top of the next phase.
__global__ __launch_bounds__(256, 4) void k_read(const unsigned short* __restrict__ x,
        const unsigned short* __restrict__ WpT, const unsigned short* __restrict__ bp,
        const unsigned short* __restrict__ mem2T,
        float* __restrict__ pacc, float* __restrict__ Spp) {
    __shared__ unsigned short bstage[2][32 * 264];
    __shared__ unsigned short ptile[4][16 * 40];
    int bx = blockIdx.x;
    int xcd = bx & 7, grp = bx >> 3;
    int rc = xcd * 8 + (grp >> 4), tb = grp & 15;
    int t = threadIdx.x, wv = t >> 6, l = t & 63;
    int lane15 = l & 15, quad = l >> 4;
    int brow = tb * 64 + wv * 16 + lane15;
    bf16x8 afr[8];
#pragma unroll
    for (int kk = 0; kk < 8; kk++)
        afr[kk] = ld_bf8(x + brow * 256 + kk * 32 + quad * 8);
    f32x4 accO[4];
#pragma unroll
    for (int nt = 0; nt < 4; nt++) accO[nt] = (f32x4){0.f, 0.f, 0.f, 0.f};
    float sp[4] = {0.f, 0.f, 0.f, 0.f};
    unsigned short* ptw = &ptile[wv][0];

    int srow = t >> 3, scg = (t & 7) * 8;
    bf16x8 pf[4];
    {   // prefetch phase 0 staging
        const unsigned short* src = WpT + (size_t)(rc * 256 + srow) * 256 + scg;
#pragma unroll
        for (int j = 0; j < 4; j++) pf[j] = *(const bf16x8*)(src + 64 * j);
    }
    const unsigned short* vrow = mem2T + (size_t)lane15 * R_ + rc * 256 + quad * 8;

    for (int ss = 0; ss < 8; ss++) {
        unsigned short* bcur = bstage[ss & 1];
        {   // commit prefetched rows (counted vmcnt via register dep), then
            // issue next phase's loads -- they stay in flight across the barrier
            unsigned short* dst = bcur + srow * 264 + scg;
#pragma unroll
            for (int j = 0; j < 4; j++) *(bf16x8*)(dst + 64 * j) = pf[j];
        }
        if (ss < 7) {
            const unsigned short* src = WpT
                + (size_t)(rc * 256 + (ss + 1) * 32 + srow) * 256 + scg;
#pragma unroll
            for (int j = 0; j < 4; j++) pf[j] = *(const bf16x8*)(src + 64 * j);
        }
        // relaxed barrier: drain LDS (cross-wave visibility) but NOT vmem
        __builtin_amdgcn_sched_barrier(0);
        asm volatile("s_waitcnt lgkmcnt(0)" ::: "memory");
        __builtin_amdgcn_s_barrier();
        __builtin_amdgcn_sched_barrier(0);
        // V fragments for this k-slice; L2-resident, lands under the QK MFMAs
        bf16x8 vv0 = ld_bf8(vrow + (size_t)0 * 16 * R_ + ss * 32);
        bf16x8 vv1 = ld_bf8(vrow + (size_t)1 * 16 * R_ + ss * 32);
        bf16x8 vv2 = ld_bf8(vrow + (size_t)2 * 16 * R_ + ss * 32);
        bf16x8 vv3 = ld_bf8(vrow + (size_t)3 * 16 * R_ + ss * 32);
        int rbase = rc * 256 + ss * 32;
#pragma unroll
        for (int nt = 0; nt < 2; nt++) {
            f32x4 acc = (f32x4){0.f, 0.f, 0.f, 0.f};
            const unsigned short* bb = bcur + (nt * 16 + lane15) * 264 + quad * 8;
#pragma unroll
            for (int kk = 0; kk < 8; kk++) {
                bf16x8 bfr = *(const bf16x8*)(bb + kk * 32);
                acc = mfma16(afr[kk], bfr, acc);
            }
            int rr = rbase + nt * 16 + lane15;
            float bpv = bf2f(bp[rr]);
#pragma unroll
            for (int reg = 0; reg < 4; reg++) {
                float e = __expf(acc[reg] + bpv);
                unsigned short ue = f2bf(e);
                sp[reg] += bf2f(ue);   // match PV numerator quantization
                ptw[(quad * 4 + reg) * 40 + nt * 16 + lane15] = ue;
            }
        }
        // wave-private transpose readback -> PV A-fragment for this k-slice
        bf16x8 pa = *(const bf16x8*)(ptw + lane15 * 40 + quad * 8);
        accO[0] = mfma16(pa, vv0, accO[0]);
        accO[1] = mfma16(pa, vv1, accO[1]);
        accO[2] = mfma16(pa, vv2, accO[2]);
        accO[3] = mfma16(pa, vv3, accO[3]);
    }
    // non-atomic partial writes: this block is the sole writer of (rc, b-tile)
#pragma unroll
    for (int nt = 0; nt < 4; nt++) {
        int wcol = nt * 16 + lane15;
#pragma unroll
        for (int reg = 0; reg < 4; reg++) {
            int b2 = tb * 64 + wv * 16 + quad * 4 + reg;
            pacc[((size_t)rc * B_ + b2) * 64 + wcol] = accO[nt][reg];
        }
    }
#pragma unroll
    for (int reg = 0; reg < 4; reg++) {
        float s = sp[reg];
        s += __shfl_xor(s, 1, 64); s += __shfl_xor(s, 2, 64);
        s += __shfl_xor(s, 4, 64); s += __shfl_xor(s, 8, 64);
        if (lane15 == 0) {
            int b2 = tb * 64 + wv * 16 + quad * 4 + reg;
            Spp[(size_t)rc * B_ + b2] = s;
        }
    }
}

// ---------------- K7: out = (sum_rc pacc) / (sum_rc Spp) -> FP32 --------------
__global__ __launch_bounds__(256) void k_out(const float* __restrict__ pacc,
                                             const float* __restrict__ Spp,
                                             float* __restrict__ out) {
    int idx = blockIdx.x * 256 + threadIdx.x;   // 65536 elements
    int b = idx >> 6;
    float acc = 0.f, sps = 0.f;
#pragma unroll 8
    for (int rc = 0; rc < 64; rc++) {
        acc += pacc[(size_t)rc * (B_ * 64) + idx];
        sps += Spp[rc * B_ + b];
    }
    out[idx] = acc / sps;
}

extern "C" void kernel_launch(void* const* d_in, const int* in_sizes, int n_in,
                              void* d_out, int out_size, void* d_ws, size_t ws_size,
                              hipStream_t stream) {
    (void)n_in; (void)out_size;
    float* outp = (float*)d_out;

    char* ws = (char*)d_ws;
    size_t o = 0;
    unsigned short* arena = (unsigned short*)(ws + o); o += (size_t)AO_TOT * 2;
    unsigned short* WpT = (unsigned short*)(ws + o); o += (size_t)R_ * D_ * 2;
    unsigned short* E   = (unsigned short*)(ws + o); o += (size_t)B_ * R_ * 2;
    unsigned short* AT  = (unsigned short*)(ws + o); o += (size_t)B_ * R_ * 2;
    float* v            = (float*)(ws + o);          o += (size_t)B_ * 64 * 4;
    unsigned short* vb  = (unsigned short*)(ws + o); o += (size_t)B_ * 64 * 2;
    unsigned short* vpb = (unsigned short*)(ws + o); o += (size_t)80 * B_ * 2;
    float* invmn        = (float*)(ws + o);          o += (size_t)R_ * 4;  (void)invmn;
    float* bovn         = (float*)(ws + o);          o += 4096;
    float* beta         = (float*)(ws + o);          o += 4096;
    float* gamma        = (float*)(ws + o);          o += 4096;
    unsigned short* m2T = (unsigned short*)(ws + o); o += (size_t)R_ * 64 * 2;
    float* S      = (float*)(ws + o);                o += 4096;
    float* T      = (float*)(ws + o);                o += 4096;
    float* Sp     = (float*)(ws + o);                o += 4096;  (void)Sp;
    float* Spp    = (float*)(ws + o);                o += (size_t)B_ * 64 * 4;
    // pacc (64 x 1024 x 64 fp32 = 16.8 MB) reuses AT's slot (AT dead after k_add)
    float* pacc = (float*)AT;

    if (ws_size < o) {
        k_sentinel<<<256, 256, 0, stream>>>(outp, 1000.0f);
        return;
    }
    if (in_sizes[0] != B_ * D_ || in_sizes[7] != D_ * R_ || in_sizes[11] != R_ * W_) {
        k_sentinel<<<256, 256, 0, stream>>>(outp, 2000.0f);
        return;
    }

    k_convert<<<(AO_TOT + 511) / 512, 256, 0, stream>>>(
        (const float*)d_in[0], (const float*)d_in[1], (const float*)d_in[2],
        (const float*)d_in[3], (const float*)d_in[4], (const float*)d_in[5],
        (const float*)d_in[6], (const float*)d_in[8],
        (const float*)d_in[9], (const float*)d_in[10], (const float*)d_in[11],
        arena, S);

    k_transpose_wp<<<dim3(256, 4), 256, 0, stream>>>((const float*)d_in[7], WpT);
    k_heads<<<1024, 64, 0, stream>>>(arena + AO_X, arena + AO_WV, arena + AO_BV,
                                     arena + AO_WB, arena + AO_BB, arena + AO_WG,
                                     arena + AO_BG, v, vb, bovn, beta, gamma);
    k_sim<<<2048, 256, 0, stream>>>(vb, arena + AO_MEM, bovn, beta, E, S);
    k_conv<<<2048, 256, 0, stream>>>(E, AT, S, gamma, arena + AO_CK, arena + AO_CB, T);
    k_vp2<<<320, 256, 0, stream>>>(v, T, vpb);
    k_add<<<256, 256, 0, stream>>>(AT, vpb, arena + AO_MEM, m2T);
    k_read<<<1024, 256, 0, stream>>>(arena + AO_X, WpT, arena + AO_BP, m2T, pacc, Spp);
    k_out<<<256, 256, 0, stream>>>(pacc, Spp, outp);
}

// Round 9
// 217.404 us; speedup vs baseline: 1.7097x; 1.0149x over previous
//
#include <hip/hip_runtime.h>
#include <hip/hip_bf16.h>

#define B_ 1024
#define D_ 256
#define R_ 16384
#define W_ 64

typedef float f32x4 __attribute__((ext_vector_type(4)));
typedef __bf16 bf16x8 __attribute__((ext_vector_type(8)));

__device__ __forceinline__ float bf2f(unsigned short u) {
    union { unsigned int i; float f; } v; v.i = ((unsigned int)u) << 16; return v.f;
}
__device__ __forceinline__ unsigned short f2bf(float f) {
    union { float fv; unsigned int i; } v; v.fv = f;
    unsigned int r = v.i + 0x7FFFu + ((v.i >> 16) & 1u);
    return (unsigned short)(r >> 16);
}
__device__ __forceinline__ float rt(float f) {   // bf16 round-trip (matches arena path)
    return bf2f(f2bf(f));
}
__device__ __forceinline__ f32x4 mfma16(bf16x8 a, bf16x8 b, f32x4 c) {
    return __builtin_amdgcn_mfma_f32_16x16x32_bf16(a, b, c, 0, 0, 0);
}
__device__ __forceinline__ bf16x8 ld_bf8(const unsigned short* p) {
    return *(const bf16x8*)p;
}
__device__ __forceinline__ float sumsq8(bf16x8 v) {
    union { bf16x8 v; unsigned short u[8]; } c; c.v = v;
    float s = 0.f;
#pragma unroll
    for (int j = 0; j < 8; j++) { float f = bf2f(c.u[j]); s += f * f; }
    return s;
}

// ---------------- arena element offsets (each segment start 16-elem aligned) ----
#define AO_X     0
#define AO_WV    262144
#define AO_BV    278528
#define AO_WB    278592
#define AO_BB    278848
#define AO_WG    278864
#define AO_BG    279120
#define AO_BP    279136
#define AO_CK    295520
#define AO_CB    295536
#define AO_MEM   295552
#define AO_TOT   1344128

#define NB_CONV  ((AO_TOT + 511) / 512)
#define NB_TR    1024
#define NB_HEADS 256

__global__ __launch_bounds__(256) void k_sentinel(float* __restrict__ out, float val) {
    out[blockIdx.x * 256 + threadIdx.x] = val;
}

// ---------------- K-prep: 3 independent roles in ONE dispatch ----------------
// role A (blocks [0, NB_CONV)):            fp32 -> bf16 arena convert + S/T zero
// role B (blocks [NB_CONV, +NB_TR)):       Wp fp32 [D,R] -> WpT bf16 [R,D]
// role C (blocks [NB_CONV+NB_TR, +256)):   controller heads (reads RAW fp32
//   inputs with f2bf->bf2f round-trip == bit-identical to the arena path);
//   4 waves/block, wave wv handles b = bid*4 + wv.
// Merging removes 2 graph nodes (~7us inter-dispatch gap each) and runs the
// three roles concurrently.
__global__ __launch_bounds__(256) void k_prep(
        const float* x, const float* Wv, const float* bv, const float* Wb, const float* bb,
        const float* Wg, const float* bg, const float* bp,
        const float* ck, const float* cb, const float* mem, const float* Wp,
        unsigned short* __restrict__ dst, float* __restrict__ zst,
        unsigned short* __restrict__ WpT,
        float* __restrict__ v, unsigned short* __restrict__ vb,
        float* __restrict__ bovn, float* __restrict__ beta, float* __restrict__ gamma) {
    __shared__ unsigned short tile[64][66];
    __shared__ float sxh[4][256];
    int bid = blockIdx.x;
    int t = threadIdx.x;
    if (bid < NB_CONV) {
        // ---- role A: convert ----
        int base = bid * 512 + t;
#pragma unroll
        for (int h = 0; h < 2; h++) {
            int idx = base + h * 256;
            if (idx >= AO_TOT) continue;
            if (idx < 2048) zst[idx] = 0.f;   // S[1024] + T[1024]
            const float* p; int st; int n;
            if      (idx >= AO_MEM) { p = mem; st = AO_MEM; n = R_ * W_; }
            else if (idx >= AO_CB)  { p = cb;  st = AO_CB;  n = 1; }
            else if (idx >= AO_CK)  { p = ck;  st = AO_CK;  n = 3; }
            else if (idx >= AO_BP)  { p = bp;  st = AO_BP;  n = R_; }
            else if (idx >= AO_BG)  { p = bg;  st = AO_BG;  n = 1; }
            else if (idx >= AO_WG)  { p = Wg;  st = AO_WG;  n = D_; }
            else if (idx >= AO_BB)  { p = bb;  st = AO_BB;  n = 1; }
            else if (idx >= AO_WB)  { p = Wb;  st = AO_WB;  n = D_; }
            else if (idx >= AO_BV)  { p = bv;  st = AO_BV;  n = W_; }
            else if (idx >= AO_WV)  { p = Wv;  st = AO_WV;  n = D_ * W_; }
            else                    { p = x;   st = AO_X;   n = B_ * D_; }
            int local = idx - st;
            dst[idx] = (local < n) ? f2bf(p[local]) : (unsigned short)0;
        }
    } else if (bid < NB_CONV + NB_TR) {
        // ---- role B: Wp transpose+convert ----
        int b2 = bid - NB_CONV;
        int r0 = (b2 & 255) * 64, d0 = (b2 >> 8) * 64;
        int lane = t & 63, wv = t >> 6;
#pragma unroll
        for (int i = 0; i < 16; i++) {
            int dl = wv + 4 * i;
            tile[dl][lane] = f2bf(Wp[(size_t)(d0 + dl) * R_ + r0 + lane]);
        }
        __syncthreads();
#pragma unroll
        for (int i = 0; i < 16; i++) {
            int rl = wv + 4 * i;
            WpT[(size_t)(r0 + rl) * D_ + d0 + lane] = tile[lane][rl];
        }
    } else {
        // ---- role C: controller heads (raw fp32 inputs, rt() rounding) ----
        int wv = t >> 6, lane = t & 63;
        int b = (bid - NB_CONV - NB_TR) * 4 + wv;
        float* sx = sxh[wv];
#pragma unroll
        for (int j = 0; j < 4; j++) sx[lane + 64 * j] = rt(x[b * 256 + lane + 64 * j]);
        __syncthreads();
        float acc = 0.f;
#pragma unroll 8
        for (int d = 0; d < 256; d++) acc += sx[d] * rt(Wv[d * 64 + lane]);
        acc += rt(bv[lane]);
        v[b * 64 + lane] = acc;
        vb[b * 64 + lane] = f2bf(acc);
        float sq = acc * acc;
#pragma unroll
        for (int d = 32; d >= 1; d >>= 1) sq += __shfl_xor(sq, d, 64);
        float pb = 0.f, pg = 0.f;
#pragma unroll
        for (int j = 0; j < 4; j++) {
            float xv = sx[lane + 64 * j];
            pb += xv * rt(Wb[lane + 64 * j]);
            pg += xv * rt(Wg[lane + 64 * j]);
        }
#pragma unroll
        for (int d = 32; d >= 1; d >>= 1) { pb += __shfl_xor(pb, d, 64); pg += __shfl_xor(pg, d, 64); }
        if (lane == 0) {
            float vn = sqrtf(sq);
            float zb = pb + rt(bb[0]);
            float zg = pg + rt(bg[0]);
            float be = (zb > 20.f) ? zb : log1pf(__expf(zb));
            beta[b]  = be;
            bovn[b]  = be / (vn + 1e-16f);
            gamma[b] = 1.f + ((zg > 20.f) ? zg : log1pf(__expf(zg)));
        }
    }
}

// ---------------- K3: sim MFMA -> E = exp(acc*bovn*invmn - beta), S[b] ----------
// invmn computed INLINE from the already-loaded bm fragments.
__global__ __launch_bounds__(256, 8) void k_sim(const unsigned short* __restrict__ vb,
        const unsigned short* __restrict__ mem,
        const float* __restrict__ bovn,
        const float* __restrict__ beta,
        unsigned short* __restrict__ E, float* __restrict__ S) {
    __shared__ unsigned short etile[64][132];
    __shared__ float sred[4][64];
    int bx = blockIdx.x;
    int rc = bx & 127, tb = bx >> 7;
    int t = threadIdx.x, wv = t >> 6, l = t & 63;
    int lane15 = l & 15, quad = l >> 4;
    int rr0 = rc * 128 + wv * 32 + lane15;
    bf16x8 bm[2][2];
    float im[2];
#pragma unroll
    for (int nt = 0; nt < 2; nt++) {
        int rr = rr0 + nt * 16;
        bm[nt][0] = ld_bf8(mem + rr * 64 + quad * 8);
        bm[nt][1] = ld_bf8(mem + rr * 64 + 32 + quad * 8);
        float sq = sumsq8(bm[nt][0]) + sumsq8(bm[nt][1]);
        sq += __shfl_xor(sq, 16, 64);
        sq += __shfl_xor(sq, 32, 64);
        im[nt] = 1.0f / (sqrtf(sq) + 1e-16f);
    }
    bf16x8 afr[4][2];
    float bvl[4][4], bel[4][4];
#pragma unroll
    for (int m = 0; m < 4; m++) {
        int brow = tb * 64 + m * 16 + lane15;
        afr[m][0] = ld_bf8(vb + brow * 64 + quad * 8);
        afr[m][1] = ld_bf8(vb + brow * 64 + 32 + quad * 8);
#pragma unroll
        for (int reg = 0; reg < 4; reg++) {
            int b2 = tb * 64 + m * 16 + quad * 4 + reg;
            bvl[m][reg] = bovn[b2];
            bel[m][reg] = beta[b2];
        }
    }
    float sp[4][4];
#pragma unroll
    for (int m = 0; m < 4; m++)
#pragma unroll
        for (int r = 0; r < 4; r++) sp[m][r] = 0.f;

#pragma unroll
    for (int nt = 0; nt < 2; nt++) {
        int rl = wv * 32 + nt * 16 + lane15;
#pragma unroll
        for (int m = 0; m < 4; m++) {
            f32x4 acc = (f32x4){0.f, 0.f, 0.f, 0.f};
            acc = mfma16(afr[m][0], bm[nt][0], acc);
            acc = mfma16(afr[m][1], bm[nt][1], acc);
#pragma unroll
            for (int reg = 0; reg < 4; reg++) {
                float e = __expf(acc[reg] * (bvl[m][reg] * im[nt]) - bel[m][reg]);
                sp[m][reg] += e;
                etile[m * 16 + quad * 4 + reg][rl] = f2bf(e);
            }
        }
    }
#pragma unroll
    for (int m = 0; m < 4; m++)
#pragma unroll
        for (int reg = 0; reg < 4; reg++) {
            float s = sp[m][reg];
            s += __shfl_xor(s, 1, 64); s += __shfl_xor(s, 2, 64);
            s += __shfl_xor(s, 4, 64); s += __shfl_xor(s, 8, 64);
            if (lane15 == 0) sred[wv][m * 16 + quad * 4 + reg] = s;
        }
    __syncthreads();
#pragma unroll
    for (int j = 0; j < 4; j++) {
        int idx8 = t + j * 256;
        int row = idx8 >> 4;
        int c8 = (idx8 & 15) * 8;
        *(bf16x8*)(E + (size_t)(tb * 64 + row) * R_ + rc * 128 + c8) =
            *(const bf16x8*)&etile[row][c8];
    }
    if (t < 64)
        atomicAdd(&S[tb * 64 + t], sred[0][t] + sred[1][t] + sred[2][t] + sred[3][t]);
}

// ---------------- K4: conv+pow -> AT [R,B] (transposed!), T[b] ----------------
// ein padded to [64][136] (272B rows = 16-byte aligned) so staging uses 16B
// bf16x8 loads (4 iterations instead of 8x ushort4).
__global__ __launch_bounds__(256) void k_conv(const unsigned short* __restrict__ E,
        unsigned short* __restrict__ AT,
        const float* __restrict__ S, const float* __restrict__ gamma,
        const unsigned short* __restrict__ conv_k, const unsigned short* __restrict__ conv_b,
        float* __restrict__ T) {
    __shared__ unsigned short ein[64][136];   // 0..127 data; 128 right halo; 130 left halo
    __shared__ unsigned short aout[128][68];
    float k0 = bf2f(conv_k[0]), k1 = bf2f(conv_k[1]), k2 = bf2f(conv_k[2]);
    float cb = bf2f(conv_b[0]);
    int b0 = (blockIdx.x >> 7) * 64;
    int r0 = (blockIdx.x & 127) * 128;
    int t = threadIdx.x;
#pragma unroll
    for (int j = 0; j < 4; j++) {
        int idx8 = t + j * 256;
        int row = idx8 >> 4, c8 = (idx8 & 15) * 8;
        *(bf16x8*)&ein[row][c8] = *(const bf16x8*)(E + (size_t)(b0 + row) * R_ + r0 + c8);
    }
    if (t < 64) {
        ein[t][130] = (r0 > 0) ? E[(b0 + t) * R_ + r0 - 1] : (unsigned short)0;
    } else if (t < 128) {
        int tb = t - 64;
        ein[tb][128] = (r0 + 128 < R_) ? E[(b0 + tb) * R_ + r0 + 128] : (unsigned short)0;
    }
    int b = t >> 2;
    int base = (t & 3) * 32;
    float sS_ = 1.0f / S[b0 + b];
    float g = gamma[b0 + b];
    __syncthreads();

    float el = bf2f((base == 0) ? ein[b][130] : ein[b][base - 1]);
    float ec = bf2f(ein[b][base]);
    float tacc = 0.f;
#pragma unroll
    for (int i = 0; i < 32; i++) {
        float er = bf2f(ein[b][base + 1 + i]);
        float wc = (k0 * el + k1 * ec + k2 * er) * sS_ + cb;
        wc = fmaxf(wc, 1e-30f);
        float au = __builtin_amdgcn_exp2f(g * __log2f(wc));
        aout[base + i][b] = f2bf(au);
        tacc += au;
        el = ec; ec = er;
    }
    tacc += __shfl_xor(tacc, 1, 64);
    tacc += __shfl_xor(tacc, 2, 64);
    if ((t & 3) == 0) atomicAdd(&T[b0 + b], tacc);
    __syncthreads();
#pragma unroll
    for (int j = 0; j < 8; j++) {
        int idx4 = t + j * 256;
        int rrow = idx4 >> 4, c4 = (idx4 & 15) * 4;
        *(ushort4*)(AT + (size_t)(r0 + rrow) * B_ + b0 + c4) = *(ushort4*)&aout[rrow][c4];
    }
}

// ---------------- K4b: build vp' [80,1024] bf16 ----------------
__global__ __launch_bounds__(256) void k_vp2(const float* __restrict__ v, const float* __restrict__ T,
                                             unsigned short* __restrict__ vpb) {
    int idx = blockIdx.x * 256 + threadIdx.x;
    int m = idx >> 10, b = idx & 1023;
    float s = 1.0f / ((T[b] + (float)R_ * 1e-16f) * (float)B_);
    float val = (m < 64) ? v[b * 64 + m] * s : ((m == 64) ? s : 0.f);
    vpb[idx] = f2bf(val);
}

// ---------------- K5: MFMA GEMM mem2T = mem*(1-er) + vp'^ AT ----------------
__global__ __launch_bounds__(256) void k_add(const unsigned short* __restrict__ AT,
        const unsigned short* __restrict__ vpb,
        const unsigned short* __restrict__ memb, unsigned short* __restrict__ mem2T) {
    __shared__ unsigned short smem[64][68];
    __shared__ unsigned short sm2[64][68];
    int r0 = blockIdx.x * 64;
    int t = threadIdx.x, wv = t >> 6, l = t & 63;
    int lane15 = l & 15, quad = l >> 4;
#pragma unroll
    for (int j = 0; j < 4; j++) {
        int idx4 = t + j * 256;
        int rl = idx4 >> 4, w4 = (idx4 & 15) * 4;
        *(ushort4*)&smem[rl][w4] = *(const ushort4*)(memb + (r0 + rl) * 64 + w4);
    }
    __syncthreads();

    const unsigned short* Brow = AT + (size_t)(r0 + wv * 16 + lane15) * B_ + quad * 8;
    const unsigned short* A0 = vpb + (0 * 16 + lane15) * B_ + quad * 8;
    const unsigned short* A1 = vpb + (1 * 16 + lane15) * B_ + quad * 8;
    const unsigned short* A2 = vpb + (2 * 16 + lane15) * B_ + quad * 8;
    const unsigned short* A3 = vpb + (3 * 16 + lane15) * B_ + quad * 8;
    const unsigned short* A4 = vpb + (4 * 16 + lane15) * B_ + quad * 8;
    f32x4 acc0 = {0,0,0,0}, acc1 = {0,0,0,0}, acc2 = {0,0,0,0}, acc3 = {0,0,0,0}, acc4 = {0,0,0,0};
#pragma unroll 4
    for (int k0 = 0; k0 < B_; k0 += 32) {
        bf16x8 bf = ld_bf8(Brow + k0);
        acc0 = mfma16(ld_bf8(A0 + k0), bf, acc0);
        acc1 = mfma16(ld_bf8(A1 + k0), bf, acc1);
        acc2 = mfma16(ld_bf8(A2 + k0), bf, acc2);
        acc3 = mfma16(ld_bf8(A3 + k0), bf, acc3);
        acc4 = mfma16(ld_bf8(A4 + k0), bf, acc4);
    }
    float er = __shfl(acc4[0], l & 15, 64);
    float ome = 1.f - er;
    f32x4 accs[4] = {acc0, acc1, acc2, acc3};
#pragma unroll
    for (int mt = 0; mt < 4; mt++) {
#pragma unroll
        for (int reg = 0; reg < 4; reg++) {
            int w = mt * 16 + quad * 4 + reg;
            int rl = wv * 16 + lane15;
            float m2 = bf2f(smem[rl][w]) * ome + accs[mt][reg];
            sm2[w][rl] = f2bf(m2);
        }
    }
    __syncthreads();
#pragma unroll
    for (int j = 0; j < 4; j++) {
        int idx4 = t + j * 256;
        int w = idx4 >> 4, r4 = (idx4 & 15) * 4;
        *(ushort4*)(mem2T + (size_t)w * R_ + r0 + r4) = *(ushort4*)&sm2[w][r4];
    }
}

// ---------------- K6: flash read head, relaxed-barrier pipeline --------------
// XCD swizzle + dbuf bstage + fused PV + non-atomic partials + the R8 key fix:
// {lgkmcnt(0); s_barrier} instead of __syncthreads() so register prefetch
// loads span the barrier (no vmcnt(0) drain). -31us in R8.
__global__ __launch_bounds__(256, 4) void k_read(const unsigned short* __restrict__ x,
        const unsigned short* __restrict__ WpT, const unsigned short* __restrict__ bp,
        const unsigned short* __restrict__ mem2T,
        float* __restrict__ pacc, float* __restrict__ Spp) {
    __shared__ unsigned short bstage[2][32 * 264];
    __shared__ unsigned short ptile[4][16 * 40];
    int bx = blockIdx.x;
    int xcd = bx & 7, grp = bx >> 3;
    int rc = xcd * 8 + (grp >> 4), tb = grp & 15;
    int t = threadIdx.x, wv = t >> 6, l = t & 63;
    int lane15 = l & 15, quad = l >> 4;
    int brow = tb * 64 + wv * 16 + lane15;
    bf16x8 afr[8];
#pragma unroll
    for (int kk = 0; kk < 8; kk++)
        afr[kk] = ld_bf8(x + brow * 256 + kk * 32 + quad * 8);
    f32x4 accO[4];
#pragma unroll
    for (int nt = 0; nt < 4; nt++) accO[nt] = (f32x4){0.f, 0.f, 0.f, 0.f};
    float sp[4] = {0.f, 0.f, 0.f, 0.f};
    unsigned short* ptw = &ptile[wv][0];

    int srow = t >> 3, scg = (t & 7) * 8;
    bf16x8 pf[4];
    {   // prefetch phase 0 staging
        const unsigned short* src = WpT + (size_t)(rc * 256 + srow) * 256 + scg;
#pragma unroll
        for (int j = 0; j < 4; j++) pf[j] = *(const bf16x8*)(src + 64 * j);
    }
    const unsigned short* vrow = mem2T + (size_t)lane15 * R_ + rc * 256 + quad * 8;

    for (int ss = 0; ss < 8; ss++) {
        unsigned short* bcur = bstage[ss & 1];
        {
            unsigned short* dst = bcur + srow * 264 + scg;
#pragma unroll
            for (int j = 0; j < 4; j++) *(bf16x8*)(dst + 64 * j) = pf[j];
        }
        if (ss < 7) {
            const unsigned short* src = WpT
                + (size_t)(rc * 256 + (ss + 1) * 32 + srow) * 256 + scg;
#pragma unroll
            for (int j = 0; j < 4; j++) pf[j] = *(const bf16x8*)(src + 64 * j);
        }
        // relaxed barrier: drain LDS (cross-wave visibility) but NOT vmem
        __builtin_amdgcn_sched_barrier(0);
        asm volatile("s_waitcnt lgkmcnt(0)" ::: "memory");
        __builtin_amdgcn_s_barrier();
        __builtin_amdgcn_sched_barrier(0);
        bf16x8 vv0 = ld_bf8(vrow + (size_t)0 * 16 * R_ + ss * 32);
        bf16x8 vv1 = ld_bf8(vrow + (size_t)1 * 16 * R_ + ss * 32);
        bf16x8 vv2 = ld_bf8(vrow + (size_t)2 * 16 * R_ + ss * 32);
        bf16x8 vv3 = ld_bf8(vrow + (size_t)3 * 16 * R_ + ss * 32);
        int rbase = rc * 256 + ss * 32;
#pragma unroll
        for (int nt = 0; nt < 2; nt++) {
            f32x4 acc = (f32x4){0.f, 0.f, 0.f, 0.f};
            const unsigned short* bb = bcur + (nt * 16 + lane15) * 264 + quad * 8;
#pragma unroll
            for (int kk = 0; kk < 8; kk++) {
                bf16x8 bfr = *(const bf16x8*)(bb + kk * 32);
                acc = mfma16(afr[kk], bfr, acc);
            }
            int rr = rbase + nt * 16 + lane15;
            float bpv = bf2f(bp[rr]);
#pragma unroll
            for (int reg = 0; reg < 4; reg++) {
                float e = __expf(acc[reg] + bpv);
                unsigned short ue = f2bf(e);
                sp[reg] += bf2f(ue);   // match PV numerator quantization
                ptw[(quad * 4 + reg) * 40 + nt * 16 + lane15] = ue;
            }
        }
        bf16x8 pa = *(const bf16x8*)(ptw + lane15 * 40 + quad * 8);
        accO[0] = mfma16(pa, vv0, accO[0]);
        accO[1] = mfma16(pa, vv1, accO[1]);
        accO[2] = mfma16(pa, vv2, accO[2]);
        accO[3] = mfma16(pa, vv3, accO[3]);
    }
    // non-atomic partial writes: this block is the sole writer of (rc, b-tile)
#pragma unroll
    for (int nt = 0; nt < 4; nt++) {
        int wcol = nt * 16 + lane15;
#pragma unroll
        for (int reg = 0; reg < 4; reg++) {
            int b2 = tb * 64 + wv * 16 + quad * 4 + reg;
            pacc[((size_t)rc * B_ + b2) * 64 + wcol] = accO[nt][reg];
        }
    }
#pragma unroll
    for (int reg = 0; reg < 4; reg++) {
        float s = sp[reg];
        s += __shfl_xor(s, 1, 64); s += __shfl_xor(s, 2, 64);
        s += __shfl_xor(s, 4, 64); s += __shfl_xor(s, 8, 64);
        if (lane15 == 0) {
            int b2 = tb * 64 + wv * 16 + quad * 4 + reg;
            Spp[(size_t)rc * B_ + b2] = s;
        }
    }
}

// ---------------- K7: out = (sum_rc pacc) / (sum_rc Spp) -> FP32 --------------
__global__ __launch_bounds__(256) void k_out(const float* __restrict__ pacc,
                                             const float* __restrict__ Spp,
                                             float* __restrict__ out) {
    int idx = blockIdx.x * 256 + threadIdx.x;   // 65536 elements
    int b = idx >> 6;
    float acc = 0.f, sps = 0.f;
#pragma unroll 8
    for (int rc = 0; rc < 64; rc++) {
        acc += pacc[(size_t)rc * (B_ * 64) + idx];
        sps += Spp[rc * B_ + b];
    }
    out[idx] = acc / sps;
}

extern "C" void kernel_launch(void* const* d_in, const int* in_sizes, int n_in,
                              void* d_out, int out_size, void* d_ws, size_t ws_size,
                              hipStream_t stream) {
    (void)n_in; (void)out_size;
    float* outp = (float*)d_out;

    char* ws = (char*)d_ws;
    size_t o = 0;
    unsigned short* arena = (unsigned short*)(ws + o); o += (size_t)AO_TOT * 2;
    unsigned short* WpT = (unsigned short*)(ws + o); o += (size_t)R_ * D_ * 2;
    unsigned short* E   = (unsigned short*)(ws + o); o += (size_t)B_ * R_ * 2;
    unsigned short* AT  = (unsigned short*)(ws + o); o += (size_t)B_ * R_ * 2;
    float* v            = (float*)(ws + o);          o += (size_t)B_ * 64 * 4;
    unsigned short* vb  = (unsigned short*)(ws + o); o += (size_t)B_ * 64 * 2;
    unsigned short* vpb = (unsigned short*)(ws + o); o += (size_t)80 * B_ * 2;
    float* bovn         = (float*)(ws + o);          o += 4096;
    float* beta         = (float*)(ws + o);          o += 4096;
    float* gamma        = (float*)(ws + o);          o += 4096;
    unsigned short* m2T = (unsigned short*)(ws + o); o += (size_t)R_ * 64 * 2;
    float* S      = (float*)(ws + o);                o += 4096;
    float* T      = (float*)(ws + o);                o += 4096;
    float* Spp    = (float*)(ws + o);                o += (size_t)B_ * 64 * 4;
    // pacc (64 x 1024 x 64 fp32 = 16.8 MB) reuses AT's slot (AT dead after k_add)
    float* pacc = (float*)AT;

    if (ws_size < o) {
        k_sentinel<<<256, 256, 0, stream>>>(outp, 1000.0f);
        return;
    }
    if (in_sizes[0] != B_ * D_ || in_sizes[7] != D_ * R_ || in_sizes[11] != R_ * W_) {
        k_sentinel<<<256, 256, 0, stream>>>(outp, 2000.0f);
        return;
    }

    k_prep<<<NB_CONV + NB_TR + NB_HEADS, 256, 0, stream>>>(
        (const float*)d_in[0], (const float*)d_in[1], (const float*)d_in[2],
        (const float*)d_in[3], (const float*)d_in[4], (const float*)d_in[5],
        (const float*)d_in[6], (const float*)d_in[8],
        (const float*)d_in[9], (const float*)d_in[10], (const float*)d_in[11],
        (const float*)d_in[7],
        arena, S, WpT, v, vb, bovn, beta, gamma);

    k_sim<<<2048, 256, 0, stream>>>(vb, arena + AO_MEM, bovn, beta, E, S);
    k_conv<<<2048, 256, 0, stream>>>(E, AT, S, gamma, arena + AO_CK, arena + AO_CB, T);
    k_vp2<<<320, 256, 0, stream>>>(v, T, vpb);
    k_add<<<256, 256, 0, stream>>>(AT, vpb, arena + AO_MEM, m2T);
    k_read<<<1024, 256, 0, stream>>>(arena + AO_X, WpT, arena + AO_BP, m2T, pacc, Spp);
    k_out<<<256, 256, 0, stream>>>(pacc, Spp, outp);
}

// Round 10
// 212.227 us; speedup vs baseline: 1.7514x; 1.0244x over previous
//
#include <hip/hip_runtime.h>
#include <hip/hip_bf16.h>

#define B_ 1024
#define D_ 256
#define R_ 16384
#define W_ 64

typedef float f32x4 __attribute__((ext_vector_type(4)));
typedef __bf16 bf16x8 __attribute__((ext_vector_type(8)));

__device__ __forceinline__ float bf2f(unsigned short u) {
    union { unsigned int i; float f; } v; v.i = ((unsigned int)u) << 16; return v.f;
}
__device__ __forceinline__ unsigned short f2bf(float f) {
    union { float fv; unsigned int i; } v; v.fv = f;
    unsigned int r = v.i + 0x7FFFu + ((v.i >> 16) & 1u);
    return (unsigned short)(r >> 16);
}
__device__ __forceinline__ float rt(float f) {   // bf16 round-trip (matches arena path)
    return bf2f(f2bf(f));
}
__device__ __forceinline__ f32x4 mfma16(bf16x8 a, bf16x8 b, f32x4 c) {
    return __builtin_amdgcn_mfma_f32_16x16x32_bf16(a, b, c, 0, 0, 0);
}
__device__ __forceinline__ bf16x8 ld_bf8(const unsigned short* p) {
    return *(const bf16x8*)p;
}
__device__ __forceinline__ float sumsq8(bf16x8 v) {
    union { bf16x8 v; unsigned short u[8]; } c; c.v = v;
    float s = 0.f;
#pragma unroll
    for (int j = 0; j < 8; j++) { float f = bf2f(c.u[j]); s += f * f; }
    return s;
}

// ---------------- arena element offsets (each segment start 16-elem aligned) ----
#define AO_X     0
#define AO_WV    262144
#define AO_BV    278528
#define AO_WB    278592
#define AO_BB    278848
#define AO_WG    278864
#define AO_BG    279120
#define AO_BP    279136
#define AO_CK    295520
#define AO_CB    295536
#define AO_MEM   295552
#define AO_TOT   1344128

#define NB_CONV  ((AO_TOT + 511) / 512)
#define NB_TR    1024
#define NB_HEADS 256

__global__ __launch_bounds__(256) void k_sentinel(float* __restrict__ out, float val) {
    out[blockIdx.x * 256 + threadIdx.x] = val;
}

// ---------------- K-prep: 3 independent roles in ONE dispatch ----------------
// role A: fp32 -> bf16 arena convert + S/T zero
// role B: Wp fp32 [D,R] -> WpT bf16 [R,D]
// role C: controller heads (raw fp32 + rt() == bit-identical to arena path)
__global__ __launch_bounds__(256) void k_prep(
        const float* x, const float* Wv, const float* bv, const float* Wb, const float* bb,
        const float* Wg, const float* bg, const float* bp,
        const float* ck, const float* cb, const float* mem, const float* Wp,
        unsigned short* __restrict__ dst, float* __restrict__ zst,
        unsigned short* __restrict__ WpT,
        float* __restrict__ v, unsigned short* __restrict__ vb,
        float* __restrict__ bovn, float* __restrict__ beta, float* __restrict__ gamma) {
    __shared__ unsigned short tile[64][66];
    __shared__ float sxh[4][256];
    int bid = blockIdx.x;
    int t = threadIdx.x;
    if (bid < NB_CONV) {
        int base = bid * 512 + t;
#pragma unroll
        for (int h = 0; h < 2; h++) {
            int idx = base + h * 256;
            if (idx >= AO_TOT) continue;
            if (idx < 2048) zst[idx] = 0.f;   // S[1024] + T[1024]
            const float* p; int st; int n;
            if      (idx >= AO_MEM) { p = mem; st = AO_MEM; n = R_ * W_; }
            else if (idx >= AO_CB)  { p = cb;  st = AO_CB;  n = 1; }
            else if (idx >= AO_CK)  { p = ck;  st = AO_CK;  n = 3; }
            else if (idx >= AO_BP)  { p = bp;  st = AO_BP;  n = R_; }
            else if (idx >= AO_BG)  { p = bg;  st = AO_BG;  n = 1; }
            else if (idx >= AO_WG)  { p = Wg;  st = AO_WG;  n = D_; }
            else if (idx >= AO_BB)  { p = bb;  st = AO_BB;  n = 1; }
            else if (idx >= AO_WB)  { p = Wb;  st = AO_WB;  n = D_; }
            else if (idx >= AO_BV)  { p = bv;  st = AO_BV;  n = W_; }
            else if (idx >= AO_WV)  { p = Wv;  st = AO_WV;  n = D_ * W_; }
            else                    { p = x;   st = AO_X;   n = B_ * D_; }
            int local = idx - st;
            dst[idx] = (local < n) ? f2bf(p[local]) : (unsigned short)0;
        }
    } else if (bid < NB_CONV + NB_TR) {
        int b2 = bid - NB_CONV;
        int r0 = (b2 & 255) * 64, d0 = (b2 >> 8) * 64;
        int lane = t & 63, wv = t >> 6;
#pragma unroll
        for (int i = 0; i < 16; i++) {
            int dl = wv + 4 * i;
            tile[dl][lane] = f2bf(Wp[(size_t)(d0 + dl) * R_ + r0 + lane]);
        }
        __syncthreads();
#pragma unroll
        for (int i = 0; i < 16; i++) {
            int rl = wv + 4 * i;
            WpT[(size_t)(r0 + rl) * D_ + d0 + lane] = tile[lane][rl];
        }
    } else {
        int wv = t >> 6, lane = t & 63;
        int b = (bid - NB_CONV - NB_TR) * 4 + wv;
        float* sx = sxh[wv];
#pragma unroll
        for (int j = 0; j < 4; j++) sx[lane + 64 * j] = rt(x[b * 256 + lane + 64 * j]);
        __syncthreads();
        float acc = 0.f;
#pragma unroll 8
        for (int d = 0; d < 256; d++) acc += sx[d] * rt(Wv[d * 64 + lane]);
        acc += rt(bv[lane]);
        v[b * 64 + lane] = acc;
        vb[b * 64 + lane] = f2bf(acc);
        float sq = acc * acc;
#pragma unroll
        for (int d = 32; d >= 1; d >>= 1) sq += __shfl_xor(sq, d, 64);
        float pb = 0.f, pg = 0.f;
#pragma unroll
        for (int j = 0; j < 4; j++) {
            float xv = sx[lane + 64 * j];
            pb += xv * rt(Wb[lane + 64 * j]);
            pg += xv * rt(Wg[lane + 64 * j]);
        }
#pragma unroll
        for (int d = 32; d >= 1; d >>= 1) { pb += __shfl_xor(pb, d, 64); pg += __shfl_xor(pg, d, 64); }
        if (lane == 0) {
            float vn = sqrtf(sq);
            float zb = pb + rt(bb[0]);
            float zg = pg + rt(bg[0]);
            float be = (zb > 20.f) ? zb : log1pf(__expf(zb));
            beta[b]  = be;
            bovn[b]  = be / (vn + 1e-16f);
            gamma[b] = 1.f + ((zg > 20.f) ? zg : log1pf(__expf(zg)));
        }
    }
}

// ---------------- K3: sim MFMA -> E = exp(acc*bovn*invmn - beta), S[b] ----------
// invmn computed INLINE from the already-loaded bm fragments.
// LAUNCH BOUNDS FIX (R10): was (256,8) which caps VGPRs at 64, but live state
// (afr 32 + bm 16 + bvl/bel 32 + sp 16 + misc) is ~110 VGPRs -> ~45 VGPRs
// spilled to scratch in the hot loop since R0. (256,4) -> 128-VGPR cap, no
// spill; 4 blocks/CU (16 waves) is ample for a 33.5MB-streaming kernel.
__global__ __launch_bounds__(256, 4) void k_sim(const unsigned short* __restrict__ vb,
        const unsigned short* __restrict__ mem,
        const float* __restrict__ bovn,
        const float* __restrict__ beta,
        unsigned short* __restrict__ E, float* __restrict__ S) {
    __shared__ unsigned short etile[64][132];
    __shared__ float sred[4][64];
    int bx = blockIdx.x;
    int rc = bx & 127, tb = bx >> 7;
    int t = threadIdx.x, wv = t >> 6, l = t & 63;
    int lane15 = l & 15, quad = l >> 4;
    int rr0 = rc * 128 + wv * 32 + lane15;
    bf16x8 bm[2][2];
    float im[2];
#pragma unroll
    for (int nt = 0; nt < 2; nt++) {
        int rr = rr0 + nt * 16;
        bm[nt][0] = ld_bf8(mem + rr * 64 + quad * 8);
        bm[nt][1] = ld_bf8(mem + rr * 64 + 32 + quad * 8);
        float sq = sumsq8(bm[nt][0]) + sumsq8(bm[nt][1]);
        sq += __shfl_xor(sq, 16, 64);
        sq += __shfl_xor(sq, 32, 64);
        im[nt] = 1.0f / (sqrtf(sq) + 1e-16f);
    }
    bf16x8 afr[4][2];
    float bvl[4][4], bel[4][4];
#pragma unroll
    for (int m = 0; m < 4; m++) {
        int brow = tb * 64 + m * 16 + lane15;
        afr[m][0] = ld_bf8(vb + brow * 64 + quad * 8);
        afr[m][1] = ld_bf8(vb + brow * 64 + 32 + quad * 8);
#pragma unroll
        for (int reg = 0; reg < 4; reg++) {
            int b2 = tb * 64 + m * 16 + quad * 4 + reg;
            bvl[m][reg] = bovn[b2];
            bel[m][reg] = beta[b2];
        }
    }
    float sp[4][4];
#pragma unroll
    for (int m = 0; m < 4; m++)
#pragma unroll
        for (int r = 0; r < 4; r++) sp[m][r] = 0.f;

#pragma unroll
    for (int nt = 0; nt < 2; nt++) {
        int rl = wv * 32 + nt * 16 + lane15;
#pragma unroll
        for (int m = 0; m < 4; m++) {
            f32x4 acc = (f32x4){0.f, 0.f, 0.f, 0.f};
            acc = mfma16(afr[m][0], bm[nt][0], acc);
            acc = mfma16(afr[m][1], bm[nt][1], acc);
#pragma unroll
            for (int reg = 0; reg < 4; reg++) {
                float e = __expf(acc[reg] * (bvl[m][reg] * im[nt]) - bel[m][reg]);
                sp[m][reg] += e;
                etile[m * 16 + quad * 4 + reg][rl] = f2bf(e);
            }
        }
    }
#pragma unroll
    for (int m = 0; m < 4; m++)
#pragma unroll
        for (int reg = 0; reg < 4; reg++) {
            float s = sp[m][reg];
            s += __shfl_xor(s, 1, 64); s += __shfl_xor(s, 2, 64);
            s += __shfl_xor(s, 4, 64); s += __shfl_xor(s, 8, 64);
            if (lane15 == 0) sred[wv][m * 16 + quad * 4 + reg] = s;
        }
    __syncthreads();
#pragma unroll
    for (int j = 0; j < 4; j++) {
        int idx8 = t + j * 256;
        int row = idx8 >> 4;
        int c8 = (idx8 & 15) * 8;
        *(bf16x8*)(E + (size_t)(tb * 64 + row) * R_ + rc * 128 + c8) =
            *(const bf16x8*)&etile[row][c8];
    }
    if (t < 64)
        atomicAdd(&S[tb * 64 + t], sred[0][t] + sred[1][t] + sred[2][t] + sred[3][t]);
}

// ---------------- K4: conv+pow -> AT [R,B] (transposed!), T[b] ----------------
__global__ __launch_bounds__(256) void k_conv(const unsigned short* __restrict__ E,
        unsigned short* __restrict__ AT,
        const float* __restrict__ S, const float* __restrict__ gamma,
        const unsigned short* __restrict__ conv_k, const unsigned short* __restrict__ conv_b,
        float* __restrict__ T) {
    __shared__ unsigned short ein[64][136];   // 0..127 data; 128 right halo; 130 left halo
    __shared__ unsigned short aout[128][68];
    float k0 = bf2f(conv_k[0]), k1 = bf2f(conv_k[1]), k2 = bf2f(conv_k[2]);
    float cb = bf2f(conv_b[0]);
    int b0 = (blockIdx.x >> 7) * 64;
    int r0 = (blockIdx.x & 127) * 128;
    int t = threadIdx.x;
#pragma unroll
    for (int j = 0; j < 4; j++) {
        int idx8 = t + j * 256;
        int row = idx8 >> 4, c8 = (idx8 & 15) * 8;
        *(bf16x8*)&ein[row][c8] = *(const bf16x8*)(E + (size_t)(b0 + row) * R_ + r0 + c8);
    }
    if (t < 64) {
        ein[t][130] = (r0 > 0) ? E[(b0 + t) * R_ + r0 - 1] : (unsigned short)0;
    } else if (t < 128) {
        int tb = t - 64;
        ein[tb][128] = (r0 + 128 < R_) ? E[(b0 + tb) * R_ + r0 + 128] : (unsigned short)0;
    }
    int b = t >> 2;
    int base = (t & 3) * 32;
    float sS_ = 1.0f / S[b0 + b];
    float g = gamma[b0 + b];
    __syncthreads();

    float el = bf2f((base == 0) ? ein[b][130] : ein[b][base - 1]);
    float ec = bf2f(ein[b][base]);
    float tacc = 0.f;
#pragma unroll
    for (int i = 0; i < 32; i++) {
        float er = bf2f(ein[b][base + 1 + i]);
        float wc = (k0 * el + k1 * ec + k2 * er) * sS_ + cb;
        wc = fmaxf(wc, 1e-30f);
        float au = __builtin_amdgcn_exp2f(g * __log2f(wc));
        aout[base + i][b] = f2bf(au);
        tacc += au;
        el = ec; ec = er;
    }
    tacc += __shfl_xor(tacc, 1, 64);
    tacc += __shfl_xor(tacc, 2, 64);
    if ((t & 3) == 0) atomicAdd(&T[b0 + b], tacc);
    __syncthreads();
#pragma unroll
    for (int j = 0; j < 8; j++) {
        int idx4 = t + j * 256;
        int rrow = idx4 >> 4, c4 = (idx4 & 15) * 4;
        *(ushort4*)(AT + (size_t)(r0 + rrow) * B_ + b0 + c4) = *(ushort4*)&aout[rrow][c4];
    }
}

// ---------------- K4b: build vp' [80,1024] bf16 ----------------
__global__ __launch_bounds__(256) void k_vp2(const float* __restrict__ v, const float* __restrict__ T,
                                             unsigned short* __restrict__ vpb) {
    int idx = blockIdx.x * 256 + threadIdx.x;
    int m = idx >> 10, b = idx & 1023;
    float s = 1.0f / ((T[b] + (float)R_ * 1e-16f) * (float)B_);
    float val = (m < 64) ? v[b * 64 + m] * s : ((m == 64) ? s : 0.f);
    vpb[idx] = f2bf(val);
}

// ---------------- K5: MFMA GEMM mem2T = mem*(1-er) + vp'^ AT ----------------
__global__ __launch_bounds__(256) void k_add(const unsigned short* __restrict__ AT,
        const unsigned short* __restrict__ vpb,
        const unsigned short* __restrict__ memb, unsigned short* __restrict__ mem2T) {
    __shared__ unsigned short smem[64][68];
    __shared__ unsigned short sm2[64][68];
    int r0 = blockIdx.x * 64;
    int t = threadIdx.x, wv = t >> 6, l = t & 63;
    int lane15 = l & 15, quad = l >> 4;
#pragma unroll
    for (int j = 0; j < 4; j++) {
        int idx4 = t + j * 256;
        int rl = idx4 >> 4, w4 = (idx4 & 15) * 4;
        *(ushort4*)&smem[rl][w4] = *(const ushort4*)(memb + (r0 + rl) * 64 + w4);
    }
    __syncthreads();

    const unsigned short* Brow = AT + (size_t)(r0 + wv * 16 + lane15) * B_ + quad * 8;
    const unsigned short* A0 = vpb + (0 * 16 + lane15) * B_ + quad * 8;
    const unsigned short* A1 = vpb + (1 * 16 + lane15) * B_ + quad * 8;
    const unsigned short* A2 = vpb + (2 * 16 + lane15) * B_ + quad * 8;
    const unsigned short* A3 = vpb + (3 * 16 + lane15) * B_ + quad * 8;
    const unsigned short* A4 = vpb + (4 * 16 + lane15) * B_ + quad * 8;
    f32x4 acc0 = {0,0,0,0}, acc1 = {0,0,0,0}, acc2 = {0,0,0,0}, acc3 = {0,0,0,0}, acc4 = {0,0,0,0};
#pragma unroll 4
    for (int k0 = 0; k0 < B_; k0 += 32) {
        bf16x8 bf = ld_bf8(Brow + k0);
        acc0 = mfma16(ld_bf8(A0 + k0), bf, acc0);
        acc1 = mfma16(ld_bf8(A1 + k0), bf, acc1);
        acc2 = mfma16(ld_bf8(A2 + k0), bf, acc2);
        acc3 = mfma16(ld_bf8(A3 + k0), bf, acc3);
        acc4 = mfma16(ld_bf8(A4 + k0), bf, acc4);
    }
    float er = __shfl(acc4[0], l & 15, 64);
    float ome = 1.f - er;
    f32x4 accs[4] = {acc0, acc1, acc2, acc3};
#pragma unroll
    for (int mt = 0; mt < 4; mt++) {
#pragma unroll
        for (int reg = 0; reg < 4; reg++) {
            int w = mt * 16 + quad * 4 + reg;
            int rl = wv * 16 + lane15;
            float m2 = bf2f(smem[rl][w]) * ome + accs[mt][reg];
            sm2[w][rl] = f2bf(m2);
        }
    }
    __syncthreads();
#pragma unroll
    for (int j = 0; j < 4; j++) {
        int idx4 = t + j * 256;
        int w = idx4 >> 4, r4 = (idx4 & 15) * 4;
        *(ushort4*)(mem2T + (size_t)w * R_ + r0 + r4) = *(ushort4*)&sm2[w][r4];
    }
}

// ---------------- K6: flash read head, relaxed-barrier pipeline --------------
// XCD swizzle + dbuf bstage + fused PV + non-atomic partials + the R8 key fix:
// {lgkmcnt(0); s_barrier} instead of __syncthreads() so register prefetch
// loads span the barrier (no vmcnt(0) drain). -31us in R8.
__global__ __launch_bounds__(256, 4) void k_read(const unsigned short* __restrict__ x,
        const unsigned short* __restrict__ WpT, const unsigned short* __restrict__ bp,
        const unsigned short* __restrict__ mem2T,
        float* __restrict__ pacc, float* __restrict__ Spp) {
    __shared__ unsigned short bstage[2][32 * 264];
    __shared__ unsigned short ptile[4][16 * 40];
    int bx = blockIdx.x;
    int xcd = bx & 7, grp = bx >> 3;
    int rc = xcd * 8 + (grp >> 4), tb = grp & 15;
    int t = threadIdx.x, wv = t >> 6, l = t & 63;
    int lane15 = l & 15, quad = l >> 4;
    int brow = tb * 64 + wv * 16 + lane15;
    bf16x8 afr[8];
#pragma unroll
    for (int kk = 0; kk < 8; kk++)
        afr[kk] = ld_bf8(x + brow * 256 + kk * 32 + quad * 8);
    f32x4 accO[4];
#pragma unroll
    for (int nt = 0; nt < 4; nt++) accO[nt] = (f32x4){0.f, 0.f, 0.f, 0.f};
    float sp[4] = {0.f, 0.f, 0.f, 0.f};
    unsigned short* ptw = &ptile[wv][0];

    int srow = t >> 3, scg = (t & 7) * 8;
    bf16x8 pf[4];
    {   // prefetch phase 0 staging
        const unsigned short* src = WpT + (size_t)(rc * 256 + srow) * 256 + scg;
#pragma unroll
        for (int j = 0; j < 4; j++) pf[j] = *(const bf16x8*)(src + 64 * j);
    }
    const unsigned short* vrow = mem2T + (size_t)lane15 * R_ + rc * 256 + quad * 8;

    for (int ss = 0; ss < 8; ss++) {
        unsigned short* bcur = bstage[ss & 1];
        {
            unsigned short* dst = bcur + srow * 264 + scg;
#pragma unroll
            for (int j = 0; j < 4; j++) *(bf16x8*)(dst + 64 * j) = pf[j];
        }
        if (ss < 7) {
            const unsigned short* src = WpT
                + (size_t)(rc * 256 + (ss + 1) * 32 + srow) * 256 + scg;
#pragma unroll
            for (int j = 0; j < 4; j++) pf[j] = *(const bf16x8*)(src + 64 * j);
        }
        // relaxed barrier: drain LDS (cross-wave visibility) but NOT vmem
        __builtin_amdgcn_sched_barrier(0);
        asm volatile("s_waitcnt lgkmcnt(0)" ::: "memory");
        __builtin_amdgcn_s_barrier();
        __builtin_amdgcn_sched_barrier(0);
        bf16x8 vv0 = ld_bf8(vrow + (size_t)0 * 16 * R_ + ss * 32);
        bf16x8 vv1 = ld_bf8(vrow + (size_t)1 * 16 * R_ + ss * 32);
        bf16x8 vv2 = ld_bf8(vrow + (size_t)2 * 16 * R_ + ss * 32);
        bf16x8 vv3 = ld_bf8(vrow + (size_t)3 * 16 * R_ + ss * 32);
        int rbase = rc * 256 + ss * 32;
#pragma unroll
        for (int nt = 0; nt < 2; nt++) {
            f32x4 acc = (f32x4){0.f, 0.f, 0.f, 0.f};
            const unsigned short* bb = bcur + (nt * 16 + lane15) * 264 + quad * 8;
#pragma unroll
            for (int kk = 0; kk < 8; kk++) {
                bf16x8 bfr = *(const bf16x8*)(bb + kk * 32);
                acc = mfma16(afr[kk], bfr, acc);
            }
            int rr = rbase + nt * 16 + lane15;
            float bpv = bf2f(bp[rr]);
#pragma unroll
            for (int reg = 0; reg < 4; reg++) {
                float e = __expf(acc[reg] + bpv);
                unsigned short ue = f2bf(e);
                sp[reg] += bf2f(ue);   // match PV numerator quantization
                ptw[(quad * 4 + reg) * 40 + nt * 16 + lane15] = ue;
            }
        }
        bf16x8 pa = *(const bf16x8*)(ptw + lane15 * 40 + quad * 8);
        accO[0] = mfma16(pa, vv0, accO[0]);
        accO[1] = mfma16(pa, vv1, accO[1]);
        accO[2] = mfma16(pa, vv2, accO[2]);
        accO[3] = mfma16(pa, vv3, accO[3]);
    }
    // non-atomic partial writes: this block is the sole writer of (rc, b-tile)
#pragma unroll
    for (int nt = 0; nt < 4; nt++) {
        int wcol = nt * 16 + lane15;
#pragma unroll
        for (int reg = 0; reg < 4; reg++) {
            int b2 = tb * 64 + wv * 16 + quad * 4 + reg;
            pacc[((size_t)rc * B_ + b2) * 64 + wcol] = accO[nt][reg];
        }
    }
#pragma unroll
    for (int reg = 0; reg < 4; reg++) {
        float s = sp[reg];
        s += __shfl_xor(s, 1, 64); s += __shfl_xor(s, 2, 64);
        s += __shfl_xor(s, 4, 64); s += __shfl_xor(s, 8, 64);
        if (lane15 == 0) {
            int b2 = tb * 64 + wv * 16 + quad * 4 + reg;
            Spp[(size_t)rc * B_ + b2] = s;
        }
    }
}

// ---------------- K7: out = (sum_rc pacc) / (sum_rc Spp) -> FP32 --------------
__global__ __launch_bounds__(256) void k_out(const float* __restrict__ pacc,
                                             const float* __restrict__ Spp,
                                             float* __restrict__ out) {
    int idx = blockIdx.x * 256 + threadIdx.x;   // 65536 elements
    int b = idx >> 6;
    float acc = 0.f, sps = 0.f;
#pragma unroll 8
    for (int rc = 0; rc < 64; rc++) {
        acc += pacc[(size_t)rc * (B_ * 64) + idx];
        sps += Spp[rc * B_ + b];
    }
    out[idx] = acc / sps;
}

extern "C" void kernel_launch(void* const* d_in, const int* in_sizes, int n_in,
                              void* d_out, int out_size, void* d_ws, size_t ws_size,
                              hipStream_t stream) {
    (void)n_in; (void)out_size;
    float* outp = (float*)d_out;

    char* ws = (char*)d_ws;
    size_t o = 0;
    unsigned short* arena = (unsigned short*)(ws + o); o += (size_t)AO_TOT * 2;
    unsigned short* WpT = (unsigned short*)(ws + o); o += (size_t)R_ * D_ * 2;
    unsigned short* E   = (unsigned short*)(ws + o); o += (size_t)B_ * R_ * 2;
    unsigned short* AT  = (unsigned short*)(ws + o); o += (size_t)B_ * R_ * 2;
    float* v            = (float*)(ws + o);          o += (size_t)B_ * 64 * 4;
    unsigned short* vb  = (unsigned short*)(ws + o); o += (size_t)B_ * 64 * 2;
    unsigned short* vpb = (unsigned short*)(ws + o); o += (size_t)80 * B_ * 2;
    float* bovn         = (float*)(ws + o);          o += 4096;
    float* beta         = (float*)(ws + o);          o += 4096;
    float* gamma        = (float*)(ws + o);          o += 4096;
    unsigned short* m2T = (unsigned short*)(ws + o); o += (size_t)R_ * 64 * 2;
    float* S      = (float*)(ws + o);                o += 4096;
    float* T      = (float*)(ws + o);                o += 4096;
    float* Spp    = (float*)(ws + o);                o += (size_t)B_ * 64 * 4;
    // pacc (64 x 1024 x 64 fp32 = 16.8 MB) reuses AT's slot (AT dead after k_add)
    float* pacc = (float*)AT;

    if (ws_size < o) {
        k_sentinel<<<256, 256, 0, stream>>>(outp, 1000.0f);
        return;
    }
    if (in_sizes[0] != B_ * D_ || in_sizes[7] != D_ * R_ || in_sizes[11] != R_ * W_) {
        k_sentinel<<<256, 256, 0, stream>>>(outp, 2000.0f);
        return;
    }

    k_prep<<<NB_CONV + NB_TR + NB_HEADS, 256, 0, stream>>>(
        (const float*)d_in[0], (const float*)d_in[1], (const float*)d_in[2],
        (const float*)d_in[3], (const float*)d_in[4], (const float*)d_in[5],
        (const float*)d_in[6], (const float*)d_in[8],
        (const float*)d_in[9], (const float*)d_in[10], (const float*)d_in[11],
        (const float*)d_in[7],
        arena, S, WpT, v, vb, bovn, beta, gamma);

    k_sim<<<2048, 256, 0, stream>>>(vb, arena + AO_MEM, bovn, beta, E, S);
    k_conv<<<2048, 256, 0, stream>>>(E, AT, S, gamma, arena + AO_CK, arena + AO_CB, T);
    k_vp2<<<320, 256, 0, stream>>>(v, T, vpb);
    k_add<<<256, 256, 0, stream>>>(AT, vpb, arena + AO_MEM, m2T);
    k_read<<<1024, 256, 0, stream>>>(arena + AO_X, WpT, arena + AO_BP, m2T, pacc, Spp);
    k_out<<<256, 256, 0, stream>>>(pacc, Spp, outp);
}